// Round 1
// baseline (652.586 us; speedup 1.0000x reference)
//
#include <hip/hip_runtime.h>
#include <math.h>

#define BB 16
#define SS 512
#define HH 1024
#define KT 5
#define NEGV 1e30f
#define TM 16

// ---------------- helpers ----------------
__device__ __forceinline__ float wave_sum(float v) {
    for (int off = 32; off; off >>= 1) v += __shfl_down(v, off);
    return v;
}

// ---------------- kernel 1: start logits + mask ----------------
__global__ void k_start_logits(const float* __restrict__ seq, const float* __restrict__ pm,
                               const float* __restrict__ w_start, const float* __restrict__ b_start,
                               float* __restrict__ sm) {
    const int row = blockIdx.x;   // 0..B*S-1
    const int t = threadIdx.x;    // 256
    __shared__ float scr[4];
    float4 a = ((const float4*)(seq + (size_t)row * HH))[t];
    float4 w = ((const float4*)w_start)[t];
    float d = a.x * w.x + a.y * w.y + a.z * w.z + a.w * w.w;
    d = wave_sum(d);
    if ((t & 63) == 0) scr[t >> 6] = d;
    __syncthreads();
    if (t == 0) {
        float s = scr[0] + scr[1] + scr[2] + scr[3] + b_start[0];
        float m = pm[row];
        sm[row] = s * (1.f - m) - NEGV * m;
    }
}

// ---------------- softmax + top-5 over 512 values (one block, 256 thr) ----------------
template <bool WRITE_P>
__device__ void softmax_topk(const float* __restrict__ x, float* __restrict__ p_out,
                             float* __restrict__ val_out, float* __restrict__ idxf_out,
                             int* __restrict__ idxi_out) {
    const int t = threadIdx.x;
    __shared__ float scr[4];
    __shared__ float sv[4];
    __shared__ int si[4];
    __shared__ int wi_s;
    float x0 = x[t], x1 = x[t + 256];

    // max
    float m = fmaxf(x0, x1);
    for (int off = 32; off; off >>= 1) m = fmaxf(m, __shfl_down(m, off));
    if ((t & 63) == 0) scr[t >> 6] = m;
    __syncthreads();
    m = fmaxf(fmaxf(scr[0], scr[1]), fmaxf(scr[2], scr[3]));
    __syncthreads();

    // sum of exp
    float e0 = expf(x0 - m), e1 = expf(x1 - m);
    float ssum = wave_sum(e0 + e1);
    if ((t & 63) == 0) scr[t >> 6] = ssum;
    __syncthreads();
    ssum = scr[0] + scr[1] + scr[2] + scr[3];
    __syncthreads();

    if (WRITE_P) {
        p_out[t] = e0 / ssum;
        p_out[t + 256] = e1 / ssum;
    }
    const float lse = m + logf(ssum);

    float v0 = x0, v1 = x1;
    for (int k = 0; k < KT; ++k) {
        float bv;
        int bi;
        if (v0 >= v1) { bv = v0; bi = t; } else { bv = v1; bi = t + 256; }
        for (int off = 32; off; off >>= 1) {
            float ov = __shfl_down(bv, off);
            int oi = __shfl_down(bi, off);
            if (ov > bv || (ov == bv && oi < bi)) { bv = ov; bi = oi; }
        }
        if ((t & 63) == 0) { sv[t >> 6] = bv; si[t >> 6] = bi; }
        __syncthreads();
        if (t == 0) {
            float fv = sv[0];
            int fi = si[0];
            for (int w = 1; w < 4; ++w)
                if (sv[w] > fv || (sv[w] == fv && si[w] < fi)) { fv = sv[w]; fi = si[w]; }
            wi_s = fi;
            val_out[k] = fv - lse;
            idxf_out[k] = (float)fi;
            if (idxi_out) idxi_out[k] = fi;
        }
        __syncthreads();
        const int wi = wi_s;
        if (wi == t) v0 = -INFINITY;
        else if (wi == t + 256) v1 = -INFINITY;
        __syncthreads();
    }
}

__global__ void k_softmax_start(const float* __restrict__ sm, float* __restrict__ sp,
                                float* __restrict__ dout, int* __restrict__ idx) {
    const int b = blockIdx.x;
    softmax_topk<true>(sm + (size_t)b * SS, sp + (size_t)b * SS,
                       dout + b * KT, dout + 80 + b * KT, idx + b * KT);
}

__global__ void k_softmax_end(const float* __restrict__ em, float* __restrict__ dout) {
    const int bk = blockIdx.x;  // b*KT + k
    const int b = bk / KT, k = bk % KT;
    softmax_topk<false>(em + (size_t)bk * SS, nullptr,
                        dout + 160 + b * 25 + k * KT, dout + 560 + b * 25 + k * KT, nullptr);
}

// ---------------- kernel 3a: start_feature partial sums ----------------
__global__ void k_sf_partial(const float* __restrict__ seq, const float* __restrict__ sp,
                             float* __restrict__ partial) {
    const int chunk = blockIdx.x;  // 0..7
    const int b = blockIdx.y;
    const int t = threadIdx.x;
    __shared__ float p[64];
    if (t < 64) p[t] = sp[b * SS + chunk * 64 + t];
    __syncthreads();
    float4 acc = make_float4(0.f, 0.f, 0.f, 0.f);
    const float4* base = (const float4*)(seq + ((size_t)b * SS + chunk * 64) * HH);
    for (int s = 0; s < 64; ++s) {
        float4 v = base[(size_t)s * 256 + t];
        float ps = p[s];
        acc.x = fmaf(ps, v.x, acc.x);
        acc.y = fmaf(ps, v.y, acc.y);
        acc.z = fmaf(ps, v.z, acc.z);
        acc.w = fmaf(ps, v.w, acc.w);
    }
    ((float4*)partial)[(size_t)(b * 8 + chunk) * 256 + t] = acc;
}

// ---------------- kernel 3b: ans head + cls_logits ----------------
__global__ void k_ans(const float* __restrict__ seq, const float* __restrict__ partial,
                      const float* __restrict__ w_ans0, const float* __restrict__ b_ans0,
                      const float* __restrict__ w_ans1, float* __restrict__ out) {
    __shared__ float feat[2 * HH];
    __shared__ float scr[4];
    const int b = blockIdx.x, t = threadIdx.x;
    float4 a = make_float4(0.f, 0.f, 0.f, 0.f);
    for (int c = 0; c < 8; ++c) {
        float4 v = ((const float4*)partial)[(size_t)(b * 8 + c) * 256 + t];
        a.x += v.x; a.y += v.y; a.z += v.z; a.w += v.w;
    }
    ((float4*)feat)[t] = a;
    ((float4*)feat)[256 + t] = ((const float4*)(seq + (size_t)b * SS * HH))[t];  // cls row s=0
    __syncthreads();
    float4 acc = ((const float4*)b_ans0)[t];
    const float4* W4 = (const float4*)w_ans0;  // row stride 256 float4
    for (int d4 = 0; d4 < 512; ++d4) {
        float4 f = ((const float4*)feat)[d4];
        float4 w0 = W4[(size_t)(d4 * 4 + 0) * 256 + t];
        float4 w1 = W4[(size_t)(d4 * 4 + 1) * 256 + t];
        float4 w2 = W4[(size_t)(d4 * 4 + 2) * 256 + t];
        float4 w3 = W4[(size_t)(d4 * 4 + 3) * 256 + t];
        acc.x = fmaf(f.x, w0.x, fmaf(f.y, w1.x, fmaf(f.z, w2.x, fmaf(f.w, w3.x, acc.x))));
        acc.y = fmaf(f.x, w0.y, fmaf(f.y, w1.y, fmaf(f.z, w2.y, fmaf(f.w, w3.y, acc.y))));
        acc.z = fmaf(f.x, w0.z, fmaf(f.y, w1.z, fmaf(f.z, w2.z, fmaf(f.w, w3.z, acc.z))));
        acc.w = fmaf(f.x, w0.w, fmaf(f.y, w1.w, fmaf(f.z, w2.w, fmaf(f.w, w3.w, acc.w))));
    }
    acc.x = tanhf(acc.x);
    acc.y = tanhf(acc.y);
    acc.z = tanhf(acc.z);
    acc.w = tanhf(acc.w);
    float4 w1v = ((const float4*)w_ans1)[t];
    float dsum = acc.x * w1v.x + acc.y * w1v.y + acc.z * w1v.z + acc.w * w1v.w;
    dsum = wave_sum(dsum);
    if ((t & 63) == 0) scr[t >> 6] = dsum;
    __syncthreads();
    if (t == 0) out[960 + b] = scr[0] + scr[1] + scr[2] + scr[3];
}

// ---------------- kernel 4: C[b,k,h] = start_feature @ W0b + b_end0 ----------------
__global__ void k_cfeat(const float* __restrict__ seq, const int* __restrict__ idx,
                        const float* __restrict__ w_end0, const float* __restrict__ b_end0,
                        float* __restrict__ Cb) {
    __shared__ float feat[HH];
    const int bk = blockIdx.x, t = threadIdx.x;
    const int b = bk / KT;
    const int id = idx[bk];
    ((float4*)feat)[t] = ((const float4*)(seq + ((size_t)b * SS + id) * HH))[t];
    __syncthreads();
    float4 acc = ((const float4*)b_end0)[t];
    const float4* W4 = (const float4*)(w_end0 + (size_t)HH * HH);  // second-half rows
    for (int d4 = 0; d4 < 256; ++d4) {
        float4 f = ((const float4*)feat)[d4];
        float4 w0 = W4[(size_t)(d4 * 4 + 0) * 256 + t];
        float4 w1 = W4[(size_t)(d4 * 4 + 1) * 256 + t];
        float4 w2 = W4[(size_t)(d4 * 4 + 2) * 256 + t];
        float4 w3 = W4[(size_t)(d4 * 4 + 3) * 256 + t];
        acc.x = fmaf(f.x, w0.x, fmaf(f.y, w1.x, fmaf(f.z, w2.x, fmaf(f.w, w3.x, acc.x))));
        acc.y = fmaf(f.x, w0.y, fmaf(f.y, w1.y, fmaf(f.z, w2.y, fmaf(f.w, w3.y, acc.y))));
        acc.z = fmaf(f.x, w0.z, fmaf(f.y, w1.z, fmaf(f.z, w2.z, fmaf(f.w, w3.z, acc.z))));
        acc.w = fmaf(f.x, w0.w, fmaf(f.y, w1.w, fmaf(f.z, w2.w, fmaf(f.w, w3.w, acc.w))));
    }
    ((float4*)(Cb + (size_t)bk * HH))[t] = acc;
}

// ---------------- kernel 5: big fused GEMM + tanh + LN + dot + mask ----------------
__launch_bounds__(256, 2)
__global__ void k_end(const float* __restrict__ seq, const float* __restrict__ w_end0,
                      const float* __restrict__ Cb, const float* __restrict__ ln_g,
                      const float* __restrict__ ln_b, const float* __restrict__ w_end1,
                      const float* __restrict__ b_end1, const float* __restrict__ p_mask,
                      float* __restrict__ em) {
    __shared__ float lds[TM * HH];  // 64 KB; reused as reduction scratch in epilogue
    const int t = threadIdx.x;
    const int blk = blockIdx.x;
    const int row0 = blk * TM;
    const int b = row0 / SS;

    // stage TM rows of seq into LDS (contiguous 64KB copy)
    {
        const float4* gsrc = (const float4*)(seq + (size_t)row0 * HH);
        float4* l4 = (float4*)lds;
#pragma unroll
        for (int i = 0; i < TM; ++i) l4[i * 256 + t] = gsrc[(size_t)i * 256 + t];
    }
    __syncthreads();

    float4 acc[TM];
#pragma unroll
    for (int r = 0; r < TM; ++r) acc[r] = make_float4(0.f, 0.f, 0.f, 0.f);

    const float4* W4 = (const float4*)w_end0;  // first-half rows, stride 256 float4
    const float4* l4 = (const float4*)lds;
    for (int d4 = 0; d4 < 256; ++d4) {
        const int dbase = d4 * 4;
        float4 w0 = W4[(size_t)(dbase + 0) * 256 + t];
        float4 w1 = W4[(size_t)(dbase + 1) * 256 + t];
        float4 w2 = W4[(size_t)(dbase + 2) * 256 + t];
        float4 w3 = W4[(size_t)(dbase + 3) * 256 + t];
#pragma unroll
        for (int r = 0; r < TM; ++r) {
            float4 a = l4[r * 256 + d4];
            acc[r].x = fmaf(a.x, w0.x, fmaf(a.y, w1.x, fmaf(a.z, w2.x, fmaf(a.w, w3.x, acc[r].x))));
            acc[r].y = fmaf(a.x, w0.y, fmaf(a.y, w1.y, fmaf(a.z, w2.y, fmaf(a.w, w3.y, acc[r].y))));
            acc[r].z = fmaf(a.x, w0.z, fmaf(a.y, w1.z, fmaf(a.z, w2.z, fmaf(a.w, w3.z, acc[r].z))));
            acc[r].w = fmaf(a.x, w0.w, fmaf(a.y, w1.w, fmaf(a.z, w2.w, fmaf(a.w, w3.w, acc[r].w))));
        }
    }
    __syncthreads();  // done with staged seq; lds becomes scratch

    // epilogue
    float4 cb[KT];
#pragma unroll
    for (int k = 0; k < KT; ++k) cb[k] = ((const float4*)(Cb + (size_t)(b * KT + k) * HH))[t];
    const float4 g = ((const float4*)ln_g)[t];
    const float4 bb = ((const float4*)ln_b)[t];
    const float4 w1v = ((const float4*)w_end1)[t];
    const float be1 = b_end1[0];
    const int lane = t & 63, wave = t >> 6;

#pragma unroll
    for (int r = 0; r < TM; ++r) {
        const int srow = row0 + r;
        float vs[KT][4];
        float s_[KT], q_[KT];
#pragma unroll
        for (int k = 0; k < KT; ++k) {
            float v0 = tanhf(acc[r].x + cb[k].x);
            float v1 = tanhf(acc[r].y + cb[k].y);
            float v2 = tanhf(acc[r].z + cb[k].z);
            float v3 = tanhf(acc[r].w + cb[k].w);
            vs[k][0] = v0; vs[k][1] = v1; vs[k][2] = v2; vs[k][3] = v3;
            s_[k] = v0 + v1 + v2 + v3;
            q_[k] = v0 * v0 + v1 * v1 + v2 * v2 + v3 * v3;
        }
        for (int off = 32; off; off >>= 1) {
#pragma unroll
            for (int k = 0; k < KT; ++k) {
                s_[k] += __shfl_down(s_[k], off);
                q_[k] += __shfl_down(q_[k], off);
            }
        }
        if (lane == 0) {
#pragma unroll
            for (int k = 0; k < KT; ++k) {
                lds[wave * KT + k] = s_[k];
                lds[32 + wave * KT + k] = q_[k];
            }
        }
        __syncthreads();
        float d_[KT];
#pragma unroll
        for (int k = 0; k < KT; ++k) {
            float Ssum = lds[k] + lds[KT + k] + lds[2 * KT + k] + lds[3 * KT + k];
            float Qsum = lds[32 + k] + lds[32 + KT + k] + lds[32 + 2 * KT + k] + lds[32 + 3 * KT + k];
            float mu = Ssum * (1.f / HH);
            float var = Qsum * (1.f / HH) - mu * mu;
            float rs = rsqrtf(var + 1e-12f);
            float dsum = 0.f;
            dsum += ((vs[k][0] - mu) * rs * g.x + bb.x) * w1v.x;
            dsum += ((vs[k][1] - mu) * rs * g.y + bb.y) * w1v.y;
            dsum += ((vs[k][2] - mu) * rs * g.z + bb.z) * w1v.z;
            dsum += ((vs[k][3] - mu) * rs * g.w + bb.w) * w1v.w;
            d_[k] = dsum;
        }
        __syncthreads();  // before reusing lds for dot reduction
        for (int off = 32; off; off >>= 1) {
#pragma unroll
            for (int k = 0; k < KT; ++k) d_[k] += __shfl_down(d_[k], off);
        }
        if (lane == 0) {
#pragma unroll
            for (int k = 0; k < KT; ++k) lds[wave * KT + k] = d_[k];
        }
        __syncthreads();
        if (t == 0) {
            const float pm = p_mask[srow];
            const int ss = srow & (SS - 1);
#pragma unroll
            for (int k = 0; k < KT; ++k) {
                float L = lds[k] + lds[KT + k] + lds[2 * KT + k] + lds[3 * KT + k] + be1;
                em[(size_t)(b * KT + k) * SS + ss] = L * (1.f - pm) - NEGV * pm;
            }
        }
        __syncthreads();
    }
}

// ---------------- launch ----------------
extern "C" void kernel_launch(void* const* d_in, const int* in_sizes, int n_in,
                              void* d_out, int out_size, void* d_ws, size_t ws_size,
                              hipStream_t stream) {
    const float* seq     = (const float*)d_in[0];
    const float* p_mask  = (const float*)d_in[1];
    const float* w_start = (const float*)d_in[2];
    const float* b_start = (const float*)d_in[3];
    const float* w_end0  = (const float*)d_in[4];
    const float* b_end0  = (const float*)d_in[5];
    const float* ln_g    = (const float*)d_in[6];
    const float* ln_b    = (const float*)d_in[7];
    const float* w_end1  = (const float*)d_in[8];
    const float* b_end1  = (const float*)d_in[9];
    const float* w_ans0  = (const float*)d_in[10];
    const float* b_ans0  = (const float*)d_in[11];
    const float* w_ans1  = (const float*)d_in[12];
    float* out = (float*)d_out;

    float* ws = (float*)d_ws;
    float* sm      = ws;                        // B*S
    float* sp      = sm + BB * SS;              // B*S
    float* partial = sp + BB * SS;              // B*8*H
    float* Cb      = partial + BB * 8 * HH;     // B*KT*H
    float* em      = Cb + BB * KT * HH;         // B*KT*S
    int*   idx     = (int*)(em + BB * KT * SS); // B*KT ints

    hipLaunchKernelGGL(k_start_logits, dim3(BB * SS), dim3(256), 0, stream,
                       seq, p_mask, w_start, b_start, sm);
    hipLaunchKernelGGL(k_softmax_start, dim3(BB), dim3(256), 0, stream, sm, sp, out, idx);
    hipLaunchKernelGGL(k_sf_partial, dim3(8, BB), dim3(256), 0, stream, seq, sp, partial);
    hipLaunchKernelGGL(k_ans, dim3(BB), dim3(256), 0, stream,
                       seq, partial, w_ans0, b_ans0, w_ans1, out);
    hipLaunchKernelGGL(k_cfeat, dim3(BB * KT), dim3(256), 0, stream,
                       seq, idx, w_end0, b_end0, Cb);
    hipLaunchKernelGGL(k_end, dim3(BB * SS / TM), dim3(256), 0, stream,
                       seq, w_end0, Cb, ln_g, ln_b, w_end1, b_end1, p_mask, em);
    hipLaunchKernelGGL(k_softmax_end, dim3(BB * KT), dim3(256), 0, stream, em, out);
}

// Round 2
// 351.771 us; speedup vs baseline: 1.8551x; 1.8551x over previous
//
#include <hip/hip_runtime.h>
#include <math.h>

#define BB 16
#define SS 512
#define HH 1024
#define KT 5
#define NEGV 1e30f

typedef __attribute__((ext_vector_type(8))) short short8_t;
typedef __attribute__((ext_vector_type(4))) float f32x4;

// ---------------- helpers ----------------
__device__ __forceinline__ float wave_sum(float v) {
    for (int off = 32; off; off >>= 1) v += __shfl_down(v, off);
    return v;
}

__device__ __forceinline__ unsigned short bf16rn(float x) {
    unsigned u = __float_as_uint(x);
    return (unsigned short)((u + 0x7fffu + ((u >> 16) & 1u)) >> 16);
}

__device__ __forceinline__ void split2(float x, unsigned short& h, unsigned short& l) {
    h = bf16rn(x);
    float hf = __uint_as_float(((unsigned)h) << 16);
    l = bf16rn(x - hf);
}

__device__ __forceinline__ float tanh_fast(float x) {
    float e = __expf(2.0f * x);
    return 1.0f - 2.0f * __builtin_amdgcn_rcpf(e + 1.0f);
}

// ---------------- k_prep: pack W0a into MFMA B-frag order (hi/lo) + LN scalars ----------------
// Wpk layout: [ntile(64)][kblk(32)][lane(64)][8] bf16; lane l of frag holds
// B[kblk*32 + (l>>4)*8 + j][ntile*16 + (l&15)].
__global__ void k_prep(const float* __restrict__ w_end0, const float* __restrict__ ln_g,
                       const float* __restrict__ ln_b, const float* __restrict__ w_end1,
                       short* __restrict__ wpk_hi, short* __restrict__ wpk_lo,
                       float* __restrict__ scal) {
    const int t = threadIdx.x;
    if (blockIdx.x == 64) {
        // scalars: GW1 = sum g*w1, BW1 = sum b*w1
        __shared__ float scr[8];
        float4 g = ((const float4*)ln_g)[t];
        float4 w = ((const float4*)w_end1)[t];
        float4 b = ((const float4*)ln_b)[t];
        float gw = g.x * w.x + g.y * w.y + g.z * w.z + g.w * w.w;
        float bw = b.x * w.x + b.y * w.y + b.z * w.z + b.w * w.w;
        gw = wave_sum(gw);
        bw = wave_sum(bw);
        if ((t & 63) == 0) { scr[t >> 6] = gw; scr[4 + (t >> 6)] = bw; }
        __syncthreads();
        if (t == 0) {
            scal[0] = scr[0] + scr[1] + scr[2] + scr[3];
            scal[1] = scr[4] + scr[5] + scr[6] + scr[7];
        }
        return;
    }
    const int nt = blockIdx.x;      // 0..63 n-tile
    const int n_idx = t & 15;
    const int g = (t >> 4) & 3;     // k-group within kblk
    const int kq = t >> 6;          // which kblk of 4 per iter
    for (int it = 0; it < 8; ++it) {
        const int kblk = it * 4 + kq;
        const int k0 = kblk * 32 + g * 8;
        unsigned short hs[8], ls[8];
#pragma unroll
        for (int j = 0; j < 8; ++j) {
            float v = w_end0[(size_t)(k0 + j) * HH + nt * 16 + n_idx];
            split2(v, hs[j], ls[j]);
        }
        const size_t fi = (((size_t)nt * 32 + kblk) * 64 + (g * 16 + n_idx)) * 8;
        short8_t hv, lv;
#pragma unroll
        for (int j = 0; j < 8; ++j) { hv[j] = (short)hs[j]; lv[j] = (short)ls[j]; }
        *(short8_t*)(wpk_hi + fi) = hv;
        *(short8_t*)(wpk_lo + fi) = lv;
    }
}

// ---------------- kernel 1: start logits + mask (wave per row) ----------------
__global__ void k_start_logits(const float* __restrict__ seq, const float* __restrict__ pm,
                               const float* __restrict__ w_start, const float* __restrict__ b_start,
                               float* __restrict__ sm) {
    const int t = threadIdx.x;
    const int l = t & 63;
    const int row = blockIdx.x * 4 + (t >> 6);
    const float4* rp = (const float4*)(seq + (size_t)row * HH);
    const float4* wp = (const float4*)w_start;
    float d = 0.f;
#pragma unroll
    for (int q = 0; q < 4; ++q) {
        float4 a = rp[q * 64 + l];
        float4 w = wp[q * 64 + l];
        d += a.x * w.x + a.y * w.y + a.z * w.z + a.w * w.w;
    }
    d = wave_sum(d);
    if (l == 0) {
        float m = pm[row];
        sm[row] = (d + b_start[0]) * (1.f - m) - NEGV * m;
    }
}

// ---------------- softmax + top-5 over 512 values (one block, 256 thr) ----------------
template <bool WRITE_P>
__device__ void softmax_topk(const float* __restrict__ x, float* __restrict__ p_out,
                             float* __restrict__ val_out, float* __restrict__ idxf_out,
                             int* __restrict__ idxi_out) {
    const int t = threadIdx.x;
    __shared__ float scr[4];
    __shared__ float sv[4];
    __shared__ int si[4];
    __shared__ int wi_s;
    float x0 = x[t], x1 = x[t + 256];

    float m = fmaxf(x0, x1);
    for (int off = 32; off; off >>= 1) m = fmaxf(m, __shfl_down(m, off));
    if ((t & 63) == 0) scr[t >> 6] = m;
    __syncthreads();
    m = fmaxf(fmaxf(scr[0], scr[1]), fmaxf(scr[2], scr[3]));
    __syncthreads();

    float e0 = expf(x0 - m), e1 = expf(x1 - m);
    float ssum = wave_sum(e0 + e1);
    if ((t & 63) == 0) scr[t >> 6] = ssum;
    __syncthreads();
    ssum = scr[0] + scr[1] + scr[2] + scr[3];
    __syncthreads();

    if (WRITE_P) {
        p_out[t] = e0 / ssum;
        p_out[t + 256] = e1 / ssum;
    }
    const float lse = m + logf(ssum);

    float v0 = x0, v1 = x1;
    for (int k = 0; k < KT; ++k) {
        float bv;
        int bi;
        if (v0 >= v1) { bv = v0; bi = t; } else { bv = v1; bi = t + 256; }
        for (int off = 32; off; off >>= 1) {
            float ov = __shfl_down(bv, off);
            int oi = __shfl_down(bi, off);
            if (ov > bv || (ov == bv && oi < bi)) { bv = ov; bi = oi; }
        }
        if ((t & 63) == 0) { sv[t >> 6] = bv; si[t >> 6] = bi; }
        __syncthreads();
        if (t == 0) {
            float fv = sv[0];
            int fi = si[0];
            for (int w = 1; w < 4; ++w)
                if (sv[w] > fv || (sv[w] == fv && si[w] < fi)) { fv = sv[w]; fi = si[w]; }
            wi_s = fi;
            val_out[k] = fv - lse;
            idxf_out[k] = (float)fi;
            if (idxi_out) idxi_out[k] = fi;
        }
        __syncthreads();
        const int wi = wi_s;
        if (wi == t) v0 = -INFINITY;
        else if (wi == t + 256) v1 = -INFINITY;
        __syncthreads();
    }
}

__global__ void k_softmax_start(const float* __restrict__ sm, float* __restrict__ sp,
                                float* __restrict__ dout, int* __restrict__ idx) {
    const int b = blockIdx.x;
    softmax_topk<true>(sm + (size_t)b * SS, sp + (size_t)b * SS,
                       dout + b * KT, dout + 80 + b * KT, idx + b * KT);
}

__global__ void k_softmax_end(const float* __restrict__ em, float* __restrict__ dout) {
    const int bk = blockIdx.x;
    const int b = bk / KT, k = bk % KT;
    softmax_topk<false>(em + (size_t)bk * SS, nullptr,
                        dout + 160 + b * 25 + k * KT, dout + 560 + b * 25 + k * KT, nullptr);
}

// ---------------- start_feature partial sums (32-row chunks) ----------------
__global__ void k_sf_partial(const float* __restrict__ seq, const float* __restrict__ sp,
                             float* __restrict__ partial) {
    const int chunk = blockIdx.x;  // 0..15
    const int b = blockIdx.y;
    const int t = threadIdx.x;
    __shared__ float p[32];
    if (t < 32) p[t] = sp[b * SS + chunk * 32 + t];
    __syncthreads();
    float4 acc = make_float4(0.f, 0.f, 0.f, 0.f);
    const float4* base = (const float4*)(seq + ((size_t)b * SS + chunk * 32) * HH);
    for (int s = 0; s < 32; ++s) {
        float4 v = base[(size_t)s * 256 + t];
        float ps = p[s];
        acc.x = fmaf(ps, v.x, acc.x);
        acc.y = fmaf(ps, v.y, acc.y);
        acc.z = fmaf(ps, v.z, acc.z);
        acc.w = fmaf(ps, v.w, acc.w);
    }
    ((float4*)partial)[(size_t)(b * 16 + chunk) * 256 + t] = acc;
}

// ---------------- k_featsum: feat[b][0:1024]=start_feature, [1024:2048]=cls; zero cls out ----------------
__global__ void k_featsum(const float* __restrict__ seq, const float* __restrict__ partial,
                          float* __restrict__ feat, float* __restrict__ out) {
    const int b = blockIdx.x, t = threadIdx.x;
    for (int q = 0; q < 4; ++q) {
        const int h = q * 256 + t;
        float s = 0.f;
        for (int c = 0; c < 16; ++c) s += partial[(size_t)(b * 16 + c) * HH + h];
        feat[(size_t)b * 2048 + h] = s;
        feat[(size_t)b * 2048 + HH + h] = seq[(size_t)b * SS * HH + h];
    }
    if (t == 0) out[960 + b] = 0.f;
}

// ---------------- k_ans: ans head, column-chunked ----------------
__global__ void k_ans(const float* __restrict__ feat, const float* __restrict__ w_ans0,
                      const float* __restrict__ b_ans0, const float* __restrict__ w_ans1,
                      float* __restrict__ out) {
    __shared__ float featsL[16 * 129];
    __shared__ float WL[128 * 16];
    const int c = blockIdx.x;  // 64 n-chunks of 16
    const int t = threadIdx.x;
    const int j = t & 15, b = t >> 4;
    float acc = 0.f;
    for (int dc = 0; dc < 16; ++dc) {
#pragma unroll
        for (int i = 0; i < 8; ++i) {
            const int e = i * 256 + t;
            const int br = e >> 7, d = e & 127;
            featsL[br * 129 + d] = feat[(size_t)br * 2048 + dc * 128 + d];
        }
#pragma unroll
        for (int p = 0; p < 8; ++p) {
            const int d = p * 16 + (t >> 4);
            WL[d * 16 + (t & 15)] = w_ans0[(size_t)(dc * 128 + d) * HH + c * 16 + (t & 15)];
        }
        __syncthreads();
        for (int d = 0; d < 128; ++d)
            acc = fmaf(featsL[b * 129 + d], WL[d * 16 + j], acc);
        __syncthreads();
    }
    float a = tanhf(acc + b_ans0[c * 16 + j]);
    float part = a * w_ans1[c * 16 + j];
    for (int m = 1; m < 16; m <<= 1) part += __shfl_xor(part, m);
    if (j == 0) atomicAdd(&out[960 + b], part);
}

// ---------------- k_cfeat: Cb[bk][h] = start_feature(bk) @ W0b + b_end0, column-chunked ----------------
__global__ void k_cfeat(const float* __restrict__ seq, const int* __restrict__ idx,
                        const float* __restrict__ w_end0, const float* __restrict__ b_end0,
                        float* __restrict__ Cb) {
    __shared__ float featsL[80 * 65];
    __shared__ float WL[64 * 16];
    __shared__ int growL[80];
    const int c = blockIdx.x;  // 64 n-chunks
    const int t = threadIdx.x;
    const int j = t & 15, rg = t >> 4;
    if (t < 80) growL[t] = (t / KT) * SS + idx[t];
    float acc[5] = {0.f, 0.f, 0.f, 0.f, 0.f};
    for (int dc = 0; dc < 16; ++dc) {
        __syncthreads();
#pragma unroll
        for (int i = 0; i < 20; ++i) {
            const int e = i * 256 + t;
            const int r = e >> 6, d = e & 63;
            featsL[r * 65 + d] = seq[(size_t)growL[r] * HH + dc * 64 + d];
        }
#pragma unroll
        for (int p = 0; p < 4; ++p) {
            const int d = p * 16 + (t >> 4);
            WL[d * 16 + (t & 15)] = w_end0[(size_t)(HH + dc * 64 + d) * HH + c * 16 + (t & 15)];
        }
        __syncthreads();
        for (int d = 0; d < 64; ++d) {
            const float wv = WL[d * 16 + j];
#pragma unroll
            for (int i = 0; i < 5; ++i)
                acc[i] = fmaf(featsL[(rg + 16 * i) * 65 + d], wv, acc[i]);
        }
    }
    const float bias = b_end0[c * 16 + j];
#pragma unroll
    for (int i = 0; i < 5; ++i)
        Cb[(size_t)(rg + 16 * i) * HH + c * 16 + j] = acc[i] + bias;
}

// ---------------- k_end: MFMA split-bf16 GEMM + tanh + LN + dot + mask ----------------
__launch_bounds__(512, 2)
__global__ void k_end(const float* __restrict__ seq, const short* __restrict__ wpk_hi,
                      const short* __restrict__ wpk_lo, const float* __restrict__ Cb,
                      const float* __restrict__ ln_g, const float* __restrict__ w_end1,
                      const float* __restrict__ b_end1, const float* __restrict__ p_mask,
                      const float* __restrict__ scal, float* __restrict__ em) {
    extern __shared__ char smem[];  // 128KB: A_hi[32][1024] bf16 (swizzled), A_lo at +64KB
    const int t = threadIdx.x;
    const int l = t & 63, w = t >> 6;
    const int row0 = blockIdx.x * 32;
    const int b = row0 >> 9;

    // ---- stage seq rows as hi/lo bf16 into LDS with XOR swizzle ----
    {
        const float4* gp = (const float4*)(seq + (size_t)row0 * HH);
        const int f4 = t & 255;
#pragma unroll
        for (int i = 0; i < 16; ++i) {
            const int row = (i << 1) | (t >> 8);
            float4 v = gp[(size_t)row * 256 + f4];
            unsigned short h0, l0, h1, l1, h2, l2, h3, l3;
            split2(v.x, h0, l0);
            split2(v.y, h1, l1);
            split2(v.z, h2, l2);
            split2(v.w, h3, l3);
            const int boff = (row * 2048 + f4 * 8) ^ ((row & 7) << 4);
            *(short4*)(smem + boff) = make_short4((short)h0, (short)h1, (short)h2, (short)h3);
            *(short4*)(smem + 65536 + boff) = make_short4((short)l0, (short)l1, (short)l2, (short)l3);
        }
    }
    __syncthreads();

    // ---- MFMA GEMM: acc[mh][nt] covers rows mh*16+(frag rows), cols w*128 + nt*16 ----
    f32x4 acc[2][8];
#pragma unroll
    for (int m = 0; m < 2; ++m)
#pragma unroll
        for (int n = 0; n < 8; ++n) acc[m][n] = (f32x4){0.f, 0.f, 0.f, 0.f};

    const int g = l >> 4;
    const int off0 = (l & 15) * 2048 + g * 16;
    const int off1 = off0 + 16 * 2048;
    const int swz = (l & 7) << 4;
    const short8_t* WH = (const short8_t*)wpk_hi;
    const short8_t* WLo = (const short8_t*)wpk_lo;
    const size_t wbase = (size_t)w * 8 * 2048 + l;

    for (int kb = 0; kb < 32; ++kb) {
        const int ko = kb * 64;
        short8_t ah0 = *(const short8_t*)(smem + ((off0 + ko) ^ swz));
        short8_t al0 = *(const short8_t*)(smem + 65536 + ((off0 + ko) ^ swz));
        short8_t ah1 = *(const short8_t*)(smem + ((off1 + ko) ^ swz));
        short8_t al1 = *(const short8_t*)(smem + 65536 + ((off1 + ko) ^ swz));
#pragma unroll
        for (int nt = 0; nt < 8; ++nt) {
            const size_t wi = wbase + (size_t)nt * 2048 + kb * 64;
            short8_t bh = WH[wi];
            short8_t bl = WLo[wi];
            acc[0][nt] = __builtin_amdgcn_mfma_f32_16x16x32_bf16(ah0, bh, acc[0][nt], 0, 0, 0);
            acc[1][nt] = __builtin_amdgcn_mfma_f32_16x16x32_bf16(ah1, bh, acc[1][nt], 0, 0, 0);
            acc[0][nt] = __builtin_amdgcn_mfma_f32_16x16x32_bf16(al0, bh, acc[0][nt], 0, 0, 0);
            acc[1][nt] = __builtin_amdgcn_mfma_f32_16x16x32_bf16(al1, bh, acc[1][nt], 0, 0, 0);
            acc[0][nt] = __builtin_amdgcn_mfma_f32_16x16x32_bf16(ah0, bl, acc[0][nt], 0, 0, 0);
            acc[1][nt] = __builtin_amdgcn_mfma_f32_16x16x32_bf16(ah1, bl, acc[1][nt], 0, 0, 0);
        }
    }
    __syncthreads();  // all A reads done; LDS becomes scratch

    // ---- fused epilogue: tanh + LN (3 sums) + dot(w_end1) + mask ----
    float* scr = (float*)smem;  // [8 waves][32 rows][5 k][3]
    float gw[8];
#pragma unroll
    for (int nt = 0; nt < 8; ++nt) {
        const int col = (w * 8 + nt) * 16 + (l & 15);
        gw[nt] = ln_g[col] * w_end1[col];
    }

    for (int k = 0; k < KT; ++k) {
        float S[2][4], Q[2][4], G[2][4];
#pragma unroll
        for (int m = 0; m < 2; ++m)
#pragma unroll
            for (int r = 0; r < 4; ++r) { S[m][r] = 0.f; Q[m][r] = 0.f; G[m][r] = 0.f; }
#pragma unroll
        for (int nt = 0; nt < 8; ++nt) {
            const int col = (w * 8 + nt) * 16 + (l & 15);
            const float cb = Cb[((size_t)(b * KT + k) << 10) + col];
            const float gwv = gw[nt];
#pragma unroll
            for (int m = 0; m < 2; ++m) {
#pragma unroll
                for (int r = 0; r < 4; ++r) {
                    float v = tanh_fast(acc[m][nt][r] + cb);
                    S[m][r] += v;
                    Q[m][r] += v * v;
                    G[m][r] += v * gwv;
                }
            }
        }
        for (int msk = 1; msk < 16; msk <<= 1) {
#pragma unroll
            for (int m = 0; m < 2; ++m)
#pragma unroll
                for (int r = 0; r < 4; ++r) {
                    S[m][r] += __shfl_xor(S[m][r], msk);
                    Q[m][r] += __shfl_xor(Q[m][r], msk);
                    G[m][r] += __shfl_xor(G[m][r], msk);
                }
        }
        if ((l & 15) == 0) {
            const int gg = l >> 4;
#pragma unroll
            for (int m = 0; m < 2; ++m)
#pragma unroll
                for (int r = 0; r < 4; ++r) {
                    const int row = m * 16 + gg * 4 + r;
                    float* sp_ = scr + ((size_t)(w * 32 + row) * KT + k) * 3;
                    sp_[0] = S[m][r];
                    sp_[1] = Q[m][r];
                    sp_[2] = G[m][r];
                }
        }
    }
    __syncthreads();

    if (t < 32 * KT) {
        const int row = t / KT, k = t % KT;
        float S = 0.f, Q = 0.f, G = 0.f;
#pragma unroll
        for (int ww = 0; ww < 8; ++ww) {
            const float* sp_ = scr + ((size_t)(ww * 32 + row) * KT + k) * 3;
            S += sp_[0];
            Q += sp_[1];
            G += sp_[2];
        }
        const float GW1 = scal[0], BW1 = scal[1];
        const float mu = S * (1.f / HH);
        const float var = Q * (1.f / HH) - mu * mu;
        const float rs = rsqrtf(var + 1e-12f);
        float logit = rs * (G - mu * GW1) + BW1 + b_end1[0];
        const int srow = row0 + row;
        const float pm = p_mask[srow];
        em[((size_t)(b * KT + k) << 9) + (srow & (SS - 1))] = logit * (1.f - pm) - NEGV * pm;
    }
}

// ---------------- launch ----------------
extern "C" void kernel_launch(void* const* d_in, const int* in_sizes, int n_in,
                              void* d_out, int out_size, void* d_ws, size_t ws_size,
                              hipStream_t stream) {
    const float* seq     = (const float*)d_in[0];
    const float* p_mask  = (const float*)d_in[1];
    const float* w_start = (const float*)d_in[2];
    const float* b_start = (const float*)d_in[3];
    const float* w_end0  = (const float*)d_in[4];
    const float* b_end0  = (const float*)d_in[5];
    const float* ln_g    = (const float*)d_in[6];
    const float* ln_b    = (const float*)d_in[7];
    const float* w_end1  = (const float*)d_in[8];
    const float* b_end1  = (const float*)d_in[9];
    const float* w_ans0  = (const float*)d_in[10];
    const float* b_ans0  = (const float*)d_in[11];
    const float* w_ans1  = (const float*)d_in[12];
    float* out = (float*)d_out;

    float* sm      = (float*)d_ws;                  // 8192
    float* sp      = sm + BB * SS;                  // 8192
    float* partial = sp + BB * SS;                  // 16*16*1024 = 262144
    float* feat    = partial + BB * 16 * HH;        // 16*2048 = 32768
    float* Cb      = feat + BB * 2048;              // 80*1024 = 81920
    float* em      = Cb + BB * KT * HH;             // 80*512 = 40960
    float* scal    = em + BB * KT * SS;             // 16
    int*   idx     = (int*)(scal + 16);             // 80
    short* wpk_hi  = (short*)(((uintptr_t)(idx + 80) + 255) & ~(uintptr_t)255);
    short* wpk_lo  = wpk_hi + (1 << 20);            // 1M bf16 each

    hipLaunchKernelGGL(k_prep, dim3(65), dim3(256), 0, stream,
                       w_end0, ln_g, ln_b, w_end1, wpk_hi, wpk_lo, scal);
    hipLaunchKernelGGL(k_start_logits, dim3(BB * SS / 4), dim3(256), 0, stream,
                       seq, p_mask, w_start, b_start, sm);
    hipLaunchKernelGGL(k_softmax_start, dim3(BB), dim3(256), 0, stream, sm, sp, out, idx);
    hipLaunchKernelGGL(k_sf_partial, dim3(16, BB), dim3(256), 0, stream, seq, sp, partial);
    hipLaunchKernelGGL(k_featsum, dim3(BB), dim3(256), 0, stream, seq, partial, feat, out);
    hipLaunchKernelGGL(k_ans, dim3(64), dim3(256), 0, stream,
                       feat, w_ans0, b_ans0, w_ans1, out);
    hipLaunchKernelGGL(k_cfeat, dim3(64), dim3(256), 0, stream,
                       seq, idx, w_end0, b_end0, Cb);
    hipLaunchKernelGGL(k_end, dim3(BB * SS / 32), dim3(512), 131072, stream,
                       seq, wpk_hi, wpk_lo, Cb, ln_g, w_end1, b_end1, p_mask, scal, em);
    hipLaunchKernelGGL(k_softmax_end, dim3(BB * KT), dim3(256), 0, stream, em, out);
}

// Round 3
// 195.634 us; speedup vs baseline: 3.3357x; 1.7981x over previous
//
#include <hip/hip_runtime.h>
#include <math.h>

#define BB 16
#define SS 512
#define HH 1024
#define KT 5
#define NEGV 1e30f

typedef __attribute__((ext_vector_type(8))) short short8_t;
typedef __attribute__((ext_vector_type(4))) float f32x4;

// ---------------- helpers ----------------
__device__ __forceinline__ float wave_sum(float v) {
    for (int off = 32; off; off >>= 1) v += __shfl_down(v, off);
    return v;
}

__device__ __forceinline__ unsigned short bf16rn(float x) {
    unsigned u = __float_as_uint(x);
    return (unsigned short)((u + 0x7fffu + ((u >> 16) & 1u)) >> 16);
}

__device__ __forceinline__ void split2(float x, unsigned short& h, unsigned short& l) {
    h = bf16rn(x);
    float hf = __uint_as_float(((unsigned)h) << 16);
    l = bf16rn(x - hf);
}

__device__ __forceinline__ float tanh_fast(float x) {
    float e = __expf(2.0f * x);
    return 1.0f - 2.0f * __builtin_amdgcn_rcpf(e + 1.0f);
}

// ---------------- k_prep: pack W0a into MFMA B-frag order (hi/lo) ----------------
// Wpk layout: [ntile(64)][kblk(32)][lane(64)][8] bf16; lane l holds
// B[kblk*32 + (l>>4)*8 + j][ntile*16 + (l&15)].
__global__ void k_prep(const float* __restrict__ w_end0,
                       short* __restrict__ wpk_hi, short* __restrict__ wpk_lo) {
    const int nt = blockIdx.x;      // 0..63 n-tile
    const int t = threadIdx.x;
    const int n_idx = t & 15;
    const int g = (t >> 4) & 3;     // k-group within kblk
    const int kq = t >> 6;
    const int kblk = blockIdx.y * 4 + kq;
    const int k0 = kblk * 32 + g * 8;
    unsigned short hs[8], ls[8];
#pragma unroll
    for (int j = 0; j < 8; ++j) {
        float v = w_end0[(size_t)(k0 + j) * HH + nt * 16 + n_idx];
        split2(v, hs[j], ls[j]);
    }
    const size_t fi = (((size_t)nt * 32 + kblk) * 64 + (g * 16 + n_idx)) * 8;
    short8_t hv, lv;
#pragma unroll
    for (int j = 0; j < 8; ++j) { hv[j] = (short)hs[j]; lv[j] = (short)ls[j]; }
    *(short8_t*)(wpk_hi + fi) = hv;
    *(short8_t*)(wpk_lo + fi) = lv;
}

// ---------------- k_scal: GW1 = sum g*w1, BW1 = sum b*w1 ----------------
__global__ void k_scal(const float* __restrict__ ln_g, const float* __restrict__ ln_b,
                       const float* __restrict__ w_end1, float* __restrict__ scal) {
    __shared__ float scr[8];
    const int t = threadIdx.x;
    float4 g = ((const float4*)ln_g)[t];
    float4 w = ((const float4*)w_end1)[t];
    float4 b = ((const float4*)ln_b)[t];
    float gw = g.x * w.x + g.y * w.y + g.z * w.z + g.w * w.w;
    float bw = b.x * w.x + b.y * w.y + b.z * w.z + b.w * w.w;
    gw = wave_sum(gw);
    bw = wave_sum(bw);
    if ((t & 63) == 0) { scr[t >> 6] = gw; scr[4 + (t >> 6)] = bw; }
    __syncthreads();
    if (t == 0) {
        scal[0] = scr[0] + scr[1] + scr[2] + scr[3];
        scal[1] = scr[4] + scr[5] + scr[6] + scr[7];
    }
}

// ---------------- kernel 1: start logits + mask (wave per row) ----------------
__global__ void k_start_logits(const float* __restrict__ seq, const float* __restrict__ pm,
                               const float* __restrict__ w_start, const float* __restrict__ b_start,
                               float* __restrict__ sm) {
    const int t = threadIdx.x;
    const int l = t & 63;
    const int row = blockIdx.x * 4 + (t >> 6);
    const float4* rp = (const float4*)(seq + (size_t)row * HH);
    const float4* wp = (const float4*)w_start;
    float d = 0.f;
#pragma unroll
    for (int q = 0; q < 4; ++q) {
        float4 a = rp[q * 64 + l];
        float4 w = wp[q * 64 + l];
        d += a.x * w.x + a.y * w.y + a.z * w.z + a.w * w.w;
    }
    d = wave_sum(d);
    if (l == 0) {
        float m = pm[row];
        sm[row] = (d + b_start[0]) * (1.f - m) - NEGV * m;
    }
}

// ---------------- softmax + top-5 over 512 values (one block, 256 thr) ----------------
template <bool WRITE_P>
__device__ void softmax_topk(const float* __restrict__ x, float* __restrict__ p_out,
                             float* __restrict__ val_out, float* __restrict__ idxf_out,
                             int* __restrict__ idxi_out) {
    const int t = threadIdx.x;
    __shared__ float scr[4];
    __shared__ float sv[4];
    __shared__ int si[4];
    __shared__ int wi_s;
    float x0 = x[t], x1 = x[t + 256];

    float m = fmaxf(x0, x1);
    for (int off = 32; off; off >>= 1) m = fmaxf(m, __shfl_down(m, off));
    if ((t & 63) == 0) scr[t >> 6] = m;
    __syncthreads();
    m = fmaxf(fmaxf(scr[0], scr[1]), fmaxf(scr[2], scr[3]));
    __syncthreads();

    float e0 = expf(x0 - m), e1 = expf(x1 - m);
    float ssum = wave_sum(e0 + e1);
    if ((t & 63) == 0) scr[t >> 6] = ssum;
    __syncthreads();
    ssum = scr[0] + scr[1] + scr[2] + scr[3];
    __syncthreads();

    if (WRITE_P) {
        p_out[t] = e0 / ssum;
        p_out[t + 256] = e1 / ssum;
    }
    const float lse = m + logf(ssum);

    float v0 = x0, v1 = x1;
    for (int k = 0; k < KT; ++k) {
        float bv;
        int bi;
        if (v0 >= v1) { bv = v0; bi = t; } else { bv = v1; bi = t + 256; }
        for (int off = 32; off; off >>= 1) {
            float ov = __shfl_down(bv, off);
            int oi = __shfl_down(bi, off);
            if (ov > bv || (ov == bv && oi < bi)) { bv = ov; bi = oi; }
        }
        if ((t & 63) == 0) { sv[t >> 6] = bv; si[t >> 6] = bi; }
        __syncthreads();
        if (t == 0) {
            float fv = sv[0];
            int fi = si[0];
            for (int w = 1; w < 4; ++w)
                if (sv[w] > fv || (sv[w] == fv && si[w] < fi)) { fv = sv[w]; fi = si[w]; }
            wi_s = fi;
            val_out[k] = fv - lse;
            idxf_out[k] = (float)fi;
            if (idxi_out) idxi_out[k] = fi;
        }
        __syncthreads();
        const int wi = wi_s;
        if (wi == t) v0 = -INFINITY;
        else if (wi == t + 256) v1 = -INFINITY;
        __syncthreads();
    }
}

__global__ void k_softmax_start(const float* __restrict__ sm, float* __restrict__ sp,
                                float* __restrict__ dout, int* __restrict__ idx) {
    const int b = blockIdx.x;
    softmax_topk<true>(sm + (size_t)b * SS, sp + (size_t)b * SS,
                       dout + b * KT, dout + 80 + b * KT, idx + b * KT);
}

__global__ void k_softmax_end(const float* __restrict__ em, float* __restrict__ dout) {
    const int bk = blockIdx.x;
    const int b = bk / KT, k = bk % KT;
    softmax_topk<false>(em + (size_t)bk * SS, nullptr,
                        dout + 160 + b * 25 + k * KT, dout + 560 + b * 25 + k * KT, nullptr);
}

// ---------------- start_feature partial sums (16-row chunks, 512 blocks) ----------------
__global__ void k_sf_partial(const float* __restrict__ seq, const float* __restrict__ sp,
                             float* __restrict__ partial) {
    const int chunk = blockIdx.x;  // 0..31
    const int b = blockIdx.y;
    const int t = threadIdx.x;
    __shared__ float p[16];
    if (t < 16) p[t] = sp[b * SS + chunk * 16 + t];
    __syncthreads();
    float4 acc = make_float4(0.f, 0.f, 0.f, 0.f);
    const float4* base = (const float4*)(seq + ((size_t)b * SS + chunk * 16) * HH);
    for (int s = 0; s < 16; ++s) {
        float4 v = base[(size_t)s * 256 + t];
        float ps = p[s];
        acc.x = fmaf(ps, v.x, acc.x);
        acc.y = fmaf(ps, v.y, acc.y);
        acc.z = fmaf(ps, v.z, acc.z);
        acc.w = fmaf(ps, v.w, acc.w);
    }
    ((float4*)partial)[(size_t)(b * 32 + chunk) * 256 + t] = acc;
}

// ---------------- k_featsum: feat[b][0:1024]=start_feature, [1024:2048]=cls ----------------
__global__ void k_featsum(const float* __restrict__ seq, const float* __restrict__ partial,
                          float* __restrict__ feat) {
    const int b = blockIdx.x, t = threadIdx.x;
    for (int q = 0; q < 4; ++q) {
        const int h = q * 256 + t;
        float s = 0.f;
        for (int c = 0; c < 32; ++c) s += partial[(size_t)(b * 32 + c) * HH + h];
        feat[(size_t)b * 2048 + h] = s;
        feat[(size_t)b * 2048 + HH + h] = seq[(size_t)b * SS * HH + h];
    }
}

// ---------------- k_ans: ans-head GEMM partials, K-split (64 x 16 blocks) ----------------
__global__ void k_ans(const float* __restrict__ feat, const float* __restrict__ w_ans0,
                      float* __restrict__ anspart) {
    __shared__ float A[16 * 132];
    __shared__ float W[16 * 132];
    const int c = blockIdx.x;   // 0..63 col chunk of 16
    const int kc = blockIdx.y;  // 0..15 K chunk of 128 (over 2048)
    const int t = threadIdx.x;
#pragma unroll
    for (int i = 0; i < 8; ++i) {
        const int e = i * 256 + t;
        const int b = e >> 7, d = e & 127;
        A[b * 132 + d] = feat[(size_t)b * 2048 + kc * 128 + d];
    }
#pragma unroll
    for (int p = 0; p < 8; ++p) {
        const int e = p * 256 + t;
        const int d = e >> 4, j = e & 15;
        W[j * 132 + d] = w_ans0[(size_t)(kc * 128 + d) * HH + c * 16 + j];
    }
    __syncthreads();
    const int j = t & 15, b = t >> 4;
    const float4* A4 = (const float4*)A;  // stride 33 float4
    const float4* W4 = (const float4*)W;
    float acc = 0.f;
    for (int d4 = 0; d4 < 32; ++d4) {
        float4 wv = W4[j * 33 + d4];
        float4 av = A4[b * 33 + d4];
        acc += av.x * wv.x + av.y * wv.y + av.z * wv.z + av.w * wv.w;
    }
    anspart[((size_t)kc * 16 + b) * HH + c * 16 + j] = acc;
}

__global__ void k_ansred(const float* __restrict__ anspart, const float* __restrict__ b_ans0,
                         const float* __restrict__ w_ans1, float* __restrict__ out) {
    __shared__ float scr[4];
    const int b = blockIdx.x;
    const int t = threadIdx.x;
    float dsum = 0.f;
#pragma unroll
    for (int q = 0; q < 4; ++q) {
        const int h = q * 256 + t;
        float s = b_ans0[h];
#pragma unroll
        for (int kc = 0; kc < 16; ++kc) s += anspart[((size_t)kc * 16 + b) * HH + h];
        dsum += tanhf(s) * w_ans1[h];
    }
    dsum = wave_sum(dsum);
    if ((t & 63) == 0) scr[t >> 6] = dsum;
    __syncthreads();
    if (t == 0) out[960 + b] = scr[0] + scr[1] + scr[2] + scr[3];
}

// ---------------- k_cfeat: Cb partials, K-split (64 x 8 blocks) ----------------
__global__ void k_cfeat(const float* __restrict__ seq, const int* __restrict__ idx,
                        const float* __restrict__ w_end0, float* __restrict__ Cpart) {
    __shared__ float A[80 * 132];
    __shared__ float W[16 * 132];
    __shared__ int growL[80];
    const int c = blockIdx.x;   // 0..63 col chunk of 16
    const int kc = blockIdx.y;  // 0..7 K chunk of 128
    const int t = threadIdx.x;
    if (t < 80) growL[t] = (t / KT) * SS + idx[t];
    __syncthreads();
    for (int i = 0; i < 40; ++i) {
        const int e = i * 256 + t;
        const int r = e >> 7, d = e & 127;
        A[r * 132 + d] = seq[(size_t)growL[r] * HH + kc * 128 + d];
    }
#pragma unroll
    for (int p = 0; p < 8; ++p) {
        const int e = p * 256 + t;
        const int d = e >> 4, j = e & 15;
        W[j * 132 + d] = w_end0[(size_t)(HH + kc * 128 + d) * HH + c * 16 + j];
    }
    __syncthreads();
    const int j = t & 15, rg = t >> 4;
    const float4* A4 = (const float4*)A;
    const float4* W4 = (const float4*)W;
    float acc[5] = {0.f, 0.f, 0.f, 0.f, 0.f};
    for (int d4 = 0; d4 < 32; ++d4) {
        float4 wv = W4[j * 33 + d4];
#pragma unroll
        for (int i = 0; i < 5; ++i) {
            float4 av = A4[(rg + 16 * i) * 33 + d4];
            acc[i] += av.x * wv.x + av.y * wv.y + av.z * wv.z + av.w * wv.w;
        }
    }
#pragma unroll
    for (int i = 0; i < 5; ++i)
        Cpart[((size_t)kc * 80 + rg + 16 * i) * HH + c * 16 + j] = acc[i];
}

__global__ void k_cbred(const float* __restrict__ Cpart, const float* __restrict__ b_end0,
                        float* __restrict__ Cb) {
    const int bk = blockIdx.x;  // 0..79
    const int t = threadIdx.x;
#pragma unroll
    for (int q = 0; q < 4; ++q) {
        const int h = q * 256 + t;
        float s = b_end0[h];
#pragma unroll
        for (int kc = 0; kc < 8; ++kc) s += Cpart[((size_t)kc * 80 + bk) * HH + h];
        Cb[(size_t)bk * HH + h] = s;
    }
}

// ---------------- k_end: MFMA split-bf16 GEMM + tanh + LN + dot + mask ----------------
__launch_bounds__(512, 2)
__global__ void k_end(const float* __restrict__ seq, const short* __restrict__ wpk_hi,
                      const short* __restrict__ wpk_lo, const float* __restrict__ Cb,
                      const float* __restrict__ ln_g, const float* __restrict__ w_end1,
                      const float* __restrict__ b_end1, const float* __restrict__ p_mask,
                      const float* __restrict__ scal, float* __restrict__ em) {
    extern __shared__ char smem[];  // 128KB: A_hi[32][1024] bf16 (swizzled), A_lo at +64KB
    const int t = threadIdx.x;
    const int l = t & 63, w = t >> 6;
    const int row0 = blockIdx.x * 32;
    const int b = row0 >> 9;

    // ---- stage seq rows as hi/lo bf16 into LDS with XOR swizzle ----
    {
        const float4* gp = (const float4*)(seq + (size_t)row0 * HH);
        const int f4 = t & 255;
#pragma unroll
        for (int i = 0; i < 16; ++i) {
            const int row = (i << 1) | (t >> 8);
            float4 v = gp[(size_t)row * 256 + f4];
            unsigned short h0, l0, h1, l1, h2, l2, h3, l3;
            split2(v.x, h0, l0);
            split2(v.y, h1, l1);
            split2(v.z, h2, l2);
            split2(v.w, h3, l3);
            const int boff = (row * 2048 + f4 * 8) ^ ((row & 7) << 4);
            *(short4*)(smem + boff) = make_short4((short)h0, (short)h1, (short)h2, (short)h3);
            *(short4*)(smem + 65536 + boff) = make_short4((short)l0, (short)l1, (short)l2, (short)l3);
        }
    }
    __syncthreads();

    // ---- MFMA GEMM: acc[mh][nt] covers rows mh*16+(frag rows), cols w*128 + nt*16 ----
    f32x4 acc[2][8];
#pragma unroll
    for (int m = 0; m < 2; ++m)
#pragma unroll
        for (int n = 0; n < 8; ++n) acc[m][n] = (f32x4){0.f, 0.f, 0.f, 0.f};

    const int g = l >> 4;
    const int off0 = (l & 15) * 2048 + g * 16;
    const int off1 = off0 + 16 * 2048;
    const int swz = (l & 7) << 4;
    const short8_t* WH = (const short8_t*)wpk_hi;
    const short8_t* WLo = (const short8_t*)wpk_lo;
    const size_t wbase = (size_t)w * 8 * 2048 + l;

    for (int kb = 0; kb < 32; ++kb) {
        const int ko = kb * 64;
        short8_t ah0 = *(const short8_t*)(smem + ((off0 + ko) ^ swz));
        short8_t al0 = *(const short8_t*)(smem + 65536 + ((off0 + ko) ^ swz));
        short8_t ah1 = *(const short8_t*)(smem + ((off1 + ko) ^ swz));
        short8_t al1 = *(const short8_t*)(smem + 65536 + ((off1 + ko) ^ swz));
#pragma unroll
        for (int nt = 0; nt < 8; ++nt) {
            const size_t wi = wbase + (size_t)nt * 2048 + kb * 64;
            short8_t bh = WH[wi];
            short8_t bl = WLo[wi];
            acc[0][nt] = __builtin_amdgcn_mfma_f32_16x16x32_bf16(ah0, bh, acc[0][nt], 0, 0, 0);
            acc[1][nt] = __builtin_amdgcn_mfma_f32_16x16x32_bf16(ah1, bh, acc[1][nt], 0, 0, 0);
            acc[0][nt] = __builtin_amdgcn_mfma_f32_16x16x32_bf16(al0, bh, acc[0][nt], 0, 0, 0);
            acc[1][nt] = __builtin_amdgcn_mfma_f32_16x16x32_bf16(al1, bh, acc[1][nt], 0, 0, 0);
            acc[0][nt] = __builtin_amdgcn_mfma_f32_16x16x32_bf16(ah0, bl, acc[0][nt], 0, 0, 0);
            acc[1][nt] = __builtin_amdgcn_mfma_f32_16x16x32_bf16(ah1, bl, acc[1][nt], 0, 0, 0);
        }
    }
    __syncthreads();  // all A reads done; LDS becomes scratch

    // ---- fused epilogue: tanh + LN (3 sums) + dot(w_end1) + mask ----
    float* scr = (float*)smem;  // [8 waves][32 rows][5 k][3]
    float gw[8];
#pragma unroll
    for (int nt = 0; nt < 8; ++nt) {
        const int col = (w * 8 + nt) * 16 + (l & 15);
        gw[nt] = ln_g[col] * w_end1[col];
    }

    for (int k = 0; k < KT; ++k) {
        float S[2][4], Q[2][4], G[2][4];
#pragma unroll
        for (int m = 0; m < 2; ++m)
#pragma unroll
            for (int r = 0; r < 4; ++r) { S[m][r] = 0.f; Q[m][r] = 0.f; G[m][r] = 0.f; }
#pragma unroll
        for (int nt = 0; nt < 8; ++nt) {
            const int col = (w * 8 + nt) * 16 + (l & 15);
            const float cb = Cb[((size_t)(b * KT + k) << 10) + col];
            const float gwv = gw[nt];
#pragma unroll
            for (int m = 0; m < 2; ++m) {
#pragma unroll
                for (int r = 0; r < 4; ++r) {
                    float v = tanh_fast(acc[m][nt][r] + cb);
                    S[m][r] += v;
                    Q[m][r] += v * v;
                    G[m][r] += v * gwv;
                }
            }
        }
        for (int msk = 1; msk < 16; msk <<= 1) {
#pragma unroll
            for (int m = 0; m < 2; ++m)
#pragma unroll
                for (int r = 0; r < 4; ++r) {
                    S[m][r] += __shfl_xor(S[m][r], msk);
                    Q[m][r] += __shfl_xor(Q[m][r], msk);
                    G[m][r] += __shfl_xor(G[m][r], msk);
                }
        }
        if ((l & 15) == 0) {
            const int gg = l >> 4;
#pragma unroll
            for (int m = 0; m < 2; ++m)
#pragma unroll
                for (int r = 0; r < 4; ++r) {
                    const int row = m * 16 + gg * 4 + r;
                    float* sp_ = scr + ((size_t)(w * 32 + row) * KT + k) * 3;
                    sp_[0] = S[m][r];
                    sp_[1] = Q[m][r];
                    sp_[2] = G[m][r];
                }
        }
    }
    __syncthreads();

    if (t < 32 * KT) {
        const int row = t / KT, k = t % KT;
        float S = 0.f, Q = 0.f, G = 0.f;
#pragma unroll
        for (int ww = 0; ww < 8; ++ww) {
            const float* sp_ = scr + ((size_t)(ww * 32 + row) * KT + k) * 3;
            S += sp_[0];
            Q += sp_[1];
            G += sp_[2];
        }
        const float GW1 = scal[0], BW1 = scal[1];
        const float mu = S * (1.f / HH);
        const float var = Q * (1.f / HH) - mu * mu;
        const float rs = rsqrtf(var + 1e-12f);
        float logit = rs * (G - mu * GW1) + BW1 + b_end1[0];
        const int srow = row0 + row;
        const float pm = p_mask[srow];
        em[((size_t)(b * KT + k) << 9) + (srow & (SS - 1))] = logit * (1.f - pm) - NEGV * pm;
    }
}

// ---------------- launch ----------------
extern "C" void kernel_launch(void* const* d_in, const int* in_sizes, int n_in,
                              void* d_out, int out_size, void* d_ws, size_t ws_size,
                              hipStream_t stream) {
    const float* seq     = (const float*)d_in[0];
    const float* p_mask  = (const float*)d_in[1];
    const float* w_start = (const float*)d_in[2];
    const float* b_start = (const float*)d_in[3];
    const float* w_end0  = (const float*)d_in[4];
    const float* b_end0  = (const float*)d_in[5];
    const float* ln_g    = (const float*)d_in[6];
    const float* ln_b    = (const float*)d_in[7];
    const float* w_end1  = (const float*)d_in[8];
    const float* b_end1  = (const float*)d_in[9];
    const float* w_ans0  = (const float*)d_in[10];
    const float* b_ans0  = (const float*)d_in[11];
    const float* w_ans1  = (const float*)d_in[12];
    float* out = (float*)d_out;

    float* sm      = (float*)d_ws;                  // 8192
    float* sp      = sm + BB * SS;                  // 8192
    float* partial = sp + BB * SS;                  // 16*32*1024 = 524288
    float* feat    = partial + BB * 32 * HH;        // 32768
    float* Cb      = feat + BB * 2048;              // 81920
    float* Cpart   = Cb + 80 * HH;                  // 8*80*1024 = 655360
    float* anspart = Cpart + 8 * 80 * HH;           // 16*16*1024 = 262144
    float* em      = anspart + 16 * BB * HH;        // 40960
    float* scal    = em + BB * KT * SS;             // 16
    int*   idx     = (int*)(scal + 16);             // 80
    short* wpk_hi  = (short*)(((uintptr_t)(idx + 80) + 255) & ~(uintptr_t)255);
    short* wpk_lo  = wpk_hi + (1 << 20);            // 1M bf16 each

    hipLaunchKernelGGL(k_prep, dim3(64, 8), dim3(256), 0, stream, w_end0, wpk_hi, wpk_lo);
    hipLaunchKernelGGL(k_scal, dim3(1), dim3(256), 0, stream, ln_g, ln_b, w_end1, scal);
    hipLaunchKernelGGL(k_start_logits, dim3(BB * SS / 4), dim3(256), 0, stream,
                       seq, p_mask, w_start, b_start, sm);
    hipLaunchKernelGGL(k_softmax_start, dim3(BB), dim3(256), 0, stream, sm, sp, out, idx);
    hipLaunchKernelGGL(k_sf_partial, dim3(32, BB), dim3(256), 0, stream, seq, sp, partial);
    hipLaunchKernelGGL(k_featsum, dim3(BB), dim3(256), 0, stream, seq, partial, feat);
    hipLaunchKernelGGL(k_ans, dim3(64, 16), dim3(256), 0, stream, feat, w_ans0, anspart);
    hipLaunchKernelGGL(k_ansred, dim3(BB), dim3(256), 0, stream, anspart, b_ans0, w_ans1, out);
    hipLaunchKernelGGL(k_cfeat, dim3(64, 8), dim3(256), 0, stream, seq, idx, w_end0, Cpart);
    hipLaunchKernelGGL(k_cbred, dim3(80), dim3(256), 0, stream, Cpart, b_end0, Cb);
    hipLaunchKernelGGL(k_end, dim3(BB * SS / 32), dim3(512), 131072, stream,
                       seq, wpk_hi, wpk_lo, Cb, ln_g, w_end1, b_end1, p_mask, scal, em);
    hipLaunchKernelGGL(k_softmax_end, dim3(BB * KT), dim3(256), 0, stream, em, out);
}

// Round 4
// 188.899 us; speedup vs baseline: 3.4547x; 1.0357x over previous
//
#include <hip/hip_runtime.h>
#include <math.h>

#define BB 16
#define SS 512
#define HH 1024
#define KT 5
#define NEGV 1e30f

typedef __attribute__((ext_vector_type(8))) short short8_t;
typedef __attribute__((ext_vector_type(4))) float f32x4;

// ---------------- helpers ----------------
__device__ __forceinline__ float wave_sum(float v) {
    for (int off = 32; off; off >>= 1) v += __shfl_down(v, off);
    return v;
}

__device__ __forceinline__ unsigned short bf16rn(float x) {
    unsigned u = __float_as_uint(x);
    return (unsigned short)((u + 0x7fffu + ((u >> 16) & 1u)) >> 16);
}

__device__ __forceinline__ void split2(float x, unsigned short& h, unsigned short& l) {
    h = bf16rn(x);
    float hf = __uint_as_float(((unsigned)h) << 16);
    l = bf16rn(x - hf);
}

__device__ __forceinline__ float tanh_fast(float x) {
    float e = __expf(2.0f * x);
    return 1.0f - 2.0f * __builtin_amdgcn_rcpf(e + 1.0f);
}

// ---------------- k_prep: pack W0a into MFMA B-frag order (hi/lo) ----------------
// Wpk layout: [ntile(64)][kblk(32)][lane(64)][8] bf16; lane l holds
// B[kblk*32 + (l>>4)*8 + j][ntile*16 + (l&15)].
__global__ void k_prep(const float* __restrict__ w_end0,
                       short* __restrict__ wpk_hi, short* __restrict__ wpk_lo) {
    const int nt = blockIdx.x;      // 0..63 n-tile
    const int t = threadIdx.x;
    const int n_idx = t & 15;
    const int g = (t >> 4) & 3;     // k-group within kblk
    const int kq = t >> 6;
    const int kblk = blockIdx.y * 4 + kq;
    const int k0 = kblk * 32 + g * 8;
    unsigned short hs[8], ls[8];
#pragma unroll
    for (int j = 0; j < 8; ++j) {
        float v = w_end0[(size_t)(k0 + j) * HH + nt * 16 + n_idx];
        split2(v, hs[j], ls[j]);
    }
    const size_t fi = (((size_t)nt * 32 + kblk) * 64 + (g * 16 + n_idx)) * 8;
    short8_t hv, lv;
#pragma unroll
    for (int j = 0; j < 8; ++j) { hv[j] = (short)hs[j]; lv[j] = (short)ls[j]; }
    *(short8_t*)(wpk_hi + fi) = hv;
    *(short8_t*)(wpk_lo + fi) = lv;
}

// ---------------- k_scal: GW1 = sum g*w1, BW1 = sum b*w1 ----------------
__global__ void k_scal(const float* __restrict__ ln_g, const float* __restrict__ ln_b,
                       const float* __restrict__ w_end1, float* __restrict__ scal) {
    __shared__ float scr[8];
    const int t = threadIdx.x;
    float4 g = ((const float4*)ln_g)[t];
    float4 w = ((const float4*)w_end1)[t];
    float4 b = ((const float4*)ln_b)[t];
    float gw = g.x * w.x + g.y * w.y + g.z * w.z + g.w * w.w;
    float bw = b.x * w.x + b.y * w.y + b.z * w.z + b.w * w.w;
    gw = wave_sum(gw);
    bw = wave_sum(bw);
    if ((t & 63) == 0) { scr[t >> 6] = gw; scr[4 + (t >> 6)] = bw; }
    __syncthreads();
    if (t == 0) {
        scal[0] = scr[0] + scr[1] + scr[2] + scr[3];
        scal[1] = scr[4] + scr[5] + scr[6] + scr[7];
    }
}

// ---------------- kernel 1: start logits + mask (wave per row) ----------------
__global__ void k_start_logits(const float* __restrict__ seq, const float* __restrict__ pm,
                               const float* __restrict__ w_start, const float* __restrict__ b_start,
                               float* __restrict__ sm) {
    const int t = threadIdx.x;
    const int l = t & 63;
    const int row = blockIdx.x * 4 + (t >> 6);
    const float4* rp = (const float4*)(seq + (size_t)row * HH);
    const float4* wp = (const float4*)w_start;
    float d = 0.f;
#pragma unroll
    for (int q = 0; q < 4; ++q) {
        float4 a = rp[q * 64 + l];
        float4 w = wp[q * 64 + l];
        d += a.x * w.x + a.y * w.y + a.z * w.z + a.w * w.w;
    }
    d = wave_sum(d);
    if (l == 0) {
        float m = pm[row];
        sm[row] = (d + b_start[0]) * (1.f - m) - NEGV * m;
    }
}

// ---------------- softmax + top-5 over 512 values (one block, 256 thr) ----------------
template <bool WRITE_P>
__device__ void softmax_topk(const float* __restrict__ x, float* __restrict__ p_out,
                             float* __restrict__ val_out, float* __restrict__ idxf_out,
                             int* __restrict__ idxi_out) {
    const int t = threadIdx.x;
    __shared__ float scr[4];
    __shared__ float sv[4];
    __shared__ int si[4];
    __shared__ int wi_s;
    float x0 = x[t], x1 = x[t + 256];

    float m = fmaxf(x0, x1);
    for (int off = 32; off; off >>= 1) m = fmaxf(m, __shfl_down(m, off));
    if ((t & 63) == 0) scr[t >> 6] = m;
    __syncthreads();
    m = fmaxf(fmaxf(scr[0], scr[1]), fmaxf(scr[2], scr[3]));
    __syncthreads();

    float e0 = expf(x0 - m), e1 = expf(x1 - m);
    float ssum = wave_sum(e0 + e1);
    if ((t & 63) == 0) scr[t >> 6] = ssum;
    __syncthreads();
    ssum = scr[0] + scr[1] + scr[2] + scr[3];
    __syncthreads();

    if (WRITE_P) {
        p_out[t] = e0 / ssum;
        p_out[t + 256] = e1 / ssum;
    }
    const float lse = m + logf(ssum);

    float v0 = x0, v1 = x1;
    for (int k = 0; k < KT; ++k) {
        float bv;
        int bi;
        if (v0 >= v1) { bv = v0; bi = t; } else { bv = v1; bi = t + 256; }
        for (int off = 32; off; off >>= 1) {
            float ov = __shfl_down(bv, off);
            int oi = __shfl_down(bi, off);
            if (ov > bv || (ov == bv && oi < bi)) { bv = ov; bi = oi; }
        }
        if ((t & 63) == 0) { sv[t >> 6] = bv; si[t >> 6] = bi; }
        __syncthreads();
        if (t == 0) {
            float fv = sv[0];
            int fi = si[0];
            for (int w = 1; w < 4; ++w)
                if (sv[w] > fv || (sv[w] == fv && si[w] < fi)) { fv = sv[w]; fi = si[w]; }
            wi_s = fi;
            val_out[k] = fv - lse;
            idxf_out[k] = (float)fi;
            if (idxi_out) idxi_out[k] = fi;
        }
        __syncthreads();
        const int wi = wi_s;
        if (wi == t) v0 = -INFINITY;
        else if (wi == t + 256) v1 = -INFINITY;
        __syncthreads();
    }
}

__global__ void k_softmax_start(const float* __restrict__ sm, float* __restrict__ sp,
                                float* __restrict__ dout, int* __restrict__ idx) {
    const int b = blockIdx.x;
    softmax_topk<true>(sm + (size_t)b * SS, sp + (size_t)b * SS,
                       dout + b * KT, dout + 80 + b * KT, idx + b * KT);
}

__global__ void k_softmax_end(const float* __restrict__ em, float* __restrict__ dout) {
    const int bk = blockIdx.x;
    const int b = bk / KT, k = bk % KT;
    softmax_topk<false>(em + (size_t)bk * SS, nullptr,
                        dout + 160 + b * 25 + k * KT, dout + 560 + b * 25 + k * KT, nullptr);
}

// ---------------- start_feature partial sums (16-row chunks, 512 blocks) ----------------
__global__ void k_sf_partial(const float* __restrict__ seq, const float* __restrict__ sp,
                             float* __restrict__ partial) {
    const int chunk = blockIdx.x;  // 0..31
    const int b = blockIdx.y;
    const int t = threadIdx.x;
    __shared__ float p[16];
    if (t < 16) p[t] = sp[b * SS + chunk * 16 + t];
    __syncthreads();
    float4 acc = make_float4(0.f, 0.f, 0.f, 0.f);
    const float4* base = (const float4*)(seq + ((size_t)b * SS + chunk * 16) * HH);
    for (int s = 0; s < 16; ++s) {
        float4 v = base[(size_t)s * 256 + t];
        float ps = p[s];
        acc.x = fmaf(ps, v.x, acc.x);
        acc.y = fmaf(ps, v.y, acc.y);
        acc.z = fmaf(ps, v.z, acc.z);
        acc.w = fmaf(ps, v.w, acc.w);
    }
    ((float4*)partial)[(size_t)(b * 32 + chunk) * 256 + t] = acc;
}

// ---------------- k_featsum: feat[b][0:1024]=start_feature, [1024:2048]=cls ----------------
__global__ void k_featsum(const float* __restrict__ seq, const float* __restrict__ partial,
                          float* __restrict__ feat) {
    const int b = blockIdx.x, t = threadIdx.x;
    for (int q = 0; q < 4; ++q) {
        const int h = q * 256 + t;
        float s = 0.f;
        for (int c = 0; c < 32; ++c) s += partial[(size_t)(b * 32 + c) * HH + h];
        feat[(size_t)b * 2048 + h] = s;
        feat[(size_t)b * 2048 + HH + h] = seq[(size_t)b * SS * HH + h];
    }
}

// ---------------- k_ans: ans-head GEMM partials, K-split (64 x 16 blocks) ----------------
__global__ void k_ans(const float* __restrict__ feat, const float* __restrict__ w_ans0,
                      float* __restrict__ anspart) {
    __shared__ float A[16 * 132];
    __shared__ float W[16 * 132];
    const int c = blockIdx.x;   // 0..63 col chunk of 16
    const int kc = blockIdx.y;  // 0..15 K chunk of 128 (over 2048)
    const int t = threadIdx.x;
#pragma unroll
    for (int i = 0; i < 8; ++i) {
        const int e = i * 256 + t;
        const int b = e >> 7, d = e & 127;
        A[b * 132 + d] = feat[(size_t)b * 2048 + kc * 128 + d];
    }
#pragma unroll
    for (int p = 0; p < 8; ++p) {
        const int e = p * 256 + t;
        const int d = e >> 4, j = e & 15;
        W[j * 132 + d] = w_ans0[(size_t)(kc * 128 + d) * HH + c * 16 + j];
    }
    __syncthreads();
    const int j = t & 15, b = t >> 4;
    const float4* A4 = (const float4*)A;  // stride 33 float4
    const float4* W4 = (const float4*)W;
    float acc = 0.f;
    for (int d4 = 0; d4 < 32; ++d4) {
        float4 wv = W4[j * 33 + d4];
        float4 av = A4[b * 33 + d4];
        acc += av.x * wv.x + av.y * wv.y + av.z * wv.z + av.w * wv.w;
    }
    anspart[((size_t)kc * 16 + b) * HH + c * 16 + j] = acc;
}

__global__ void k_ansred(const float* __restrict__ anspart, const float* __restrict__ b_ans0,
                         const float* __restrict__ w_ans1, float* __restrict__ out) {
    __shared__ float scr[4];
    const int b = blockIdx.x;
    const int t = threadIdx.x;
    float dsum = 0.f;
#pragma unroll
    for (int q = 0; q < 4; ++q) {
        const int h = q * 256 + t;
        float s = b_ans0[h];
#pragma unroll
        for (int kc = 0; kc < 16; ++kc) s += anspart[((size_t)kc * 16 + b) * HH + h];
        dsum += tanhf(s) * w_ans1[h];
    }
    dsum = wave_sum(dsum);
    if ((t & 63) == 0) scr[t >> 6] = dsum;
    __syncthreads();
    if (t == 0) out[960 + b] = scr[0] + scr[1] + scr[2] + scr[3];
}

// ---------------- k_cfeat: Cb partials, K-split (64 x 8 blocks) ----------------
__global__ void k_cfeat(const float* __restrict__ seq, const int* __restrict__ idx,
                        const float* __restrict__ w_end0, float* __restrict__ Cpart) {
    __shared__ float A[80 * 132];
    __shared__ float W[16 * 132];
    __shared__ int growL[80];
    const int c = blockIdx.x;   // 0..63 col chunk of 16
    const int kc = blockIdx.y;  // 0..7 K chunk of 128
    const int t = threadIdx.x;
    if (t < 80) growL[t] = (t / KT) * SS + idx[t];
    __syncthreads();
    for (int i = 0; i < 40; ++i) {
        const int e = i * 256 + t;
        const int r = e >> 7, d = e & 127;
        A[r * 132 + d] = seq[(size_t)growL[r] * HH + kc * 128 + d];
    }
#pragma unroll
    for (int p = 0; p < 8; ++p) {
        const int e = p * 256 + t;
        const int d = e >> 4, j = e & 15;
        W[j * 132 + d] = w_end0[(size_t)(HH + kc * 128 + d) * HH + c * 16 + j];
    }
    __syncthreads();
    const int j = t & 15, rg = t >> 4;
    const float4* A4 = (const float4*)A;
    const float4* W4 = (const float4*)W;
    float acc[5] = {0.f, 0.f, 0.f, 0.f, 0.f};
    for (int d4 = 0; d4 < 32; ++d4) {
        float4 wv = W4[j * 33 + d4];
#pragma unroll
        for (int i = 0; i < 5; ++i) {
            float4 av = A4[(rg + 16 * i) * 33 + d4];
            acc[i] += av.x * wv.x + av.y * wv.y + av.z * wv.z + av.w * wv.w;
        }
    }
#pragma unroll
    for (int i = 0; i < 5; ++i)
        Cpart[((size_t)kc * 80 + rg + 16 * i) * HH + c * 16 + j] = acc[i];
}

__global__ void k_cbred(const float* __restrict__ Cpart, const float* __restrict__ b_end0,
                        float* __restrict__ Cb) {
    const int bk = blockIdx.x;  // 0..79
    const int t = threadIdx.x;
#pragma unroll
    for (int q = 0; q < 4; ++q) {
        const int h = q * 256 + t;
        float s = b_end0[h];
#pragma unroll
        for (int kc = 0; kc < 8; ++kc) s += Cpart[((size_t)kc * 80 + bk) * HH + h];
        Cb[(size_t)bk * HH + h] = s;
    }
}

// ---------------- k_end: MFMA split-bf16 GEMM + tanh + LN + dot + mask ----------------
// R4: register double-buffered software pipeline on the kb loop (prefetch
// kb+1's W global loads + A ds_reads while doing kb's 48 MFMAs).
__launch_bounds__(512, 1)
__global__ void k_end(const float* __restrict__ seq, const short* __restrict__ wpk_hi,
                      const short* __restrict__ wpk_lo, const float* __restrict__ Cb,
                      const float* __restrict__ ln_g, const float* __restrict__ w_end1,
                      const float* __restrict__ b_end1, const float* __restrict__ p_mask,
                      const float* __restrict__ scal, float* __restrict__ em) {
    extern __shared__ char smem[];  // 128KB: A_hi[32][1024] bf16 (swizzled), A_lo at +64KB
    const int t = threadIdx.x;
    const int l = t & 63, w = t >> 6;
    const int row0 = blockIdx.x * 32;
    const int b = row0 >> 9;

    // ---- stage seq rows as hi/lo bf16 into LDS with XOR swizzle ----
    {
        const float4* gp = (const float4*)(seq + (size_t)row0 * HH);
        const int f4 = t & 255;
#pragma unroll
        for (int i = 0; i < 16; ++i) {
            const int row = (i << 1) | (t >> 8);
            float4 v = gp[(size_t)row * 256 + f4];
            unsigned short h0, l0, h1, l1, h2, l2, h3, l3;
            split2(v.x, h0, l0);
            split2(v.y, h1, l1);
            split2(v.z, h2, l2);
            split2(v.w, h3, l3);
            const int boff = (row * 2048 + f4 * 8) ^ ((row & 7) << 4);
            *(short4*)(smem + boff) = make_short4((short)h0, (short)h1, (short)h2, (short)h3);
            *(short4*)(smem + 65536 + boff) = make_short4((short)l0, (short)l1, (short)l2, (short)l3);
        }
    }
    __syncthreads();

    // ---- MFMA GEMM: acc[mh][nt] covers rows mh*16+(frag rows), cols w*128 + nt*16 ----
    f32x4 acc[2][8];
#pragma unroll
    for (int m = 0; m < 2; ++m)
#pragma unroll
        for (int n = 0; n < 8; ++n) acc[m][n] = (f32x4){0.f, 0.f, 0.f, 0.f};

    const int g = l >> 4;
    const int off0 = (l & 15) * 2048 + g * 16;
    const int off1 = off0 + 16 * 2048;
    const int swz = (l & 7) << 4;
    const short8_t* WH = (const short8_t*)wpk_hi;
    const short8_t* WLo = (const short8_t*)wpk_lo;
    const size_t wbase = (size_t)w * 8 * 2048 + l;

    short8_t ahC[2], alC[2], bhC[8], blC[8];
    short8_t ahN[2], alN[2], bhN[8], blN[8];

    // prologue: load kb=0
    {
        const int ko = 0;
        ahC[0] = *(const short8_t*)(smem + ((off0 + ko) ^ swz));
        alC[0] = *(const short8_t*)(smem + 65536 + ((off0 + ko) ^ swz));
        ahC[1] = *(const short8_t*)(smem + ((off1 + ko) ^ swz));
        alC[1] = *(const short8_t*)(smem + 65536 + ((off1 + ko) ^ swz));
#pragma unroll
        for (int nt = 0; nt < 8; ++nt) {
            const size_t wi = wbase + (size_t)nt * 2048;
            bhC[nt] = WH[wi];
            blC[nt] = WLo[wi];
        }
    }

#pragma unroll
    for (int kb = 0; kb < 32; ++kb) {
        if (kb < 31) {
            const int ko = (kb + 1) * 64;
            ahN[0] = *(const short8_t*)(smem + ((off0 + ko) ^ swz));
            alN[0] = *(const short8_t*)(smem + 65536 + ((off0 + ko) ^ swz));
            ahN[1] = *(const short8_t*)(smem + ((off1 + ko) ^ swz));
            alN[1] = *(const short8_t*)(smem + 65536 + ((off1 + ko) ^ swz));
#pragma unroll
            for (int nt = 0; nt < 8; ++nt) {
                const size_t wi = wbase + (size_t)nt * 2048 + (kb + 1) * 64;
                bhN[nt] = WH[wi];
                blN[nt] = WLo[wi];
            }
        }
#pragma unroll
        for (int nt = 0; nt < 8; ++nt) {
            acc[0][nt] = __builtin_amdgcn_mfma_f32_16x16x32_bf16(ahC[0], bhC[nt], acc[0][nt], 0, 0, 0);
            acc[1][nt] = __builtin_amdgcn_mfma_f32_16x16x32_bf16(ahC[1], bhC[nt], acc[1][nt], 0, 0, 0);
            acc[0][nt] = __builtin_amdgcn_mfma_f32_16x16x32_bf16(alC[0], bhC[nt], acc[0][nt], 0, 0, 0);
            acc[1][nt] = __builtin_amdgcn_mfma_f32_16x16x32_bf16(alC[1], bhC[nt], acc[1][nt], 0, 0, 0);
            acc[0][nt] = __builtin_amdgcn_mfma_f32_16x16x32_bf16(ahC[0], blC[nt], acc[0][nt], 0, 0, 0);
            acc[1][nt] = __builtin_amdgcn_mfma_f32_16x16x32_bf16(ahC[1], blC[nt], acc[1][nt], 0, 0, 0);
        }
        if (kb < 31) {
#pragma unroll
            for (int i = 0; i < 2; ++i) { ahC[i] = ahN[i]; alC[i] = alN[i]; }
#pragma unroll
            for (int nt = 0; nt < 8; ++nt) { bhC[nt] = bhN[nt]; blC[nt] = blN[nt]; }
        }
    }
    __syncthreads();  // all A reads done; LDS becomes scratch

    // ---- fused epilogue: tanh + LN (3 sums) + dot(w_end1) + mask ----
    float* scr = (float*)smem;  // [8 waves][32 rows][5 k][3]
    float* lds_f = (float*)smem;
    float gw[8];
#pragma unroll
    for (int nt = 0; nt < 8; ++nt) {
        const int col = (w * 8 + nt) * 16 + (l & 15);
        gw[nt] = ln_g[col] * w_end1[col];
    }

    for (int k = 0; k < KT; ++k) {
        float S[2][4], Q[2][4], G[2][4];
#pragma unroll
        for (int m = 0; m < 2; ++m)
#pragma unroll
            for (int r = 0; r < 4; ++r) { S[m][r] = 0.f; Q[m][r] = 0.f; G[m][r] = 0.f; }
#pragma unroll
        for (int nt = 0; nt < 8; ++nt) {
            const int col = (w * 8 + nt) * 16 + (l & 15);
            const float cb = Cb[((size_t)(b * KT + k) << 10) + col];
            const float gwv = gw[nt];
#pragma unroll
            for (int m = 0; m < 2; ++m) {
#pragma unroll
                for (int r = 0; r < 4; ++r) {
                    float v = tanh_fast(acc[m][nt][r] + cb);
                    S[m][r] += v;
                    Q[m][r] += v * v;
                    G[m][r] += v * gwv;
                }
            }
        }
        for (int msk = 1; msk < 16; msk <<= 1) {
#pragma unroll
            for (int m = 0; m < 2; ++m)
#pragma unroll
                for (int r = 0; r < 4; ++r) {
                    S[m][r] += __shfl_xor(S[m][r], msk);
                    Q[m][r] += __shfl_xor(Q[m][r], msk);
                    G[m][r] += __shfl_xor(G[m][r], msk);
                }
        }
        if ((l & 15) == 0) {
            const int gg = l >> 4;
#pragma unroll
            for (int m = 0; m < 2; ++m)
#pragma unroll
                for (int r = 0; r < 4; ++r) {
                    const int row = m * 16 + gg * 4 + r;
                    float* sp_ = scr + ((size_t)(w * 32 + row) * KT + k) * 3;
                    sp_[0] = S[m][r];
                    sp_[1] = Q[m][r];
                    sp_[2] = G[m][r];
                }
        }
    }
    __syncthreads();

    if (t < 32 * KT) {
        const int row = t / KT, k = t % KT;
        float S = 0.f, Q = 0.f, G = 0.f;
#pragma unroll
        for (int ww = 0; ww < 8; ++ww) {
            const float* sp_ = lds_f + ((size_t)(ww * 32 + row) * KT + k) * 3;
            S += sp_[0];
            Q += sp_[1];
            G += sp_[2];
        }
        const float GW1 = scal[0], BW1 = scal[1];
        const float mu = S * (1.f / HH);
        const float var = Q * (1.f / HH) - mu * mu;
        const float rs = rsqrtf(var + 1e-12f);
        float logit = rs * (G - mu * GW1) + BW1 + b_end1[0];
        const int srow = row0 + row;
        const float pm = p_mask[srow];
        em[((size_t)(b * KT + k) << 9) + (srow & (SS - 1))] = logit * (1.f - pm) - NEGV * pm;
    }
}

// ---------------- launch ----------------
extern "C" void kernel_launch(void* const* d_in, const int* in_sizes, int n_in,
                              void* d_out, int out_size, void* d_ws, size_t ws_size,
                              hipStream_t stream) {
    const float* seq     = (const float*)d_in[0];
    const float* p_mask  = (const float*)d_in[1];
    const float* w_start = (const float*)d_in[2];
    const float* b_start = (const float*)d_in[3];
    const float* w_end0  = (const float*)d_in[4];
    const float* b_end0  = (const float*)d_in[5];
    const float* ln_g    = (const float*)d_in[6];
    const float* ln_b    = (const float*)d_in[7];
    const float* w_end1  = (const float*)d_in[8];
    const float* b_end1  = (const float*)d_in[9];
    const float* w_ans0  = (const float*)d_in[10];
    const float* b_ans0  = (const float*)d_in[11];
    const float* w_ans1  = (const float*)d_in[12];
    float* out = (float*)d_out;

    float* sm      = (float*)d_ws;                  // 8192
    float* sp      = sm + BB * SS;                  // 8192
    float* partial = sp + BB * SS;                  // 16*32*1024 = 524288
    float* feat    = partial + BB * 32 * HH;        // 32768
    float* Cb      = feat + BB * 2048;              // 81920
    float* Cpart   = Cb + 80 * HH;                  // 8*80*1024 = 655360
    float* anspart = Cpart + 8 * 80 * HH;           // 16*16*1024 = 262144
    float* em      = anspart + 16 * BB * HH;        // 40960
    float* scal    = em + BB * KT * SS;             // 16
    int*   idx     = (int*)(scal + 16);             // 80
    short* wpk_hi  = (short*)(((uintptr_t)(idx + 80) + 255) & ~(uintptr_t)255);
    short* wpk_lo  = wpk_hi + (1 << 20);            // 1M bf16 each

    hipLaunchKernelGGL(k_prep, dim3(64, 8), dim3(256), 0, stream, w_end0, wpk_hi, wpk_lo);
    hipLaunchKernelGGL(k_scal, dim3(1), dim3(256), 0, stream, ln_g, ln_b, w_end1, scal);
    hipLaunchKernelGGL(k_start_logits, dim3(BB * SS / 4), dim3(256), 0, stream,
                       seq, p_mask, w_start, b_start, sm);
    hipLaunchKernelGGL(k_softmax_start, dim3(BB), dim3(256), 0, stream, sm, sp, out, idx);
    hipLaunchKernelGGL(k_sf_partial, dim3(32, BB), dim3(256), 0, stream, seq, sp, partial);
    hipLaunchKernelGGL(k_featsum, dim3(BB), dim3(256), 0, stream, seq, partial, feat);
    hipLaunchKernelGGL(k_ans, dim3(64, 16), dim3(256), 0, stream, feat, w_ans0, anspart);
    hipLaunchKernelGGL(k_ansred, dim3(BB), dim3(256), 0, stream, anspart, b_ans0, w_ans1, out);
    hipLaunchKernelGGL(k_cfeat, dim3(64, 8), dim3(256), 0, stream, seq, idx, w_end0, Cpart);
    hipLaunchKernelGGL(k_cbred, dim3(80), dim3(256), 0, stream, Cpart, b_end0, Cb);
    hipLaunchKernelGGL(k_end, dim3(BB * SS / 32), dim3(512), 131072, stream,
                       seq, wpk_hi, wpk_lo, Cb, ln_g, w_end1, b_end1, p_mask, scal, em);
    hipLaunchKernelGGL(k_softmax_end, dim3(BB * KT), dim3(256), 0, stream, em, out);
}

// Round 5
// 165.844 us; speedup vs baseline: 3.9349x; 1.1390x over previous
//
#include <hip/hip_runtime.h>
#include <math.h>

#define BB 16
#define SS 512
#define HH 1024
#define KT 5
#define NEGV 1e30f

typedef __attribute__((ext_vector_type(8))) short short8_t;
typedef __attribute__((ext_vector_type(4))) float f32x4;

// ---------------- helpers ----------------
__device__ __forceinline__ float wave_sum(float v) {
    for (int off = 32; off; off >>= 1) v += __shfl_down(v, off);
    return v;
}

__device__ __forceinline__ unsigned short bf16rn(float x) {
    unsigned u = __float_as_uint(x);
    return (unsigned short)((u + 0x7fffu + ((u >> 16) & 1u)) >> 16);
}

__device__ __forceinline__ void split2(float x, unsigned short& h, unsigned short& l) {
    h = bf16rn(x);
    float hf = __uint_as_float(((unsigned)h) << 16);
    l = bf16rn(x - hf);
}

__device__ __forceinline__ float tanh_fast(float x) {
    float e = __expf(2.0f * x);
    return 1.0f - 2.0f * __builtin_amdgcn_rcpf(e + 1.0f);
}

// ---------------- k_prep: pack W0a into MFMA B-frag order (hi/lo) ----------------
// Wpk layout: [ntile(64)][kblk(32)][lane(64)][8] bf16; lane l holds
// B[kblk*32 + (l>>4)*8 + j][ntile*16 + (l&15)].
__global__ void k_prep(const float* __restrict__ w_end0,
                       short* __restrict__ wpk_hi, short* __restrict__ wpk_lo) {
    const int nt = blockIdx.x;      // 0..63 n-tile
    const int t = threadIdx.x;
    const int n_idx = t & 15;
    const int g = (t >> 4) & 3;     // k-group within kblk
    const int kq = t >> 6;
    const int kblk = blockIdx.y * 4 + kq;
    const int k0 = kblk * 32 + g * 8;
    unsigned short hs[8], ls[8];
#pragma unroll
    for (int j = 0; j < 8; ++j) {
        float v = w_end0[(size_t)(k0 + j) * HH + nt * 16 + n_idx];
        split2(v, hs[j], ls[j]);
    }
    const size_t fi = (((size_t)nt * 32 + kblk) * 64 + (g * 16 + n_idx)) * 8;
    short8_t hv, lv;
#pragma unroll
    for (int j = 0; j < 8; ++j) { hv[j] = (short)hs[j]; lv[j] = (short)ls[j]; }
    *(short8_t*)(wpk_hi + fi) = hv;
    *(short8_t*)(wpk_lo + fi) = lv;
}

// ---------------- k_scal: GW1 = sum g*w1, BW1 = sum b*w1 ----------------
__global__ void k_scal(const float* __restrict__ ln_g, const float* __restrict__ ln_b,
                       const float* __restrict__ w_end1, float* __restrict__ scal) {
    __shared__ float scr[8];
    const int t = threadIdx.x;
    float4 g = ((const float4*)ln_g)[t];
    float4 w = ((const float4*)w_end1)[t];
    float4 b = ((const float4*)ln_b)[t];
    float gw = g.x * w.x + g.y * w.y + g.z * w.z + g.w * w.w;
    float bw = b.x * w.x + b.y * w.y + b.z * w.z + b.w * w.w;
    gw = wave_sum(gw);
    bw = wave_sum(bw);
    if ((t & 63) == 0) { scr[t >> 6] = gw; scr[4 + (t >> 6)] = bw; }
    __syncthreads();
    if (t == 0) {
        scal[0] = scr[0] + scr[1] + scr[2] + scr[3];
        scal[1] = scr[4] + scr[5] + scr[6] + scr[7];
    }
}

// ---------------- kernel 1: start logits + mask (wave per row) ----------------
__global__ void k_start_logits(const float* __restrict__ seq, const float* __restrict__ pm,
                               const float* __restrict__ w_start, const float* __restrict__ b_start,
                               float* __restrict__ sm) {
    const int t = threadIdx.x;
    const int l = t & 63;
    const int row = blockIdx.x * 4 + (t >> 6);
    const float4* rp = (const float4*)(seq + (size_t)row * HH);
    const float4* wp = (const float4*)w_start;
    float d = 0.f;
#pragma unroll
    for (int q = 0; q < 4; ++q) {
        float4 a = rp[q * 64 + l];
        float4 w = wp[q * 64 + l];
        d += a.x * w.x + a.y * w.y + a.z * w.z + a.w * w.w;
    }
    d = wave_sum(d);
    if (l == 0) {
        float m = pm[row];
        sm[row] = (d + b_start[0]) * (1.f - m) - NEGV * m;
    }
}

// ---------------- softmax + top-5 over 512 values (one block, 256 thr) ----------------
template <bool WRITE_P>
__device__ void softmax_topk(const float* __restrict__ x, float* __restrict__ p_out,
                             float* __restrict__ val_out, float* __restrict__ idxf_out,
                             int* __restrict__ idxi_out) {
    const int t = threadIdx.x;
    __shared__ float scr[4];
    __shared__ float sv[4];
    __shared__ int si[4];
    __shared__ int wi_s;
    float x0 = x[t], x1 = x[t + 256];

    float m = fmaxf(x0, x1);
    for (int off = 32; off; off >>= 1) m = fmaxf(m, __shfl_down(m, off));
    if ((t & 63) == 0) scr[t >> 6] = m;
    __syncthreads();
    m = fmaxf(fmaxf(scr[0], scr[1]), fmaxf(scr[2], scr[3]));
    __syncthreads();

    float e0 = expf(x0 - m), e1 = expf(x1 - m);
    float ssum = wave_sum(e0 + e1);
    if ((t & 63) == 0) scr[t >> 6] = ssum;
    __syncthreads();
    ssum = scr[0] + scr[1] + scr[2] + scr[3];
    __syncthreads();

    if (WRITE_P) {
        p_out[t] = e0 / ssum;
        p_out[t + 256] = e1 / ssum;
    }
    const float lse = m + logf(ssum);

    float v0 = x0, v1 = x1;
    for (int k = 0; k < KT; ++k) {
        float bv;
        int bi;
        if (v0 >= v1) { bv = v0; bi = t; } else { bv = v1; bi = t + 256; }
        for (int off = 32; off; off >>= 1) {
            float ov = __shfl_down(bv, off);
            int oi = __shfl_down(bi, off);
            if (ov > bv || (ov == bv && oi < bi)) { bv = ov; bi = oi; }
        }
        if ((t & 63) == 0) { sv[t >> 6] = bv; si[t >> 6] = bi; }
        __syncthreads();
        if (t == 0) {
            float fv = sv[0];
            int fi = si[0];
            for (int w = 1; w < 4; ++w)
                if (sv[w] > fv || (sv[w] == fv && si[w] < fi)) { fv = sv[w]; fi = si[w]; }
            wi_s = fi;
            val_out[k] = fv - lse;
            idxf_out[k] = (float)fi;
            if (idxi_out) idxi_out[k] = fi;
        }
        __syncthreads();
        const int wi = wi_s;
        if (wi == t) v0 = -INFINITY;
        else if (wi == t + 256) v1 = -INFINITY;
        __syncthreads();
    }
}

__global__ void k_softmax_start(const float* __restrict__ sm, float* __restrict__ sp,
                                float* __restrict__ dout, int* __restrict__ idx) {
    const int b = blockIdx.x;
    softmax_topk<true>(sm + (size_t)b * SS, sp + (size_t)b * SS,
                       dout + b * KT, dout + 80 + b * KT, idx + b * KT);
}

__global__ void k_softmax_end(const float* __restrict__ em, float* __restrict__ dout) {
    const int bk = blockIdx.x;
    const int b = bk / KT, k = bk % KT;
    softmax_topk<false>(em + (size_t)bk * SS, nullptr,
                        dout + 160 + b * 25 + k * KT, dout + 560 + b * 25 + k * KT, nullptr);
}

// ---------------- start_feature partial sums (16-row chunks, 512 blocks) ----------------
__global__ void k_sf_partial(const float* __restrict__ seq, const float* __restrict__ sp,
                             float* __restrict__ partial) {
    const int chunk = blockIdx.x;  // 0..31
    const int b = blockIdx.y;
    const int t = threadIdx.x;
    __shared__ float p[16];
    if (t < 16) p[t] = sp[b * SS + chunk * 16 + t];
    __syncthreads();
    float4 acc = make_float4(0.f, 0.f, 0.f, 0.f);
    const float4* base = (const float4*)(seq + ((size_t)b * SS + chunk * 16) * HH);
    for (int s = 0; s < 16; ++s) {
        float4 v = base[(size_t)s * 256 + t];
        float ps = p[s];
        acc.x = fmaf(ps, v.x, acc.x);
        acc.y = fmaf(ps, v.y, acc.y);
        acc.z = fmaf(ps, v.z, acc.z);
        acc.w = fmaf(ps, v.w, acc.w);
    }
    ((float4*)partial)[(size_t)(b * 32 + chunk) * 256 + t] = acc;
}

// ---------------- k_featsum: feat[b][0:1024]=start_feature, [1024:2048]=cls ----------------
__global__ void k_featsum(const float* __restrict__ seq, const float* __restrict__ partial,
                          float* __restrict__ feat) {
    const int b = blockIdx.x, t = threadIdx.x;
    for (int q = 0; q < 4; ++q) {
        const int h = q * 256 + t;
        float s = 0.f;
        for (int c = 0; c < 32; ++c) s += partial[(size_t)(b * 32 + c) * HH + h];
        feat[(size_t)b * 2048 + h] = s;
        feat[(size_t)b * 2048 + HH + h] = seq[(size_t)b * SS * HH + h];
    }
}

// ---------------- k_ans: ans-head GEMM partials, K-split (64 x 16 blocks) ----------------
__global__ void k_ans(const float* __restrict__ feat, const float* __restrict__ w_ans0,
                      float* __restrict__ anspart) {
    __shared__ float A[16 * 132];
    __shared__ float W[16 * 132];
    const int c = blockIdx.x;   // 0..63 col chunk of 16
    const int kc = blockIdx.y;  // 0..15 K chunk of 128 (over 2048)
    const int t = threadIdx.x;
#pragma unroll
    for (int i = 0; i < 8; ++i) {
        const int e = i * 256 + t;
        const int b = e >> 7, d = e & 127;
        A[b * 132 + d] = feat[(size_t)b * 2048 + kc * 128 + d];
    }
#pragma unroll
    for (int p = 0; p < 8; ++p) {
        const int e = p * 256 + t;
        const int d = e >> 4, j = e & 15;
        W[j * 132 + d] = w_ans0[(size_t)(kc * 128 + d) * HH + c * 16 + j];
    }
    __syncthreads();
    const int j = t & 15, b = t >> 4;
    const float4* A4 = (const float4*)A;  // stride 33 float4
    const float4* W4 = (const float4*)W;
    float acc = 0.f;
    for (int d4 = 0; d4 < 32; ++d4) {
        float4 wv = W4[j * 33 + d4];
        float4 av = A4[b * 33 + d4];
        acc += av.x * wv.x + av.y * wv.y + av.z * wv.z + av.w * wv.w;
    }
    anspart[((size_t)kc * 16 + b) * HH + c * 16 + j] = acc;
}

__global__ void k_ansred(const float* __restrict__ anspart, const float* __restrict__ b_ans0,
                         const float* __restrict__ w_ans1, float* __restrict__ out) {
    __shared__ float scr[4];
    const int b = blockIdx.x;
    const int t = threadIdx.x;
    float dsum = 0.f;
#pragma unroll
    for (int q = 0; q < 4; ++q) {
        const int h = q * 256 + t;
        float s = b_ans0[h];
#pragma unroll
        for (int kc = 0; kc < 16; ++kc) s += anspart[((size_t)kc * 16 + b) * HH + h];
        dsum += tanhf(s) * w_ans1[h];
    }
    dsum = wave_sum(dsum);
    if ((t & 63) == 0) scr[t >> 6] = dsum;
    __syncthreads();
    if (t == 0) out[960 + b] = scr[0] + scr[1] + scr[2] + scr[3];
}

// ---------------- k_cfeat: Cb partials, K-split (64 x 8 blocks) ----------------
__global__ void k_cfeat(const float* __restrict__ seq, const int* __restrict__ idx,
                        const float* __restrict__ w_end0, float* __restrict__ Cpart) {
    __shared__ float A[80 * 132];
    __shared__ float W[16 * 132];
    __shared__ int growL[80];
    const int c = blockIdx.x;   // 0..63 col chunk of 16
    const int kc = blockIdx.y;  // 0..7 K chunk of 128
    const int t = threadIdx.x;
    if (t < 80) growL[t] = (t / KT) * SS + idx[t];
    __syncthreads();
    for (int i = 0; i < 40; ++i) {
        const int e = i * 256 + t;
        const int r = e >> 7, d = e & 127;
        A[r * 132 + d] = seq[(size_t)growL[r] * HH + kc * 128 + d];
    }
#pragma unroll
    for (int p = 0; p < 8; ++p) {
        const int e = p * 256 + t;
        const int d = e >> 4, j = e & 15;
        W[j * 132 + d] = w_end0[(size_t)(HH + kc * 128 + d) * HH + c * 16 + j];
    }
    __syncthreads();
    const int j = t & 15, rg = t >> 4;
    const float4* A4 = (const float4*)A;
    const float4* W4 = (const float4*)W;
    float acc[5] = {0.f, 0.f, 0.f, 0.f, 0.f};
    for (int d4 = 0; d4 < 32; ++d4) {
        float4 wv = W4[j * 33 + d4];
#pragma unroll
        for (int i = 0; i < 5; ++i) {
            float4 av = A4[(rg + 16 * i) * 33 + d4];
            acc[i] += av.x * wv.x + av.y * wv.y + av.z * wv.z + av.w * wv.w;
        }
    }
#pragma unroll
    for (int i = 0; i < 5; ++i)
        Cpart[((size_t)kc * 80 + rg + 16 * i) * HH + c * 16 + j] = acc[i];
}

__global__ void k_cbred(const float* __restrict__ Cpart, const float* __restrict__ b_end0,
                        float* __restrict__ Cb) {
    const int bk = blockIdx.x;  // 0..79
    const int t = threadIdx.x;
#pragma unroll
    for (int q = 0; q < 4; ++q) {
        const int h = q * 256 + t;
        float s = b_end0[h];
#pragma unroll
        for (int kc = 0; kc < 8; ++kc) s += Cpart[((size_t)kc * 80 + bk) * HH + h];
        Cb[(size_t)bk * HH + h] = s;
    }
}

// ---------------- k_gemm: 2D-tiled split-bf16 MFMA GEMM, LDS double-buffered ----------------
// Tile BM=128 x BN=128, BK=32, 4 waves (2x2), wave tile 64x64.
// Per buffer (32 KB): A [hl2][mtl8][1KB frag], W at +16KB [hl2][ntl8][1KB frag].
// Each block emits partial (S,Q,G) col-sums for its 128 cols: part[bn][row][k][4].
__global__ __launch_bounds__(256, 2)
void k_gemm(const float* __restrict__ seq, const short* __restrict__ wpk_hi,
            const short* __restrict__ wpk_lo, const float* __restrict__ Cb,
            const float* __restrict__ ln_g, const float* __restrict__ w_end1,
            float* __restrict__ part) {
    extern __shared__ char lds[];  // 65536
    const int t = threadIdx.x;
    const int l = t & 63, w = t >> 6;
    const int wr = w >> 1, wc = w & 1;
    const int bid = blockIdx.x;
    const int bm = bid >> 3, bn = bid & 7;
    const int row0 = bm * 128;
    const int b = row0 >> 9;

    f32x4 acc[4][4];
#pragma unroll
    for (int m = 0; m < 4; ++m)
#pragma unroll
        for (int n = 0; n < 4; ++n) acc[m][n] = (f32x4){0.f, 0.f, 0.f, 0.f};

    // staged registers
    float4 aR[4];
    short8_t wR[4];

    // ---- load helpers (all-static indices) ----
#define LOADA(ks, ar)                                                              \
    {                                                                              \
        _Pragma("unroll") for (int j = 0; j < 4; ++j) {                            \
            const int f4 = j * 256 + t;                                            \
            const int row = f4 >> 3, kk0 = (f4 & 7) * 4;                           \
            ar[j] = *(const float4*)(seq + (size_t)(row0 + row) * HH + (ks) * 32 + kk0); \
        }                                                                          \
    }
#define LOADW(ks, wv)                                                              \
    {                                                                              \
        _Pragma("unroll") for (int j = 0; j < 4; ++j) {                            \
            const int off = (j * 256 + t) * 16;                                    \
            const int f = off >> 10, rem = off & 1023;                             \
            const short* wb = (f < 8) ? wpk_hi : wpk_lo;                           \
            const int ntl = f & 7;                                                 \
            wv[j] = *(const short8_t*)(wb + (((size_t)(bn * 8 + ntl) * 32 + (ks)) << 9) + (rem >> 1)); \
        }                                                                          \
    }
#define WRITEB(buf, ar, wv)                                                        \
    {                                                                              \
        char* base_ = lds + (buf) * 32768;                                         \
        _Pragma("unroll") for (int j = 0; j < 4; ++j) {                            \
            const int f4 = j * 256 + t;                                            \
            const int row = f4 >> 3, kk0 = (f4 & 7) * 4;                           \
            const int lane = (row & 15) + ((kk0 >> 3) << 4);                       \
            const int boff = ((row >> 4) << 10) + (lane << 4) + ((kk0 & 7) << 1);  \
            unsigned short h0, l0, h1, l1, h2, l2, h3, l3;                         \
            split2(ar[j].x, h0, l0);                                               \
            split2(ar[j].y, h1, l1);                                               \
            split2(ar[j].z, h2, l2);                                               \
            split2(ar[j].w, h3, l3);                                               \
            *(short4*)(base_ + boff) = make_short4((short)h0, (short)h1, (short)h2, (short)h3); \
            *(short4*)(base_ + 8192 + boff) = make_short4((short)l0, (short)l1, (short)l2, (short)l3); \
            *(short8_t*)(base_ + 16384 + (j * 256 + t) * 16) = wv[j];              \
        }                                                                          \
    }

    // prologue: stage ks=0 into buf 0
    LOADA(0, aR);
    LOADW(0, wR);
    WRITEB(0, aR, wR);
    __syncthreads();

    for (int ks = 0; ks < 32; ++ks) {
        const int buf = ks & 1;
        if (ks < 31) {
            LOADA(ks + 1, aR);
            LOADW(ks + 1, wR);
        }
        // compute current buffer
        {
            const char* base_ = lds + buf * 32768;
            short8_t ah[4], al[4], wh[4], wl[4];
#pragma unroll
            for (int m = 0; m < 4; ++m) {
                const int mtl = wr * 4 + m;
                ah[m] = *(const short8_t*)(base_ + (mtl << 10) + (l << 4));
                al[m] = *(const short8_t*)(base_ + 8192 + (mtl << 10) + (l << 4));
            }
#pragma unroll
            for (int n = 0; n < 4; ++n) {
                const int ntl = wc * 4 + n;
                wh[n] = *(const short8_t*)(base_ + 16384 + (ntl << 10) + (l << 4));
                wl[n] = *(const short8_t*)(base_ + 24576 + (ntl << 10) + (l << 4));
            }
#pragma unroll
            for (int n = 0; n < 4; ++n)
#pragma unroll
                for (int m = 0; m < 4; ++m) {
                    acc[m][n] = __builtin_amdgcn_mfma_f32_16x16x32_bf16(ah[m], wh[n], acc[m][n], 0, 0, 0);
                    acc[m][n] = __builtin_amdgcn_mfma_f32_16x16x32_bf16(al[m], wh[n], acc[m][n], 0, 0, 0);
                    acc[m][n] = __builtin_amdgcn_mfma_f32_16x16x32_bf16(ah[m], wl[n], acc[m][n], 0, 0, 0);
                }
        }
        if (ks < 31) WRITEB(buf ^ 1, aR, wR);
        __syncthreads();
    }

    // ---- epilogue: per-block partial (S,Q,G) over this 128-col slice ----
    float cbv[KT][4], gwv[4];
#pragma unroll
    for (int n = 0; n < 4; ++n) {
        const int col = bn * 128 + wc * 64 + n * 16 + (l & 15);
        gwv[n] = ln_g[col] * w_end1[col];
#pragma unroll
        for (int k = 0; k < KT; ++k) cbv[k][n] = Cb[(size_t)(b * KT + k) * HH + col];
    }
    float* scr = (float*)lds;  // [wc 2][row 128][k 5][3]

    for (int k = 0; k < KT; ++k) {
        float S[4][4], Q[4][4], G[4][4];
#pragma unroll
        for (int m = 0; m < 4; ++m)
#pragma unroll
            for (int r = 0; r < 4; ++r) { S[m][r] = 0.f; Q[m][r] = 0.f; G[m][r] = 0.f; }
#pragma unroll
        for (int n = 0; n < 4; ++n) {
            const float cb = cbv[k][n];
            const float gwn = gwv[n];
#pragma unroll
            for (int m = 0; m < 4; ++m)
#pragma unroll
                for (int r = 0; r < 4; ++r) {
                    float v = tanh_fast(acc[m][n][r] + cb);
                    S[m][r] += v;
                    Q[m][r] += v * v;
                    G[m][r] += v * gwn;
                }
        }
        for (int msk = 1; msk < 16; msk <<= 1) {
#pragma unroll
            for (int m = 0; m < 4; ++m)
#pragma unroll
                for (int r = 0; r < 4; ++r) {
                    S[m][r] += __shfl_xor(S[m][r], msk);
                    Q[m][r] += __shfl_xor(Q[m][r], msk);
                    G[m][r] += __shfl_xor(G[m][r], msk);
                }
        }
        if ((l & 15) == 0) {
            const int gg = l >> 4;
#pragma unroll
            for (int m = 0; m < 4; ++m)
#pragma unroll
                for (int r = 0; r < 4; ++r) {
                    const int row = wr * 64 + m * 16 + gg * 4 + r;
                    float* sp_ = scr + ((wc * 128 + row) * KT + k) * 3;
                    sp_[0] = S[m][r];
                    sp_[1] = Q[m][r];
                    sp_[2] = G[m][r];
                }
        }
    }
    __syncthreads();

#pragma unroll
    for (int i = 0; i < 3; ++i) {
        const int idx = i * 256 + t;  // 640 = 128 rows * 5 k
        if (idx < 128 * KT) {
            const int row = idx / KT, k = idx % KT;
            const float* a_ = scr + ((0 * 128 + row) * KT + k) * 3;
            const float* b_ = scr + ((1 * 128 + row) * KT + k) * 3;
            float4 o;
            o.x = a_[0] + b_[0];
            o.y = a_[1] + b_[1];
            o.z = a_[2] + b_[2];
            o.w = 0.f;
            *(float4*)(part + (((size_t)bn * (BB * SS) + row0 + row) * KT + k) * 4) = o;
        }
    }
#undef LOADA
#undef LOADW
#undef WRITEB
}

// ---------------- k_epi2: combine 8 col-slice partials -> LN logit -> mask -> em ----------------
__global__ void k_epi2(const float* __restrict__ part, const float* __restrict__ p_mask,
                       const float* __restrict__ scal, const float* __restrict__ b_end1,
                       float* __restrict__ em) {
    const int bk = blockIdx.x;  // 0..79
    const int b = bk / KT, k = bk % KT;
    const int t = threadIdx.x;
    const float GW1 = scal[0], BW1 = scal[1], be1 = b_end1[0];
#pragma unroll
    for (int h = 0; h < 2; ++h) {
        const int s = h * 256 + t;
        const int row = b * SS + s;
        float S = 0.f, Q = 0.f, G = 0.f;
#pragma unroll
        for (int bn = 0; bn < 8; ++bn) {
            float4 v = *(const float4*)(part + (((size_t)bn * (BB * SS) + row) * KT + k) * 4);
            S += v.x;
            Q += v.y;
            G += v.z;
        }
        const float mu = S * (1.f / HH);
        const float var = Q * (1.f / HH) - mu * mu;
        const float rs = rsqrtf(var + 1e-12f);
        const float logit = rs * (G - mu * GW1) + BW1 + be1;
        const float pm = p_mask[row];
        em[(size_t)bk * SS + s] = logit * (1.f - pm) - NEGV * pm;
    }
}

// ---------------- launch ----------------
extern "C" void kernel_launch(void* const* d_in, const int* in_sizes, int n_in,
                              void* d_out, int out_size, void* d_ws, size_t ws_size,
                              hipStream_t stream) {
    const float* seq     = (const float*)d_in[0];
    const float* p_mask  = (const float*)d_in[1];
    const float* w_start = (const float*)d_in[2];
    const float* b_start = (const float*)d_in[3];
    const float* w_end0  = (const float*)d_in[4];
    const float* b_end0  = (const float*)d_in[5];
    const float* ln_g    = (const float*)d_in[6];
    const float* ln_b    = (const float*)d_in[7];
    const float* w_end1  = (const float*)d_in[8];
    const float* b_end1  = (const float*)d_in[9];
    const float* w_ans0  = (const float*)d_in[10];
    const float* b_ans0  = (const float*)d_in[11];
    const float* w_ans1  = (const float*)d_in[12];
    float* out = (float*)d_out;

    float* sm      = (float*)d_ws;                  // 8192
    float* sp      = sm + BB * SS;                  // 8192
    float* partial = sp + BB * SS;                  // 16*32*1024 = 524288
    float* feat    = partial + BB * 32 * HH;        // 32768
    float* Cb      = feat + BB * 2048;              // 81920
    float* Cpart   = Cb + 80 * HH;                  // 655360
    float* anspart = Cpart + 8 * 80 * HH;           // 262144
    float* em      = anspart + 16 * BB * HH;        // 40960
    float* scal    = em + BB * KT * SS;             // 16
    int*   idx     = (int*)(scal + 16);             // 80
    float* part    = (float*)(((uintptr_t)(idx + 80) + 255) & ~(uintptr_t)255);  // 8*8192*5*4 = 1310720
    short* wpk_hi  = (short*)(part + 8 * BB * SS * KT * 4);
    short* wpk_lo  = wpk_hi + (1 << 20);            // 1M bf16 each

    hipLaunchKernelGGL(k_prep, dim3(64, 8), dim3(256), 0, stream, w_end0, wpk_hi, wpk_lo);
    hipLaunchKernelGGL(k_scal, dim3(1), dim3(256), 0, stream, ln_g, ln_b, w_end1, scal);
    hipLaunchKernelGGL(k_start_logits, dim3(BB * SS / 4), dim3(256), 0, stream,
                       seq, p_mask, w_start, b_start, sm);
    hipLaunchKernelGGL(k_softmax_start, dim3(BB), dim3(256), 0, stream, sm, sp, out, idx);
    hipLaunchKernelGGL(k_sf_partial, dim3(32, BB), dim3(256), 0, stream, seq, sp, partial);
    hipLaunchKernelGGL(k_featsum, dim3(BB), dim3(256), 0, stream, seq, partial, feat);
    hipLaunchKernelGGL(k_ans, dim3(64, 16), dim3(256), 0, stream, feat, w_ans0, anspart);
    hipLaunchKernelGGL(k_ansred, dim3(BB), dim3(256), 0, stream, anspart, b_ans0, w_ans1, out);
    hipLaunchKernelGGL(k_cfeat, dim3(64, 8), dim3(256), 0, stream, seq, idx, w_end0, Cpart);
    hipLaunchKernelGGL(k_cbred, dim3(80), dim3(256), 0, stream, Cpart, b_end0, Cb);
    hipLaunchKernelGGL(k_gemm, dim3(64 * 8), dim3(256), 65536, stream,
                       seq, wpk_hi, wpk_lo, Cb, ln_g, w_end1, part);
    hipLaunchKernelGGL(k_epi2, dim3(BB * KT), dim3(256), 0, stream,
                       part, p_mask, scal, b_end1, em);
    hipLaunchKernelGGL(k_softmax_end, dim3(BB * KT), dim3(256), 0, stream, em, out);
}

// Round 6
// 161.243 us; speedup vs baseline: 4.0472x; 1.0285x over previous
//
#include <hip/hip_runtime.h>
#include <math.h>

#define BB 16
#define SS 512
#define HH 1024
#define KT 5
#define NEGV 1e30f

typedef __attribute__((ext_vector_type(8))) short short8_t;
typedef __attribute__((ext_vector_type(4))) float f32x4;

// ---------------- helpers ----------------
__device__ __forceinline__ float wave_sum(float v) {
    for (int off = 32; off; off >>= 1) v += __shfl_down(v, off);
    return v;
}

__device__ __forceinline__ unsigned short bf16rn(float x) {
    unsigned u = __float_as_uint(x);
    return (unsigned short)((u + 0x7fffu + ((u >> 16) & 1u)) >> 16);
}

__device__ __forceinline__ void split2(float x, unsigned short& h, unsigned short& l) {
    h = bf16rn(x);
    float hf = __uint_as_float(((unsigned)h) << 16);
    l = bf16rn(x - hf);
}

__device__ __forceinline__ float tanh_fast(float x) {
    float e = __expf(2.0f * x);
    return 1.0f - 2.0f * __builtin_amdgcn_rcpf(e + 1.0f);
}

// async global->LDS, 16B per lane; lds dst must be wave-uniform base
__device__ __forceinline__ void gld16(const short* g, char* l) {
    __builtin_amdgcn_global_load_lds((const __attribute__((address_space(1))) void*)g,
                                     (__attribute__((address_space(3))) void*)l, 16, 0, 0);
}

// ---------------- k_prep: pack W0a into MFMA B-frag order (hi/lo) ----------------
// Wpk layout: [ntile(64)][kblk(32)][lane(64)][8] bf16; lane l holds
// B[kblk*32 + (l>>4)*8 + j][ntile*16 + (l&15)].
__global__ void k_prep(const float* __restrict__ w_end0,
                       short* __restrict__ wpk_hi, short* __restrict__ wpk_lo) {
    const int nt = blockIdx.x;      // 0..63 n-tile
    const int t = threadIdx.x;
    const int n_idx = t & 15;
    const int g = (t >> 4) & 3;     // k-group within kblk
    const int kq = t >> 6;
    const int kblk = blockIdx.y * 4 + kq;
    const int k0 = kblk * 32 + g * 8;
    unsigned short hs[8], ls[8];
#pragma unroll
    for (int j = 0; j < 8; ++j) {
        float v = w_end0[(size_t)(k0 + j) * HH + nt * 16 + n_idx];
        split2(v, hs[j], ls[j]);
    }
    const size_t fi = (((size_t)nt * 32 + kblk) * 64 + (g * 16 + n_idx)) * 8;
    short8_t hv, lv;
#pragma unroll
    for (int j = 0; j < 8; ++j) { hv[j] = (short)hs[j]; lv[j] = (short)ls[j]; }
    *(short8_t*)(wpk_hi + fi) = hv;
    *(short8_t*)(wpk_lo + fi) = lv;
}

// ---------------- k_seqpk: pack seq into MFMA A-frag order (hi/lo) ----------------
// Apk layout: [bm(64)][ks(32)][mtl(8)][lane(64)][8] bf16; lane l holds
// A[bm*128 + mtl*16 + (l&15)][ks*32 + (l>>4)*8 + j].
__global__ void k_seqpk(const float* __restrict__ seq,
                        short* __restrict__ apk_hi, short* __restrict__ apk_lo) {
    const size_t g = (size_t)blockIdx.x * 256 + threadIdx.x;  // 0..1M-1
    const int l = g & 63;
    const int mtl = (g >> 6) & 7;
    const int ks = (g >> 9) & 31;
    const int bm = g >> 14;
    const int row = bm * 128 + mtl * 16 + (l & 15);
    const int k0 = ks * 32 + (l >> 4) * 8;
    const float4 v0 = *(const float4*)(seq + (size_t)row * HH + k0);
    const float4 v1 = *(const float4*)(seq + (size_t)row * HH + k0 + 4);
    unsigned short h[8], lo[8];
    split2(v0.x, h[0], lo[0]);
    split2(v0.y, h[1], lo[1]);
    split2(v0.z, h[2], lo[2]);
    split2(v0.w, h[3], lo[3]);
    split2(v1.x, h[4], lo[4]);
    split2(v1.y, h[5], lo[5]);
    split2(v1.z, h[6], lo[6]);
    split2(v1.w, h[7], lo[7]);
    short8_t hv, lv;
#pragma unroll
    for (int j = 0; j < 8; ++j) { hv[j] = (short)h[j]; lv[j] = (short)lo[j]; }
    *(short8_t*)(apk_hi + g * 8) = hv;
    *(short8_t*)(apk_lo + g * 8) = lv;
}

// ---------------- k_scal: GW1 = sum g*w1, BW1 = sum b*w1 ----------------
__global__ void k_scal(const float* __restrict__ ln_g, const float* __restrict__ ln_b,
                       const float* __restrict__ w_end1, float* __restrict__ scal) {
    __shared__ float scr[8];
    const int t = threadIdx.x;
    float4 g = ((const float4*)ln_g)[t];
    float4 w = ((const float4*)w_end1)[t];
    float4 b = ((const float4*)ln_b)[t];
    float gw = g.x * w.x + g.y * w.y + g.z * w.z + g.w * w.w;
    float bw = b.x * w.x + b.y * w.y + b.z * w.z + b.w * w.w;
    gw = wave_sum(gw);
    bw = wave_sum(bw);
    if ((t & 63) == 0) { scr[t >> 6] = gw; scr[4 + (t >> 6)] = bw; }
    __syncthreads();
    if (t == 0) {
        scal[0] = scr[0] + scr[1] + scr[2] + scr[3];
        scal[1] = scr[4] + scr[5] + scr[6] + scr[7];
    }
}

// ---------------- kernel 1: start logits + mask (wave per row) ----------------
__global__ void k_start_logits(const float* __restrict__ seq, const float* __restrict__ pm,
                               const float* __restrict__ w_start, const float* __restrict__ b_start,
                               float* __restrict__ sm) {
    const int t = threadIdx.x;
    const int l = t & 63;
    const int row = blockIdx.x * 4 + (t >> 6);
    const float4* rp = (const float4*)(seq + (size_t)row * HH);
    const float4* wp = (const float4*)w_start;
    float d = 0.f;
#pragma unroll
    for (int q = 0; q < 4; ++q) {
        float4 a = rp[q * 64 + l];
        float4 w = wp[q * 64 + l];
        d += a.x * w.x + a.y * w.y + a.z * w.z + a.w * w.w;
    }
    d = wave_sum(d);
    if (l == 0) {
        float m = pm[row];
        sm[row] = (d + b_start[0]) * (1.f - m) - NEGV * m;
    }
}

// ---------------- softmax + top-5 over 512 values (one block, 256 thr) ----------------
template <bool WRITE_P>
__device__ void softmax_topk(const float* __restrict__ x, float* __restrict__ p_out,
                             float* __restrict__ val_out, float* __restrict__ idxf_out,
                             int* __restrict__ idxi_out) {
    const int t = threadIdx.x;
    __shared__ float scr[4];
    __shared__ float sv[4];
    __shared__ int si[4];
    __shared__ int wi_s;
    float x0 = x[t], x1 = x[t + 256];

    float m = fmaxf(x0, x1);
    for (int off = 32; off; off >>= 1) m = fmaxf(m, __shfl_down(m, off));
    if ((t & 63) == 0) scr[t >> 6] = m;
    __syncthreads();
    m = fmaxf(fmaxf(scr[0], scr[1]), fmaxf(scr[2], scr[3]));
    __syncthreads();

    float e0 = expf(x0 - m), e1 = expf(x1 - m);
    float ssum = wave_sum(e0 + e1);
    if ((t & 63) == 0) scr[t >> 6] = ssum;
    __syncthreads();
    ssum = scr[0] + scr[1] + scr[2] + scr[3];
    __syncthreads();

    if (WRITE_P) {
        p_out[t] = e0 / ssum;
        p_out[t + 256] = e1 / ssum;
    }
    const float lse = m + logf(ssum);

    float v0 = x0, v1 = x1;
    for (int k = 0; k < KT; ++k) {
        float bv;
        int bi;
        if (v0 >= v1) { bv = v0; bi = t; } else { bv = v1; bi = t + 256; }
        for (int off = 32; off; off >>= 1) {
            float ov = __shfl_down(bv, off);
            int oi = __shfl_down(bi, off);
            if (ov > bv || (ov == bv && oi < bi)) { bv = ov; bi = oi; }
        }
        if ((t & 63) == 0) { sv[t >> 6] = bv; si[t >> 6] = bi; }
        __syncthreads();
        if (t == 0) {
            float fv = sv[0];
            int fi = si[0];
            for (int w = 1; w < 4; ++w)
                if (sv[w] > fv || (sv[w] == fv && si[w] < fi)) { fv = sv[w]; fi = si[w]; }
            wi_s = fi;
            val_out[k] = fv - lse;
            idxf_out[k] = (float)fi;
            if (idxi_out) idxi_out[k] = fi;
        }
        __syncthreads();
        const int wi = wi_s;
        if (wi == t) v0 = -INFINITY;
        else if (wi == t + 256) v1 = -INFINITY;
        __syncthreads();
    }
}

__global__ void k_softmax_start(const float* __restrict__ sm, float* __restrict__ sp,
                                float* __restrict__ dout, int* __restrict__ idx) {
    const int b = blockIdx.x;
    softmax_topk<true>(sm + (size_t)b * SS, sp + (size_t)b * SS,
                       dout + b * KT, dout + 80 + b * KT, idx + b * KT);
}

__global__ void k_softmax_end(const float* __restrict__ em, float* __restrict__ dout) {
    const int bk = blockIdx.x;
    const int b = bk / KT, k = bk % KT;
    softmax_topk<false>(em + (size_t)bk * SS, nullptr,
                        dout + 160 + b * 25 + k * KT, dout + 560 + b * 25 + k * KT, nullptr);
}

// ---------------- start_feature partial sums (16-row chunks, 512 blocks) ----------------
__global__ void k_sf_partial(const float* __restrict__ seq, const float* __restrict__ sp,
                             float* __restrict__ partial) {
    const int chunk = blockIdx.x;  // 0..31
    const int b = blockIdx.y;
    const int t = threadIdx.x;
    __shared__ float p[16];
    if (t < 16) p[t] = sp[b * SS + chunk * 16 + t];
    __syncthreads();
    float4 acc = make_float4(0.f, 0.f, 0.f, 0.f);
    const float4* base = (const float4*)(seq + ((size_t)b * SS + chunk * 16) * HH);
    for (int s = 0; s < 16; ++s) {
        float4 v = base[(size_t)s * 256 + t];
        float ps = p[s];
        acc.x = fmaf(ps, v.x, acc.x);
        acc.y = fmaf(ps, v.y, acc.y);
        acc.z = fmaf(ps, v.z, acc.z);
        acc.w = fmaf(ps, v.w, acc.w);
    }
    ((float4*)partial)[(size_t)(b * 32 + chunk) * 256 + t] = acc;
}

// ---------------- k_featsum: feat[b][0:1024]=start_feature, [1024:2048]=cls ----------------
__global__ void k_featsum(const float* __restrict__ seq, const float* __restrict__ partial,
                          float* __restrict__ feat) {
    const int b = blockIdx.x, t = threadIdx.x;
    for (int q = 0; q < 4; ++q) {
        const int h = q * 256 + t;
        float s = 0.f;
        for (int c = 0; c < 32; ++c) s += partial[(size_t)(b * 32 + c) * HH + h];
        feat[(size_t)b * 2048 + h] = s;
        feat[(size_t)b * 2048 + HH + h] = seq[(size_t)b * SS * HH + h];
    }
}

// ---------------- k_ans: ans-head GEMM partials, K-split (64 x 16 blocks) ----------------
__global__ void k_ans(const float* __restrict__ feat, const float* __restrict__ w_ans0,
                      float* __restrict__ anspart) {
    __shared__ float A[16 * 132];
    __shared__ float W[16 * 132];
    const int c = blockIdx.x;   // 0..63 col chunk of 16
    const int kc = blockIdx.y;  // 0..15 K chunk of 128 (over 2048)
    const int t = threadIdx.x;
#pragma unroll
    for (int i = 0; i < 8; ++i) {
        const int e = i * 256 + t;
        const int b = e >> 7, d = e & 127;
        A[b * 132 + d] = feat[(size_t)b * 2048 + kc * 128 + d];
    }
#pragma unroll
    for (int p = 0; p < 8; ++p) {
        const int e = p * 256 + t;
        const int d = e >> 4, j = e & 15;
        W[j * 132 + d] = w_ans0[(size_t)(kc * 128 + d) * HH + c * 16 + j];
    }
    __syncthreads();
    const int j = t & 15, b = t >> 4;
    const float4* A4 = (const float4*)A;  // stride 33 float4
    const float4* W4 = (const float4*)W;
    float acc = 0.f;
    for (int d4 = 0; d4 < 32; ++d4) {
        float4 wv = W4[j * 33 + d4];
        float4 av = A4[b * 33 + d4];
        acc += av.x * wv.x + av.y * wv.y + av.z * wv.z + av.w * wv.w;
    }
    anspart[((size_t)kc * 16 + b) * HH + c * 16 + j] = acc;
}

__global__ void k_ansred(const float* __restrict__ anspart, const float* __restrict__ b_ans0,
                         const float* __restrict__ w_ans1, float* __restrict__ out) {
    __shared__ float scr[4];
    const int b = blockIdx.x;
    const int t = threadIdx.x;
    float dsum = 0.f;
#pragma unroll
    for (int q = 0; q < 4; ++q) {
        const int h = q * 256 + t;
        float s = b_ans0[h];
#pragma unroll
        for (int kc = 0; kc < 16; ++kc) s += anspart[((size_t)kc * 16 + b) * HH + h];
        dsum += tanhf(s) * w_ans1[h];
    }
    dsum = wave_sum(dsum);
    if ((t & 63) == 0) scr[t >> 6] = dsum;
    __syncthreads();
    if (t == 0) out[960 + b] = scr[0] + scr[1] + scr[2] + scr[3];
}

// ---------------- k_cfeat: Cb partials, K-split (64 x 8 blocks) ----------------
__global__ void k_cfeat(const float* __restrict__ seq, const int* __restrict__ idx,
                        const float* __restrict__ w_end0, float* __restrict__ Cpart) {
    __shared__ float A[80 * 132];
    __shared__ float W[16 * 132];
    __shared__ int growL[80];
    const int c = blockIdx.x;   // 0..63 col chunk of 16
    const int kc = blockIdx.y;  // 0..7 K chunk of 128
    const int t = threadIdx.x;
    if (t < 80) growL[t] = (t / KT) * SS + idx[t];
    __syncthreads();
    for (int i = 0; i < 40; ++i) {
        const int e = i * 256 + t;
        const int r = e >> 7, d = e & 127;
        A[r * 132 + d] = seq[(size_t)growL[r] * HH + kc * 128 + d];
    }
#pragma unroll
    for (int p = 0; p < 8; ++p) {
        const int e = p * 256 + t;
        const int d = e >> 4, j = e & 15;
        W[j * 132 + d] = w_end0[(size_t)(HH + kc * 128 + d) * HH + c * 16 + j];
    }
    __syncthreads();
    const int j = t & 15, rg = t >> 4;
    const float4* A4 = (const float4*)A;
    const float4* W4 = (const float4*)W;
    float acc[5] = {0.f, 0.f, 0.f, 0.f, 0.f};
    for (int d4 = 0; d4 < 32; ++d4) {
        float4 wv = W4[j * 33 + d4];
#pragma unroll
        for (int i = 0; i < 5; ++i) {
            float4 av = A4[(rg + 16 * i) * 33 + d4];
            acc[i] += av.x * wv.x + av.y * wv.y + av.z * wv.z + av.w * wv.w;
        }
    }
#pragma unroll
    for (int i = 0; i < 5; ++i)
        Cpart[((size_t)kc * 80 + rg + 16 * i) * HH + c * 16 + j] = acc[i];
}

__global__ void k_cbred(const float* __restrict__ Cpart, const float* __restrict__ b_end0,
                        float* __restrict__ Cb) {
    const int bk = blockIdx.x;  // 0..79
    const int t = threadIdx.x;
#pragma unroll
    for (int q = 0; q < 4; ++q) {
        const int h = q * 256 + t;
        float s = b_end0[h];
#pragma unroll
        for (int kc = 0; kc < 8; ++kc) s += Cpart[((size_t)kc * 80 + bk) * HH + h];
        Cb[(size_t)bk * HH + h] = s;
    }
}

// ---------------- k_gemm: 2D-tiled split-bf16 MFMA GEMM ----------------
// BM=128 x BN=128, BK=32, 4 waves (2x2), wave tile 64x64. Pre-packed A and W
// fragments staged via global_load_lds (16B/lane, linear LDS), double-buffered.
// Per buffer (32 KB): AH[8][1KB] @0, AL @8K, WH @16K, WL @24K.
// XCD swizzle: each XCD owns an 8bm x 8bn square region.
__global__ __launch_bounds__(256, 2)
void k_gemm(const short* __restrict__ apk_hi, const short* __restrict__ apk_lo,
            const short* __restrict__ wpk_hi, const short* __restrict__ wpk_lo,
            const float* __restrict__ Cb, const float* __restrict__ ln_g,
            const float* __restrict__ w_end1, float* __restrict__ part) {
    extern __shared__ char smem[];  // 65536
    const int t = threadIdx.x;
    const int l = t & 63, w = t >> 6;
    const int wr = w >> 1, wc = w & 1;
    const int wg = blockIdx.x;
    const int xcd = wg & 7;
    const int local = wg >> 3;          // 0..63
    const int bm = xcd * 8 + (local >> 3);
    const int bn = local & 7;
    const int row0 = bm * 128;
    const int b = row0 >> 9;

    f32x4 acc[4][4];
#pragma unroll
    for (int m = 0; m < 4; ++m)
#pragma unroll
        for (int n = 0; n < 4; ++n) acc[m][n] = (f32x4){0.f, 0.f, 0.f, 0.f};

    // per-wave staging: 8 x global_load_lds (2 AH, 2 AL, 2 WH, 2 WL frags)
#define STAGE(buf, ks)                                                                   \
    {                                                                                    \
        const size_t abase = (size_t)(bm * 32 + (ks)) * 8 * 512;                         \
        const size_t wbase = ((size_t)(bn * 8) * 32 + (ks)) * 512;                       \
        char* lb = smem + (buf) * 32768;                                                 \
        _Pragma("unroll") for (int q = 0; q < 2; ++q) {                                  \
            const int fr = w + q * 4;                                                    \
            gld16(apk_hi + abase + fr * 512 + l * 8, lb + fr * 1024);                    \
            gld16(apk_lo + abase + fr * 512 + l * 8, lb + 8192 + fr * 1024);             \
            gld16(wpk_hi + wbase + (size_t)fr * 32 * 512 + l * 8, lb + 16384 + fr * 1024); \
            gld16(wpk_lo + wbase + (size_t)fr * 32 * 512 + l * 8, lb + 24576 + fr * 1024); \
        }                                                                                \
    }

    STAGE(0, 0);
    __syncthreads();

    for (int ks = 0; ks < 32; ++ks) {
        const int buf = ks & 1;
        if (ks < 31) STAGE(buf ^ 1, ks + 1);
        {
            const char* base_ = smem + buf * 32768;
            short8_t ah[4], al[4], wh[4], wl[4];
#pragma unroll
            for (int m = 0; m < 4; ++m) {
                const int mtl = wr * 4 + m;
                ah[m] = *(const short8_t*)(base_ + (mtl << 10) + (l << 4));
                al[m] = *(const short8_t*)(base_ + 8192 + (mtl << 10) + (l << 4));
            }
#pragma unroll
            for (int n = 0; n < 4; ++n) {
                const int ntl = wc * 4 + n;
                wh[n] = *(const short8_t*)(base_ + 16384 + (ntl << 10) + (l << 4));
                wl[n] = *(const short8_t*)(base_ + 24576 + (ntl << 10) + (l << 4));
            }
#pragma unroll
            for (int n = 0; n < 4; ++n)
#pragma unroll
                for (int m = 0; m < 4; ++m) {
                    acc[m][n] = __builtin_amdgcn_mfma_f32_16x16x32_bf16(ah[m], wh[n], acc[m][n], 0, 0, 0);
                    acc[m][n] = __builtin_amdgcn_mfma_f32_16x16x32_bf16(al[m], wh[n], acc[m][n], 0, 0, 0);
                    acc[m][n] = __builtin_amdgcn_mfma_f32_16x16x32_bf16(ah[m], wl[n], acc[m][n], 0, 0, 0);
                }
        }
        __syncthreads();
    }
#undef STAGE

    // ---- epilogue: per-block partial (S,Q,G) over this 128-col slice ----
    float cbv[KT][4], gwv[4];
#pragma unroll
    for (int n = 0; n < 4; ++n) {
        const int col = bn * 128 + wc * 64 + n * 16 + (l & 15);
        gwv[n] = ln_g[col] * w_end1[col];
#pragma unroll
        for (int k = 0; k < KT; ++k) cbv[k][n] = Cb[(size_t)(b * KT + k) * HH + col];
    }
    float* scr = (float*)smem;  // [wc 2][row 128][k 5][3]

    for (int k = 0; k < KT; ++k) {
        float S[4][4], Q[4][4], G[4][4];
#pragma unroll
        for (int m = 0; m < 4; ++m)
#pragma unroll
            for (int r = 0; r < 4; ++r) { S[m][r] = 0.f; Q[m][r] = 0.f; G[m][r] = 0.f; }
#pragma unroll
        for (int n = 0; n < 4; ++n) {
            const float cb = cbv[k][n];
            const float gwn = gwv[n];
#pragma unroll
            for (int m = 0; m < 4; ++m)
#pragma unroll
                for (int r = 0; r < 4; ++r) {
                    float v = tanh_fast(acc[m][n][r] + cb);
                    S[m][r] += v;
                    Q[m][r] += v * v;
                    G[m][r] += v * gwn;
                }
        }
        for (int msk = 1; msk < 16; msk <<= 1) {
#pragma unroll
            for (int m = 0; m < 4; ++m)
#pragma unroll
                for (int r = 0; r < 4; ++r) {
                    S[m][r] += __shfl_xor(S[m][r], msk);
                    Q[m][r] += __shfl_xor(Q[m][r], msk);
                    G[m][r] += __shfl_xor(G[m][r], msk);
                }
        }
        if ((l & 15) == 0) {
            const int gg = l >> 4;
#pragma unroll
            for (int m = 0; m < 4; ++m)
#pragma unroll
                for (int r = 0; r < 4; ++r) {
                    const int row = wr * 64 + m * 16 + gg * 4 + r;
                    float* sp_ = scr + ((wc * 128 + row) * KT + k) * 3;
                    sp_[0] = S[m][r];
                    sp_[1] = Q[m][r];
                    sp_[2] = G[m][r];
                }
        }
    }
    __syncthreads();

#pragma unroll
    for (int i = 0; i < 3; ++i) {
        const int idx = i * 256 + t;  // 640 = 128 rows * 5 k
        if (idx < 128 * KT) {
            const int row = idx / KT, k = idx % KT;
            const float* a_ = scr + ((0 * 128 + row) * KT + k) * 3;
            const float* b_ = scr + ((1 * 128 + row) * KT + k) * 3;
            float4 o;
            o.x = a_[0] + b_[0];
            o.y = a_[1] + b_[1];
            o.z = a_[2] + b_[2];
            o.w = 0.f;
            *(float4*)(part + (((size_t)bn * (BB * SS) + row0 + row) * KT + k) * 4) = o;
        }
    }
}

// ---------------- k_epi2: combine 8 col-slice partials -> LN logit -> mask -> em ----------------
__global__ void k_epi2(const float* __restrict__ part, const float* __restrict__ p_mask,
                       const float* __restrict__ scal, const float* __restrict__ b_end1,
                       float* __restrict__ em) {
    const int bk = blockIdx.x;  // 0..79
    const int b = bk / KT, k = bk % KT;
    const int t = threadIdx.x;
    const float GW1 = scal[0], BW1 = scal[1], be1 = b_end1[0];
#pragma unroll
    for (int h = 0; h < 2; ++h) {
        const int s = h * 256 + t;
        const int row = b * SS + s;
        float S = 0.f, Q = 0.f, G = 0.f;
#pragma unroll
        for (int bn = 0; bn < 8; ++bn) {
            float4 v = *(const float4*)(part + (((size_t)bn * (BB * SS) + row) * KT + k) * 4);
            S += v.x;
            Q += v.y;
            G += v.z;
        }
        const float mu = S * (1.f / HH);
        const float var = Q * (1.f / HH) - mu * mu;
        const float rs = rsqrtf(var + 1e-12f);
        const float logit = rs * (G - mu * GW1) + BW1 + be1;
        const float pm = p_mask[row];
        em[(size_t)bk * SS + s] = logit * (1.f - pm) - NEGV * pm;
    }
}

// ---------------- launch ----------------
extern "C" void kernel_launch(void* const* d_in, const int* in_sizes, int n_in,
                              void* d_out, int out_size, void* d_ws, size_t ws_size,
                              hipStream_t stream) {
    const float* seq     = (const float*)d_in[0];
    const float* p_mask  = (const float*)d_in[1];
    const float* w_start = (const float*)d_in[2];
    const float* b_start = (const float*)d_in[3];
    const float* w_end0  = (const float*)d_in[4];
    const float* b_end0  = (const float*)d_in[5];
    const float* ln_g    = (const float*)d_in[6];
    const float* ln_b    = (const float*)d_in[7];
    const float* w_end1  = (const float*)d_in[8];
    const float* b_end1  = (const float*)d_in[9];
    const float* w_ans0  = (const float*)d_in[10];
    const float* b_ans0  = (const float*)d_in[11];
    const float* w_ans1  = (const float*)d_in[12];
    float* out = (float*)d_out;

    float* sm      = (float*)d_ws;                  // 8192
    float* sp      = sm + BB * SS;                  // 8192
    float* partial = sp + BB * SS;                  // 524288
    float* feat    = partial + BB * 32 * HH;        // 32768
    float* Cb      = feat + BB * 2048;              // 81920
    float* Cpart   = Cb + 80 * HH;                  // 655360
    float* anspart = Cpart + 8 * 80 * HH;           // 262144
    float* em      = anspart + 16 * BB * HH;        // 40960
    float* scal    = em + BB * KT * SS;             // 16
    int*   idx     = (int*)(scal + 16);             // 80
    float* part    = (float*)(((uintptr_t)(idx + 80) + 255) & ~(uintptr_t)255);  // 1310720 floats
    short* wpk_hi  = (short*)(part + 8 * BB * SS * KT * 4);
    short* wpk_lo  = wpk_hi + (1 << 20);            // 1M bf16 each
    short* apk_hi  = wpk_lo + (1 << 20);            // 8M bf16 each
    short* apk_lo  = apk_hi + (1 << 23);

    hipLaunchKernelGGL(k_prep, dim3(64, 8), dim3(256), 0, stream, w_end0, wpk_hi, wpk_lo);
    hipLaunchKernelGGL(k_seqpk, dim3(4096), dim3(256), 0, stream, seq, apk_hi, apk_lo);
    hipLaunchKernelGGL(k_scal, dim3(1), dim3(256), 0, stream, ln_g, ln_b, w_end1, scal);
    hipLaunchKernelGGL(k_start_logits, dim3(BB * SS / 4), dim3(256), 0, stream,
                       seq, p_mask, w_start, b_start, sm);
    hipLaunchKernelGGL(k_softmax_start, dim3(BB), dim3(256), 0, stream, sm, sp, out, idx);
    hipLaunchKernelGGL(k_sf_partial, dim3(32, BB), dim3(256), 0, stream, seq, sp, partial);
    hipLaunchKernelGGL(k_featsum, dim3(BB), dim3(256), 0, stream, seq, partial, feat);
    hipLaunchKernelGGL(k_ans, dim3(64, 16), dim3(256), 0, stream, feat, w_ans0, anspart);
    hipLaunchKernelGGL(k_ansred, dim3(BB), dim3(256), 0, stream, anspart, b_ans0, w_ans1, out);
    hipLaunchKernelGGL(k_cfeat, dim3(64, 8), dim3(256), 0, stream, seq, idx, w_end0, Cpart);
    hipLaunchKernelGGL(k_cbred, dim3(80), dim3(256), 0, stream, Cpart, b_end0, Cb);
    hipLaunchKernelGGL(k_gemm, dim3(512), dim3(256), 65536, stream,
                       apk_hi, apk_lo, wpk_hi, wpk_lo, Cb, ln_g, w_end1, part);
    hipLaunchKernelGGL(k_epi2, dim3(BB * KT), dim3(256), 0, stream,
                       part, p_mask, scal, b_end1, em);
    hipLaunchKernelGGL(k_softmax_end, dim3(BB * KT), dim3(256), 0, stream, em, out);
}

// Round 7
// 156.486 us; speedup vs baseline: 4.1702x; 1.0304x over previous
//
#include <hip/hip_runtime.h>
#include <math.h>

#define BB 16
#define SS 512
#define HH 1024
#define KT 5
#define NEGV 1e30f

typedef __attribute__((ext_vector_type(8))) short short8_t;
typedef __attribute__((ext_vector_type(4))) float f32x4;

// ---------------- helpers ----------------
__device__ __forceinline__ float wave_sum(float v) {
    for (int off = 32; off; off >>= 1) v += __shfl_down(v, off);
    return v;
}

__device__ __forceinline__ unsigned short bf16rn(float x) {
    unsigned u = __float_as_uint(x);
    return (unsigned short)((u + 0x7fffu + ((u >> 16) & 1u)) >> 16);
}

__device__ __forceinline__ void split2(float x, unsigned short& h, unsigned short& l) {
    h = bf16rn(x);
    float hf = __uint_as_float(((unsigned)h) << 16);
    l = bf16rn(x - hf);
}

__device__ __forceinline__ float tanh_fast(float x) {
    float e = __expf(2.0f * x);
    return 1.0f - 2.0f * __builtin_amdgcn_rcpf(e + 1.0f);
}

// async global->LDS, 16B per lane; lds dst must be wave-uniform base
__device__ __forceinline__ void gld16(const short* g, char* l) {
    __builtin_amdgcn_global_load_lds((const __attribute__((address_space(1))) void*)g,
                                     (__attribute__((address_space(3))) void*)l, 16, 0, 0);
}

// ---------------- k_prep: pack W0a into MFMA B-frag order (hi/lo) ----------------
// Wpk layout: [ntile(64)][kblk(32)][lane(64)][8] bf16; lane l holds
// B[kblk*32 + (l>>4)*8 + j][ntile*16 + (l&15)].
__global__ void k_prep(const float* __restrict__ w_end0,
                       short* __restrict__ wpk_hi, short* __restrict__ wpk_lo) {
    const int nt = blockIdx.x;      // 0..63 n-tile
    const int t = threadIdx.x;
    const int n_idx = t & 15;
    const int g = (t >> 4) & 3;     // k-group within kblk
    const int kq = t >> 6;
    const int kblk = blockIdx.y * 4 + kq;
    const int k0 = kblk * 32 + g * 8;
    unsigned short hs[8], ls[8];
#pragma unroll
    for (int j = 0; j < 8; ++j) {
        float v = w_end0[(size_t)(k0 + j) * HH + nt * 16 + n_idx];
        split2(v, hs[j], ls[j]);
    }
    const size_t fi = (((size_t)nt * 32 + kblk) * 64 + (g * 16 + n_idx)) * 8;
    short8_t hv, lv;
#pragma unroll
    for (int j = 0; j < 8; ++j) { hv[j] = (short)hs[j]; lv[j] = (short)ls[j]; }
    *(short8_t*)(wpk_hi + fi) = hv;
    *(short8_t*)(wpk_lo + fi) = lv;
}

// ---------------- k_seqpk: pack seq into MFMA A-frag order (hi/lo) ----------------
// Apk layout: [bm(64)][ks(32)][mtl(8)][lane(64)][8] bf16; lane l holds
// A[bm*128 + mtl*16 + (l&15)][ks*32 + (l>>4)*8 + j].
__global__ void k_seqpk(const float* __restrict__ seq,
                        short* __restrict__ apk_hi, short* __restrict__ apk_lo) {
    const size_t g = (size_t)blockIdx.x * 256 + threadIdx.x;  // 0..1M-1
    const int l = g & 63;
    const int mtl = (g >> 6) & 7;
    const int ks = (g >> 9) & 31;
    const int bm = g >> 14;
    const int row = bm * 128 + mtl * 16 + (l & 15);
    const int k0 = ks * 32 + (l >> 4) * 8;
    const float4 v0 = *(const float4*)(seq + (size_t)row * HH + k0);
    const float4 v1 = *(const float4*)(seq + (size_t)row * HH + k0 + 4);
    unsigned short h[8], lo[8];
    split2(v0.x, h[0], lo[0]);
    split2(v0.y, h[1], lo[1]);
    split2(v0.z, h[2], lo[2]);
    split2(v0.w, h[3], lo[3]);
    split2(v1.x, h[4], lo[4]);
    split2(v1.y, h[5], lo[5]);
    split2(v1.z, h[6], lo[6]);
    split2(v1.w, h[7], lo[7]);
    short8_t hv, lv;
#pragma unroll
    for (int j = 0; j < 8; ++j) { hv[j] = (short)h[j]; lv[j] = (short)lo[j]; }
    *(short8_t*)(apk_hi + g * 8) = hv;
    *(short8_t*)(apk_lo + g * 8) = lv;
}

// ---------------- k_scal: GW1 = sum g*w1, BW1 = sum b*w1 ----------------
__global__ void k_scal(const float* __restrict__ ln_g, const float* __restrict__ ln_b,
                       const float* __restrict__ w_end1, float* __restrict__ scal) {
    __shared__ float scr[8];
    const int t = threadIdx.x;
    float4 g = ((const float4*)ln_g)[t];
    float4 w = ((const float4*)w_end1)[t];
    float4 b = ((const float4*)ln_b)[t];
    float gw = g.x * w.x + g.y * w.y + g.z * w.z + g.w * w.w;
    float bw = b.x * w.x + b.y * w.y + b.z * w.z + b.w * w.w;
    gw = wave_sum(gw);
    bw = wave_sum(bw);
    if ((t & 63) == 0) { scr[t >> 6] = gw; scr[4 + (t >> 6)] = bw; }
    __syncthreads();
    if (t == 0) {
        scal[0] = scr[0] + scr[1] + scr[2] + scr[3];
        scal[1] = scr[4] + scr[5] + scr[6] + scr[7];
    }
}

// ---------------- kernel 1: start logits + mask (wave per row) ----------------
__global__ void k_start_logits(const float* __restrict__ seq, const float* __restrict__ pm,
                               const float* __restrict__ w_start, const float* __restrict__ b_start,
                               float* __restrict__ sm) {
    const int t = threadIdx.x;
    const int l = t & 63;
    const int row = blockIdx.x * 4 + (t >> 6);
    const float4* rp = (const float4*)(seq + (size_t)row * HH);
    const float4* wp = (const float4*)w_start;
    float d = 0.f;
#pragma unroll
    for (int q = 0; q < 4; ++q) {
        float4 a = rp[q * 64 + l];
        float4 w = wp[q * 64 + l];
        d += a.x * w.x + a.y * w.y + a.z * w.z + a.w * w.w;
    }
    d = wave_sum(d);
    if (l == 0) {
        float m = pm[row];
        sm[row] = (d + b_start[0]) * (1.f - m) - NEGV * m;
    }
}

// ---------------- softmax + top-5 over 512 values (one block, 256 thr) ----------------
template <bool WRITE_P>
__device__ void softmax_topk(const float* __restrict__ x, float* __restrict__ p_out,
                             float* __restrict__ val_out, float* __restrict__ idxf_out,
                             int* __restrict__ idxi_out) {
    const int t = threadIdx.x;
    __shared__ float scr[4];
    __shared__ float sv[4];
    __shared__ int si[4];
    __shared__ int wi_s;
    float x0 = x[t], x1 = x[t + 256];

    float m = fmaxf(x0, x1);
    for (int off = 32; off; off >>= 1) m = fmaxf(m, __shfl_down(m, off));
    if ((t & 63) == 0) scr[t >> 6] = m;
    __syncthreads();
    m = fmaxf(fmaxf(scr[0], scr[1]), fmaxf(scr[2], scr[3]));
    __syncthreads();

    float e0 = expf(x0 - m), e1 = expf(x1 - m);
    float ssum = wave_sum(e0 + e1);
    if ((t & 63) == 0) scr[t >> 6] = ssum;
    __syncthreads();
    ssum = scr[0] + scr[1] + scr[2] + scr[3];
    __syncthreads();

    if (WRITE_P) {
        p_out[t] = e0 / ssum;
        p_out[t + 256] = e1 / ssum;
    }
    const float lse = m + logf(ssum);

    float v0 = x0, v1 = x1;
    for (int k = 0; k < KT; ++k) {
        float bv;
        int bi;
        if (v0 >= v1) { bv = v0; bi = t; } else { bv = v1; bi = t + 256; }
        for (int off = 32; off; off >>= 1) {
            float ov = __shfl_down(bv, off);
            int oi = __shfl_down(bi, off);
            if (ov > bv || (ov == bv && oi < bi)) { bv = ov; bi = oi; }
        }
        if ((t & 63) == 0) { sv[t >> 6] = bv; si[t >> 6] = bi; }
        __syncthreads();
        if (t == 0) {
            float fv = sv[0];
            int fi = si[0];
            for (int w = 1; w < 4; ++w)
                if (sv[w] > fv || (sv[w] == fv && si[w] < fi)) { fv = sv[w]; fi = si[w]; }
            wi_s = fi;
            val_out[k] = fv - lse;
            idxf_out[k] = (float)fi;
            if (idxi_out) idxi_out[k] = fi;
        }
        __syncthreads();
        const int wi = wi_s;
        if (wi == t) v0 = -INFINITY;
        else if (wi == t + 256) v1 = -INFINITY;
        __syncthreads();
    }
}

__global__ void k_softmax_start(const float* __restrict__ sm, float* __restrict__ sp,
                                float* __restrict__ dout, int* __restrict__ idx) {
    const int b = blockIdx.x;
    softmax_topk<true>(sm + (size_t)b * SS, sp + (size_t)b * SS,
                       dout + b * KT, dout + 80 + b * KT, idx + b * KT);
}

__global__ void k_softmax_end(const float* __restrict__ em, float* __restrict__ dout) {
    const int bk = blockIdx.x;
    const int b = bk / KT, k = bk % KT;
    softmax_topk<false>(em + (size_t)bk * SS, nullptr,
                        dout + 160 + b * 25 + k * KT, dout + 560 + b * 25 + k * KT, nullptr);
}

// ---------------- start_feature partial sums (16-row chunks, 512 blocks) ----------------
__global__ void k_sf_partial(const float* __restrict__ seq, const float* __restrict__ sp,
                             float* __restrict__ partial) {
    const int chunk = blockIdx.x;  // 0..31
    const int b = blockIdx.y;
    const int t = threadIdx.x;
    __shared__ float p[16];
    if (t < 16) p[t] = sp[b * SS + chunk * 16 + t];
    __syncthreads();
    float4 acc = make_float4(0.f, 0.f, 0.f, 0.f);
    const float4* base = (const float4*)(seq + ((size_t)b * SS + chunk * 16) * HH);
    for (int s = 0; s < 16; ++s) {
        float4 v = base[(size_t)s * 256 + t];
        float ps = p[s];
        acc.x = fmaf(ps, v.x, acc.x);
        acc.y = fmaf(ps, v.y, acc.y);
        acc.z = fmaf(ps, v.z, acc.z);
        acc.w = fmaf(ps, v.w, acc.w);
    }
    ((float4*)partial)[(size_t)(b * 32 + chunk) * 256 + t] = acc;
}

// ---------------- k_featsum: feat[b][0:1024]=start_feature, [1024:2048]=cls ----------------
__global__ void k_featsum(const float* __restrict__ seq, const float* __restrict__ partial,
                          float* __restrict__ feat) {
    const int b = blockIdx.x, t = threadIdx.x;
    for (int q = 0; q < 4; ++q) {
        const int h = q * 256 + t;
        float s = 0.f;
        for (int c = 0; c < 32; ++c) s += partial[(size_t)(b * 32 + c) * HH + h];
        feat[(size_t)b * 2048 + h] = s;
        feat[(size_t)b * 2048 + HH + h] = seq[(size_t)b * SS * HH + h];
    }
}

// ---------------- k_ans: ans-head GEMM partials, K-split (64 x 16 blocks) ----------------
__global__ void k_ans(const float* __restrict__ feat, const float* __restrict__ w_ans0,
                      float* __restrict__ anspart) {
    __shared__ float A[16 * 132];
    __shared__ float W[16 * 132];
    const int c = blockIdx.x;   // 0..63 col chunk of 16
    const int kc = blockIdx.y;  // 0..15 K chunk of 128 (over 2048)
    const int t = threadIdx.x;
#pragma unroll
    for (int i = 0; i < 8; ++i) {
        const int e = i * 256 + t;
        const int b = e >> 7, d = e & 127;
        A[b * 132 + d] = feat[(size_t)b * 2048 + kc * 128 + d];
    }
#pragma unroll
    for (int p = 0; p < 8; ++p) {
        const int e = p * 256 + t;
        const int d = e >> 4, j = e & 15;
        W[j * 132 + d] = w_ans0[(size_t)(kc * 128 + d) * HH + c * 16 + j];
    }
    __syncthreads();
    const int j = t & 15, b = t >> 4;
    const float4* A4 = (const float4*)A;  // stride 33 float4
    const float4* W4 = (const float4*)W;
    float acc = 0.f;
    for (int d4 = 0; d4 < 32; ++d4) {
        float4 wv = W4[j * 33 + d4];
        float4 av = A4[b * 33 + d4];
        acc += av.x * wv.x + av.y * wv.y + av.z * wv.z + av.w * wv.w;
    }
    anspart[((size_t)kc * 16 + b) * HH + c * 16 + j] = acc;
}

__global__ void k_ansred(const float* __restrict__ anspart, const float* __restrict__ b_ans0,
                         const float* __restrict__ w_ans1, float* __restrict__ out) {
    __shared__ float scr[4];
    const int b = blockIdx.x;
    const int t = threadIdx.x;
    float dsum = 0.f;
#pragma unroll
    for (int q = 0; q < 4; ++q) {
        const int h = q * 256 + t;
        float s = b_ans0[h];
#pragma unroll
        for (int kc = 0; kc < 16; ++kc) s += anspart[((size_t)kc * 16 + b) * HH + h];
        dsum += tanhf(s) * w_ans1[h];
    }
    dsum = wave_sum(dsum);
    if ((t & 63) == 0) scr[t >> 6] = dsum;
    __syncthreads();
    if (t == 0) out[960 + b] = scr[0] + scr[1] + scr[2] + scr[3];
}

// ---------------- k_cfeat: Cb partials, K-split (64 x 8 blocks) ----------------
__global__ void k_cfeat(const float* __restrict__ seq, const int* __restrict__ idx,
                        const float* __restrict__ w_end0, float* __restrict__ Cpart) {
    __shared__ float A[80 * 132];
    __shared__ float W[16 * 132];
    __shared__ int growL[80];
    const int c = blockIdx.x;   // 0..63 col chunk of 16
    const int kc = blockIdx.y;  // 0..7 K chunk of 128
    const int t = threadIdx.x;
    if (t < 80) growL[t] = (t / KT) * SS + idx[t];
    __syncthreads();
    for (int i = 0; i < 40; ++i) {
        const int e = i * 256 + t;
        const int r = e >> 7, d = e & 127;
        A[r * 132 + d] = seq[(size_t)growL[r] * HH + kc * 128 + d];
    }
#pragma unroll
    for (int p = 0; p < 8; ++p) {
        const int e = p * 256 + t;
        const int d = e >> 4, j = e & 15;
        W[j * 132 + d] = w_end0[(size_t)(HH + kc * 128 + d) * HH + c * 16 + j];
    }
    __syncthreads();
    const int j = t & 15, rg = t >> 4;
    const float4* A4 = (const float4*)A;
    const float4* W4 = (const float4*)W;
    float acc[5] = {0.f, 0.f, 0.f, 0.f, 0.f};
    for (int d4 = 0; d4 < 32; ++d4) {
        float4 wv = W4[j * 33 + d4];
#pragma unroll
        for (int i = 0; i < 5; ++i) {
            float4 av = A4[(rg + 16 * i) * 33 + d4];
            acc[i] += av.x * wv.x + av.y * wv.y + av.z * wv.z + av.w * wv.w;
        }
    }
#pragma unroll
    for (int i = 0; i < 5; ++i)
        Cpart[((size_t)kc * 80 + rg + 16 * i) * HH + c * 16 + j] = acc[i];
}

__global__ void k_cbred(const float* __restrict__ Cpart, const float* __restrict__ b_end0,
                        float* __restrict__ Cb) {
    const int bk = blockIdx.x;  // 0..79
    const int t = threadIdx.x;
#pragma unroll
    for (int q = 0; q < 4; ++q) {
        const int h = q * 256 + t;
        float s = b_end0[h];
#pragma unroll
        for (int kc = 0; kc < 8; ++kc) s += Cpart[((size_t)kc * 80 + bk) * HH + h];
        Cb[(size_t)bk * HH + h] = s;
    }
}

// ---------------- k_gemm: 2D-tiled split-bf16 MFMA GEMM, counted-vmcnt pipeline ----------------
// BM=128 x BN=128, BK=32, 4 waves (2x2), wave tile 64x64. Pre-packed A and W
// fragments staged via global_load_lds (16B/lane, linear LDS), 2-deep prefetch:
// tile ks+2 staged while ks computes; vmcnt(8) waits only the OLDER 8 of 16
// outstanding DMA loads (T3/T4: never drain to 0 in steady state).
// Per buffer (32 KB): AH[8][1KB] @0, AL @8K, WH @16K, WL @24K.
// XCD swizzle: each XCD owns an 8bm x 8bn square region.
__global__ __launch_bounds__(256, 2)
void k_gemm(const short* __restrict__ apk_hi, const short* __restrict__ apk_lo,
            const short* __restrict__ wpk_hi, const short* __restrict__ wpk_lo,
            const float* __restrict__ Cb, const float* __restrict__ ln_g,
            const float* __restrict__ w_end1, float* __restrict__ part) {
    extern __shared__ char smem[];  // 65536
    const int t = threadIdx.x;
    const int l = t & 63, w = t >> 6;
    const int wr = w >> 1, wc = w & 1;
    const int wg = blockIdx.x;
    const int xcd = wg & 7;
    const int local = wg >> 3;          // 0..63
    const int bm = xcd * 8 + (local >> 3);
    const int bn = local & 7;
    const int row0 = bm * 128;
    const int b = row0 >> 9;

    f32x4 acc[4][4];
#pragma unroll
    for (int m = 0; m < 4; ++m)
#pragma unroll
        for (int n = 0; n < 4; ++n) acc[m][n] = (f32x4){0.f, 0.f, 0.f, 0.f};

    // per-wave staging: 8 x global_load_lds (2 AH, 2 AL, 2 WH, 2 WL frags)
#define STAGE(buf, ks)                                                                   \
    {                                                                                    \
        const size_t abase = (size_t)(bm * 32 + (ks)) * 8 * 512;                         \
        const size_t wbase = ((size_t)(bn * 8) * 32 + (ks)) * 512;                       \
        char* lb = smem + (buf) * 32768;                                                 \
        _Pragma("unroll") for (int q = 0; q < 2; ++q) {                                  \
            const int fr = w + q * 4;                                                    \
            gld16(apk_hi + abase + fr * 512 + l * 8, lb + fr * 1024);                    \
            gld16(apk_lo + abase + fr * 512 + l * 8, lb + 8192 + fr * 1024);             \
            gld16(wpk_hi + wbase + (size_t)fr * 32 * 512 + l * 8, lb + 16384 + fr * 1024); \
            gld16(wpk_lo + wbase + (size_t)fr * 32 * 512 + l * 8, lb + 24576 + fr * 1024); \
        }                                                                                \
    }

    // prologue: 2 tiles in flight
    STAGE(0, 0);
    STAGE(1, 1);

#pragma unroll 2
    for (int ks = 0; ks < 32; ++ks) {
        const int buf = ks & 1;
        // wait tile ks landed (leave tile ks+1's 8 loads in flight)
        if (ks < 31) {
            asm volatile("s_waitcnt vmcnt(8)" ::: "memory");
        } else {
            asm volatile("s_waitcnt vmcnt(0)" ::: "memory");
        }
        __builtin_amdgcn_s_barrier();
        __builtin_amdgcn_sched_barrier(0);
        {
            const char* base_ = smem + buf * 32768;
            short8_t ah[4], al[4], wh[4], wl[4];
#pragma unroll
            for (int m = 0; m < 4; ++m) {
                const int mtl = wr * 4 + m;
                ah[m] = *(const short8_t*)(base_ + (mtl << 10) + (l << 4));
                al[m] = *(const short8_t*)(base_ + 8192 + (mtl << 10) + (l << 4));
            }
#pragma unroll
            for (int n = 0; n < 4; ++n) {
                const int ntl = wc * 4 + n;
                wh[n] = *(const short8_t*)(base_ + 16384 + (ntl << 10) + (l << 4));
                wl[n] = *(const short8_t*)(base_ + 24576 + (ntl << 10) + (l << 4));
            }
            __builtin_amdgcn_s_setprio(1);
#pragma unroll
            for (int n = 0; n < 4; ++n)
#pragma unroll
                for (int m = 0; m < 4; ++m) {
                    acc[m][n] = __builtin_amdgcn_mfma_f32_16x16x32_bf16(ah[m], wh[n], acc[m][n], 0, 0, 0);
                    acc[m][n] = __builtin_amdgcn_mfma_f32_16x16x32_bf16(al[m], wh[n], acc[m][n], 0, 0, 0);
                    acc[m][n] = __builtin_amdgcn_mfma_f32_16x16x32_bf16(ah[m], wl[n], acc[m][n], 0, 0, 0);
                }
            __builtin_amdgcn_s_setprio(0);
        }
        __builtin_amdgcn_sched_barrier(0);
        __builtin_amdgcn_s_barrier();   // all waves done reading buf
        if (ks < 30) STAGE(buf, ks + 2);
    }
#undef STAGE

    // ---- epilogue: per-block partial (S,Q,G) over this 128-col slice ----
    float cbv[KT][4], gwv[4];
#pragma unroll
    for (int n = 0; n < 4; ++n) {
        const int col = bn * 128 + wc * 64 + n * 16 + (l & 15);
        gwv[n] = ln_g[col] * w_end1[col];
#pragma unroll
        for (int k = 0; k < KT; ++k) cbv[k][n] = Cb[(size_t)(b * KT + k) * HH + col];
    }
    float* scr = (float*)smem;  // [wc 2][row 128][k 5][3]

    for (int k = 0; k < KT; ++k) {
        float S[4][4], Q[4][4], G[4][4];
#pragma unroll
        for (int m = 0; m < 4; ++m)
#pragma unroll
            for (int r = 0; r < 4; ++r) { S[m][r] = 0.f; Q[m][r] = 0.f; G[m][r] = 0.f; }
#pragma unroll
        for (int n = 0; n < 4; ++n) {
            const float cb = cbv[k][n];
            const float gwn = gwv[n];
#pragma unroll
            for (int m = 0; m < 4; ++m)
#pragma unroll
                for (int r = 0; r < 4; ++r) {
                    float v = tanh_fast(acc[m][n][r] + cb);
                    S[m][r] += v;
                    Q[m][r] += v * v;
                    G[m][r] += v * gwn;
                }
        }
        for (int msk = 1; msk < 16; msk <<= 1) {
#pragma unroll
            for (int m = 0; m < 4; ++m)
#pragma unroll
                for (int r = 0; r < 4; ++r) {
                    S[m][r] += __shfl_xor(S[m][r], msk);
                    Q[m][r] += __shfl_xor(Q[m][r], msk);
                    G[m][r] += __shfl_xor(G[m][r], msk);
                }
        }
        if ((l & 15) == 0) {
            const int gg = l >> 4;
#pragma unroll
            for (int m = 0; m < 4; ++m)
#pragma unroll
                for (int r = 0; r < 4; ++r) {
                    const int row = wr * 64 + m * 16 + gg * 4 + r;
                    float* sp_ = scr + ((wc * 128 + row) * KT + k) * 3;
                    sp_[0] = S[m][r];
                    sp_[1] = Q[m][r];
                    sp_[2] = G[m][r];
                }
        }
    }
    __syncthreads();

#pragma unroll
    for (int i = 0; i < 3; ++i) {
        const int idx = i * 256 + t;  // 640 = 128 rows * 5 k
        if (idx < 128 * KT) {
            const int row = idx / KT, k = idx % KT;
            const float* a_ = scr + ((0 * 128 + row) * KT + k) * 3;
            const float* b_ = scr + ((1 * 128 + row) * KT + k) * 3;
            float4 o;
            o.x = a_[0] + b_[0];
            o.y = a_[1] + b_[1];
            o.z = a_[2] + b_[2];
            o.w = 0.f;
            *(float4*)(part + (((size_t)bn * (BB * SS) + row0 + row) * KT + k) * 4) = o;
        }
    }
}

// ---------------- k_epi2: combine 8 col-slice partials -> LN logit -> mask -> em ----------------
__global__ void k_epi2(const float* __restrict__ part, const float* __restrict__ p_mask,
                       const float* __restrict__ scal, const float* __restrict__ b_end1,
                       float* __restrict__ em) {
    const int bk = blockIdx.x;  // 0..79
    const int b = bk / KT, k = bk % KT;
    const int t = threadIdx.x;
    const float GW1 = scal[0], BW1 = scal[1], be1 = b_end1[0];
#pragma unroll
    for (int h = 0; h < 2; ++h) {
        const int s = h * 256 + t;
        const int row = b * SS + s;
        float S = 0.f, Q = 0.f, G = 0.f;
#pragma unroll
        for (int bn = 0; bn < 8; ++bn) {
            float4 v = *(const float4*)(part + (((size_t)bn * (BB * SS) + row) * KT + k) * 4);
            S += v.x;
            Q += v.y;
            G += v.z;
        }
        const float mu = S * (1.f / HH);
        const float var = Q * (1.f / HH) - mu * mu;
        const float rs = rsqrtf(var + 1e-12f);
        const float logit = rs * (G - mu * GW1) + BW1 + be1;
        const float pm = p_mask[row];
        em[(size_t)bk * SS + s] = logit * (1.f - pm) - NEGV * pm;
    }
}

// ---------------- launch ----------------
extern "C" void kernel_launch(void* const* d_in, const int* in_sizes, int n_in,
                              void* d_out, int out_size, void* d_ws, size_t ws_size,
                              hipStream_t stream) {
    const float* seq     = (const float*)d_in[0];
    const float* p_mask  = (const float*)d_in[1];
    const float* w_start = (const float*)d_in[2];
    const float* b_start = (const float*)d_in[3];
    const float* w_end0  = (const float*)d_in[4];
    const float* b_end0  = (const float*)d_in[5];
    const float* ln_g    = (const float*)d_in[6];
    const float* ln_b    = (const float*)d_in[7];
    const float* w_end1  = (const float*)d_in[8];
    const float* b_end1  = (const float*)d_in[9];
    const float* w_ans0  = (const float*)d_in[10];
    const float* b_ans0  = (const float*)d_in[11];
    const float* w_ans1  = (const float*)d_in[12];
    float* out = (float*)d_out;

    float* sm      = (float*)d_ws;                  // 8192
    float* sp      = sm + BB * SS;                  // 8192
    float* partial = sp + BB * SS;                  // 524288
    float* feat    = partial + BB * 32 * HH;        // 32768
    float* Cb      = feat + BB * 2048;              // 81920
    float* Cpart   = Cb + 80 * HH;                  // 655360
    float* anspart = Cpart + 8 * 80 * HH;           // 262144
    float* em      = anspart + 16 * BB * HH;        // 40960
    float* scal    = em + BB * KT * SS;             // 16
    int*   idx     = (int*)(scal + 16);             // 80
    float* part    = (float*)(((uintptr_t)(idx + 80) + 255) & ~(uintptr_t)255);  // 1310720 floats
    short* wpk_hi  = (short*)(part + 8 * BB * SS * KT * 4);
    short* wpk_lo  = wpk_hi + (1 << 20);            // 1M bf16 each
    short* apk_hi  = wpk_lo + (1 << 20);            // 8M bf16 each
    short* apk_lo  = apk_hi + (1 << 23);

    hipLaunchKernelGGL(k_prep, dim3(64, 8), dim3(256), 0, stream, w_end0, wpk_hi, wpk_lo);
    hipLaunchKernelGGL(k_seqpk, dim3(4096), dim3(256), 0, stream, seq, apk_hi, apk_lo);
    hipLaunchKernelGGL(k_scal, dim3(1), dim3(256), 0, stream, ln_g, ln_b, w_end1, scal);
    hipLaunchKernelGGL(k_start_logits, dim3(BB * SS / 4), dim3(256), 0, stream,
                       seq, p_mask, w_start, b_start, sm);
    hipLaunchKernelGGL(k_softmax_start, dim3(BB), dim3(256), 0, stream, sm, sp, out, idx);
    hipLaunchKernelGGL(k_sf_partial, dim3(32, BB), dim3(256), 0, stream, seq, sp, partial);
    hipLaunchKernelGGL(k_featsum, dim3(BB), dim3(256), 0, stream, seq, partial, feat);
    hipLaunchKernelGGL(k_ans, dim3(64, 16), dim3(256), 0, stream, feat, w_ans0, anspart);
    hipLaunchKernelGGL(k_ansred, dim3(BB), dim3(256), 0, stream, anspart, b_ans0, w_ans1, out);
    hipLaunchKernelGGL(k_cfeat, dim3(64, 8), dim3(256), 0, stream, seq, idx, w_end0, Cpart);
    hipLaunchKernelGGL(k_cbred, dim3(80), dim3(256), 0, stream, Cpart, b_end0, Cb);
    hipLaunchKernelGGL(k_gemm, dim3(512), dim3(256), 65536, stream,
                       apk_hi, apk_lo, wpk_hi, wpk_lo, Cb, ln_g, w_end1, part);
    hipLaunchKernelGGL(k_epi2, dim3(BB * KT), dim3(256), 0, stream,
                       part, p_mask, scal, b_end1, em);
    hipLaunchKernelGGL(k_softmax_end, dim3(BB * KT), dim3(256), 0, stream, em, out);
}

// Round 9
// 129.710 us; speedup vs baseline: 5.0311x; 1.2064x over previous
//
#include <hip/hip_runtime.h>
#include <math.h>

#define BB 16
#define SS 512
#define HH 1024
#define KT 5
#define NEGV 1e30f

typedef __attribute__((ext_vector_type(8))) short short8_t;
typedef __attribute__((ext_vector_type(4))) float f32x4;

// ---------------- helpers ----------------
__device__ __forceinline__ float wave_sum(float v) {
    for (int off = 32; off; off >>= 1) v += __shfl_down(v, off);
    return v;
}

__device__ __forceinline__ unsigned short bf16rn(float x) {
    unsigned u = __float_as_uint(x);
    return (unsigned short)((u + 0x7fffu + ((u >> 16) & 1u)) >> 16);
}

__device__ __forceinline__ void split2(float x, unsigned short& h, unsigned short& l) {
    h = bf16rn(x);
    float hf = __uint_as_float(((unsigned)h) << 16);
    l = bf16rn(x - hf);
}

__device__ __forceinline__ float tanh_fast(float x) {
    float e = __expf(2.0f * x);
    return 1.0f - 2.0f * __builtin_amdgcn_rcpf(e + 1.0f);
}

// async global->LDS, 16B per lane; lds dst must be wave-uniform base
__device__ __forceinline__ void gld16(const short* g, char* l) {
    __builtin_amdgcn_global_load_lds((const __attribute__((address_space(1))) void*)g,
                                     (__attribute__((address_space(3))) void*)l, 16, 0, 0);
}

// ---------------- softmax + top-5 over 512 values held as (x0,x1) per thread ----------------
template <bool WRITE_P>
__device__ void softmax_topk_vals(float x0, float x1, float* __restrict__ p_out,
                                  float* __restrict__ val_out, float* __restrict__ idxf_out,
                                  int* __restrict__ idxi_out) {
    const int t = threadIdx.x;
    __shared__ float scr[4];
    __shared__ float sv[4];
    __shared__ int si[4];
    __shared__ int wi_s;

    float m = fmaxf(x0, x1);
    for (int off = 32; off; off >>= 1) m = fmaxf(m, __shfl_down(m, off));
    if ((t & 63) == 0) scr[t >> 6] = m;
    __syncthreads();
    m = fmaxf(fmaxf(scr[0], scr[1]), fmaxf(scr[2], scr[3]));
    __syncthreads();

    float e0 = expf(x0 - m), e1 = expf(x1 - m);
    float ssum = wave_sum(e0 + e1);
    if ((t & 63) == 0) scr[t >> 6] = ssum;
    __syncthreads();
    ssum = scr[0] + scr[1] + scr[2] + scr[3];
    __syncthreads();

    if (WRITE_P) {
        p_out[t] = e0 / ssum;
        p_out[t + 256] = e1 / ssum;
    }
    const float lse = m + logf(ssum);

    float v0 = x0, v1 = x1;
    for (int k = 0; k < KT; ++k) {
        float bv;
        int bi;
        if (v0 >= v1) { bv = v0; bi = t; } else { bv = v1; bi = t + 256; }
        for (int off = 32; off; off >>= 1) {
            float ov = __shfl_down(bv, off);
            int oi = __shfl_down(bi, off);
            if (ov > bv || (ov == bv && oi < bi)) { bv = ov; bi = oi; }
        }
        if ((t & 63) == 0) { sv[t >> 6] = bv; si[t >> 6] = bi; }
        __syncthreads();
        if (t == 0) {
            float fv = sv[0];
            int fi = si[0];
            for (int w = 1; w < 4; ++w)
                if (sv[w] > fv || (sv[w] == fv && si[w] < fi)) { fv = sv[w]; fi = si[w]; }
            wi_s = fi;
            val_out[k] = fv - lse;
            idxf_out[k] = (float)fi;
            if (idxi_out) idxi_out[k] = fi;
        }
        __syncthreads();
        const int wi = wi_s;
        if (wi == t) v0 = -INFINITY;
        else if (wi == t + 256) v1 = -INFINITY;
        __syncthreads();
    }
}

// ---------------- K1 mega_prep: seqpk | prep | start_logits | scal ----------------
// grid = 4096 (seqpk) + 512 (prep) + 2048 (start_logits) + 1 (scal) = 6657
__global__ void k_mega(const float* __restrict__ seq, const float* __restrict__ w_end0,
                       const float* __restrict__ pm, const float* __restrict__ w_start,
                       const float* __restrict__ b_start, const float* __restrict__ ln_g,
                       const float* __restrict__ ln_b, const float* __restrict__ w_end1,
                       short* __restrict__ wpk_hi, short* __restrict__ wpk_lo,
                       short* __restrict__ apk_hi, short* __restrict__ apk_lo,
                       float* __restrict__ sm, float* __restrict__ scal) {
    const int bid = blockIdx.x;
    const int t = threadIdx.x;
    __shared__ float scr8[8];

    if (bid < 4096) {
        // ---- seqpk: pack seq into MFMA A-frag order (bf16 hi/lo) ----
        // Apk layout: [bm(64)][ks(32)][mtl(8)][lane(64)][8] bf16
        const size_t g = (size_t)bid * 256 + t;
        const int l = g & 63;
        const int mtl = (g >> 6) & 7;
        const int ks = (g >> 9) & 31;
        const int bm = g >> 14;
        const int row = bm * 128 + mtl * 16 + (l & 15);
        const int k0 = ks * 32 + (l >> 4) * 8;
        const float4 v0 = *(const float4*)(seq + (size_t)row * HH + k0);
        const float4 v1 = *(const float4*)(seq + (size_t)row * HH + k0 + 4);
        float xs[8] = {v0.x, v0.y, v0.z, v0.w, v1.x, v1.y, v1.z, v1.w};
        unsigned short h[8], lo[8];
#pragma unroll
        for (int j = 0; j < 8; ++j) split2(xs[j], h[j], lo[j]);
        short8_t hv, lv;
#pragma unroll
        for (int j = 0; j < 8; ++j) { hv[j] = (short)h[j]; lv[j] = (short)lo[j]; }
        *(short8_t*)(apk_hi + g * 8) = hv;
        *(short8_t*)(apk_lo + g * 8) = lv;
    } else if (bid < 4608) {
        // ---- prep: pack W0a into MFMA B-frag order (bf16 hi/lo) ----
        const int bid2 = bid - 4096;
        const int nt = bid2 & 63;
        const int yy = bid2 >> 6;
        const int n_idx = t & 15;
        const int g = (t >> 4) & 3;
        const int kq = t >> 6;
        const int kblk = yy * 4 + kq;
        const int k0 = kblk * 32 + g * 8;
        unsigned short hs[8], ls[8];
#pragma unroll
        for (int j = 0; j < 8; ++j) {
            float v = w_end0[(size_t)(k0 + j) * HH + nt * 16 + n_idx];
            split2(v, hs[j], ls[j]);
        }
        const size_t fi = (((size_t)nt * 32 + kblk) * 64 + (g * 16 + n_idx)) * 8;
        short8_t hv, lv;
#pragma unroll
        for (int j = 0; j < 8; ++j) { hv[j] = (short)hs[j]; lv[j] = (short)ls[j]; }
        *(short8_t*)(wpk_hi + fi) = hv;
        *(short8_t*)(wpk_lo + fi) = lv;
    } else if (bid < 6656) {
        // ---- start_logits: wave per row ----
        const int l = t & 63;
        const int row = (bid - 4608) * 4 + (t >> 6);
        const float4* rp = (const float4*)(seq + (size_t)row * HH);
        const float4* wp = (const float4*)w_start;
        float d = 0.f;
#pragma unroll
        for (int q = 0; q < 4; ++q) {
            float4 a = rp[q * 64 + l];
            float4 w = wp[q * 64 + l];
            d += a.x * w.x + a.y * w.y + a.z * w.z + a.w * w.w;
        }
        d = wave_sum(d);
        if (l == 0) {
            float m = pm[row];
            sm[row] = (d + b_start[0]) * (1.f - m) - NEGV * m;
        }
    } else {
        // ---- scal: GW1 = sum g*w1, BW1 = sum b*w1 ----
        float4 g = ((const float4*)ln_g)[t];
        float4 w = ((const float4*)w_end1)[t];
        float4 b = ((const float4*)ln_b)[t];
        float gw = g.x * w.x + g.y * w.y + g.z * w.z + g.w * w.w;
        float bw = b.x * w.x + b.y * w.y + b.z * w.z + b.w * w.w;
        gw = wave_sum(gw);
        bw = wave_sum(bw);
        if ((t & 63) == 0) { scr8[t >> 6] = gw; scr8[4 + (t >> 6)] = bw; }
        __syncthreads();
        if (t == 0) {
            scal[0] = scr8[0] + scr8[1] + scr8[2] + scr8[3];
            scal[1] = scr8[4] + scr8[5] + scr8[6] + scr8[7];
        }
    }
}

// ---------------- K2: softmax_start (start top-5 + probs) ----------------
__global__ void k_softmax_start(const float* __restrict__ sm, float* __restrict__ sp,
                                float* __restrict__ dout, int* __restrict__ idx) {
    const int b = blockIdx.x;
    const int t = threadIdx.x;
    const float* x = sm + (size_t)b * SS;
    softmax_topk_vals<true>(x[t], x[t + 256], sp + (size_t)b * SS,
                            dout + b * KT, dout + 80 + b * KT, idx + b * KT);
}

// ---------------- K3 mid: cfeat (512 blocks) | sf_partial (512 blocks) ----------------
__global__ void k_mid(const float* __restrict__ seq, const int* __restrict__ idx,
                      const float* __restrict__ w_end0, float* __restrict__ Cpart,
                      const float* __restrict__ sp, float* __restrict__ partial) {
    __shared__ float shA[80 * 132];
    __shared__ float shW[16 * 132];
    __shared__ int growL[80];
    const int bid = blockIdx.x;
    const int t = threadIdx.x;

    if (bid < 512) {
        // ---- cfeat: Cb partials, K-split ----
        const int c = bid & 63;
        const int kc = bid >> 6;
        if (t < 80) growL[t] = (t / KT) * SS + idx[t];
        __syncthreads();
        for (int i = 0; i < 40; ++i) {
            const int e = i * 256 + t;
            const int r = e >> 7, d = e & 127;
            shA[r * 132 + d] = seq[(size_t)growL[r] * HH + kc * 128 + d];
        }
#pragma unroll
        for (int p = 0; p < 8; ++p) {
            const int e = p * 256 + t;
            const int d = e >> 4, j = e & 15;
            shW[j * 132 + d] = w_end0[(size_t)(HH + kc * 128 + d) * HH + c * 16 + j];
        }
        __syncthreads();
        const int j = t & 15, rg = t >> 4;
        const float4* A4 = (const float4*)shA;
        const float4* W4 = (const float4*)shW;
        float acc[5] = {0.f, 0.f, 0.f, 0.f, 0.f};
        for (int d4 = 0; d4 < 32; ++d4) {
            float4 wv = W4[j * 33 + d4];
#pragma unroll
            for (int i = 0; i < 5; ++i) {
                float4 av = A4[(rg + 16 * i) * 33 + d4];
                acc[i] += av.x * wv.x + av.y * wv.y + av.z * wv.z + av.w * wv.w;
            }
        }
#pragma unroll
        for (int i = 0; i < 5; ++i)
            Cpart[((size_t)kc * 80 + rg + 16 * i) * HH + c * 16 + j] = acc[i];
    } else {
        // ---- sf_partial: start_feature partial sums (16-row chunks) ----
        const int bid2 = bid - 512;
        const int chunk = bid2 & 31;
        const int b = bid2 >> 5;
        if (t < 16) shA[t] = sp[b * SS + chunk * 16 + t];
        __syncthreads();
        float4 acc = make_float4(0.f, 0.f, 0.f, 0.f);
        const float4* base = (const float4*)(seq + ((size_t)b * SS + chunk * 16) * HH);
        for (int s = 0; s < 16; ++s) {
            float4 v = base[(size_t)s * 256 + t];
            float ps = shA[s];
            acc.x = fmaf(ps, v.x, acc.x);
            acc.y = fmaf(ps, v.y, acc.y);
            acc.z = fmaf(ps, v.z, acc.z);
            acc.w = fmaf(ps, v.w, acc.w);
        }
        ((float4*)partial)[(size_t)(b * 32 + chunk) * 256 + t] = acc;
    }
}

// ---------------- K4 red: cbred (80) | featsum (16) ----------------
__global__ void k_red(const float* __restrict__ Cpart, const float* __restrict__ b_end0,
                      float* __restrict__ Cb, const float* __restrict__ seq,
                      const float* __restrict__ partial, float* __restrict__ feat) {
    const int bid = blockIdx.x;
    const int t = threadIdx.x;
    if (bid < 80) {
        const int bk = bid;
#pragma unroll
        for (int q = 0; q < 4; ++q) {
            const int h = q * 256 + t;
            float s = b_end0[h];
#pragma unroll
            for (int kc = 0; kc < 8; ++kc) s += Cpart[((size_t)kc * 80 + bk) * HH + h];
            Cb[(size_t)bk * HH + h] = s;
        }
    } else {
        const int b = bid - 80;
        for (int q = 0; q < 4; ++q) {
            const int h = q * 256 + t;
            float s = 0.f;
            for (int c = 0; c < 32; ++c) s += partial[(size_t)(b * 32 + c) * HH + h];
            feat[(size_t)b * 2048 + h] = s;
            feat[(size_t)b * 2048 + HH + h] = seq[(size_t)b * SS * HH + h];
        }
    }
}

// ---------------- K5: ans-head GEMM partials, K-split (1024 blocks) ----------------
__global__ void k_ans(const float* __restrict__ feat, const float* __restrict__ w_ans0,
                      float* __restrict__ anspart) {
    __shared__ float A[16 * 132];
    __shared__ float W[16 * 132];
    const int c = blockIdx.x & 63;
    const int kc = blockIdx.x >> 6;
    const int t = threadIdx.x;
#pragma unroll
    for (int i = 0; i < 8; ++i) {
        const int e = i * 256 + t;
        const int b = e >> 7, d = e & 127;
        A[b * 132 + d] = feat[(size_t)b * 2048 + kc * 128 + d];
    }
#pragma unroll
    for (int p = 0; p < 8; ++p) {
        const int e = p * 256 + t;
        const int d = e >> 4, j = e & 15;
        W[j * 132 + d] = w_ans0[(size_t)(kc * 128 + d) * HH + c * 16 + j];
    }
    __syncthreads();
    const int j = t & 15, b = t >> 4;
    const float4* A4 = (const float4*)A;
    const float4* W4 = (const float4*)W;
    float acc = 0.f;
    for (int d4 = 0; d4 < 32; ++d4) {
        float4 wv = W4[j * 33 + d4];
        float4 av = A4[b * 33 + d4];
        acc += av.x * wv.x + av.y * wv.y + av.z * wv.z + av.w * wv.w;
    }
    anspart[((size_t)kc * 16 + b) * HH + c * 16 + j] = acc;
}

// ---------------- K6 k_gemm: 2D-tiled split-bf16 MFMA GEMM (R6 proven version) ----------------
__global__ __launch_bounds__(256, 2)
void k_gemm(const short* __restrict__ apk_hi, const short* __restrict__ apk_lo,
            const short* __restrict__ wpk_hi, const short* __restrict__ wpk_lo,
            const float* __restrict__ Cb, const float* __restrict__ ln_g,
            const float* __restrict__ w_end1, float* __restrict__ part) {
    extern __shared__ char smem[];  // 65536
    const int t = threadIdx.x;
    const int l = t & 63, w = t >> 6;
    const int wr = w >> 1, wc = w & 1;
    const int wg = blockIdx.x;
    const int xcd = wg & 7;
    const int local = wg >> 3;          // 0..63
    const int bm = xcd * 8 + (local >> 3);
    const int bn = local & 7;
    const int row0 = bm * 128;
    const int b = row0 >> 9;

    f32x4 acc[4][4];
#pragma unroll
    for (int m = 0; m < 4; ++m)
#pragma unroll
        for (int n = 0; n < 4; ++n) acc[m][n] = (f32x4){0.f, 0.f, 0.f, 0.f};

#define STAGE(buf, ks)                                                                   \
    {                                                                                    \
        const size_t abase = (size_t)(bm * 32 + (ks)) * 8 * 512;                         \
        const size_t wbase = ((size_t)(bn * 8) * 32 + (ks)) * 512;                       \
        char* lb = smem + (buf) * 32768;                                                 \
        _Pragma("unroll") for (int q = 0; q < 2; ++q) {                                  \
            const int fr = w + q * 4;                                                    \
            gld16(apk_hi + abase + fr * 512 + l * 8, lb + fr * 1024);                    \
            gld16(apk_lo + abase + fr * 512 + l * 8, lb + 8192 + fr * 1024);             \
            gld16(wpk_hi + wbase + (size_t)fr * 32 * 512 + l * 8, lb + 16384 + fr * 1024); \
            gld16(wpk_lo + wbase + (size_t)fr * 32 * 512 + l * 8, lb + 24576 + fr * 1024); \
        }                                                                                \
    }

    STAGE(0, 0);
    __syncthreads();

    for (int ks = 0; ks < 32; ++ks) {
        const int buf = ks & 1;
        if (ks < 31) STAGE(buf ^ 1, ks + 1);
        {
            const char* base_ = smem + buf * 32768;
            short8_t ah[4], al[4], wh[4], wl[4];
#pragma unroll
            for (int m = 0; m < 4; ++m) {
                const int mtl = wr * 4 + m;
                ah[m] = *(const short8_t*)(base_ + (mtl << 10) + (l << 4));
                al[m] = *(const short8_t*)(base_ + 8192 + (mtl << 10) + (l << 4));
            }
#pragma unroll
            for (int n = 0; n < 4; ++n) {
                const int ntl = wc * 4 + n;
                wh[n] = *(const short8_t*)(base_ + 16384 + (ntl << 10) + (l << 4));
                wl[n] = *(const short8_t*)(base_ + 24576 + (ntl << 10) + (l << 4));
            }
#pragma unroll
            for (int n = 0; n < 4; ++n)
#pragma unroll
                for (int m = 0; m < 4; ++m) {
                    acc[m][n] = __builtin_amdgcn_mfma_f32_16x16x32_bf16(ah[m], wh[n], acc[m][n], 0, 0, 0);
                    acc[m][n] = __builtin_amdgcn_mfma_f32_16x16x32_bf16(al[m], wh[n], acc[m][n], 0, 0, 0);
                    acc[m][n] = __builtin_amdgcn_mfma_f32_16x16x32_bf16(ah[m], wl[n], acc[m][n], 0, 0, 0);
                }
        }
        __syncthreads();
    }
#undef STAGE

    // ---- epilogue: per-block partial (S,Q,G) over this 128-col slice ----
    float cbv[KT][4], gwv[4];
#pragma unroll
    for (int n = 0; n < 4; ++n) {
        const int col = bn * 128 + wc * 64 + n * 16 + (l & 15);
        gwv[n] = ln_g[col] * w_end1[col];
#pragma unroll
        for (int k = 0; k < KT; ++k) cbv[k][n] = Cb[(size_t)(b * KT + k) * HH + col];
    }
    float* scr = (float*)smem;  // [wc 2][row 128][k 5][3]

    for (int k = 0; k < KT; ++k) {
        float S[4][4], Q[4][4], G[4][4];
#pragma unroll
        for (int m = 0; m < 4; ++m)
#pragma unroll
            for (int r = 0; r < 4; ++r) { S[m][r] = 0.f; Q[m][r] = 0.f; G[m][r] = 0.f; }
#pragma unroll
        for (int n = 0; n < 4; ++n) {
            const float cb = cbv[k][n];
            const float gwn = gwv[n];
#pragma unroll
            for (int m = 0; m < 4; ++m)
#pragma unroll
                for (int r = 0; r < 4; ++r) {
                    float v = tanh_fast(acc[m][n][r] + cb);
                    S[m][r] += v;
                    Q[m][r] += v * v;
                    G[m][r] += v * gwn;
                }
        }
        for (int msk = 1; msk < 16; msk <<= 1) {
#pragma unroll
            for (int m = 0; m < 4; ++m)
#pragma unroll
                for (int r = 0; r < 4; ++r) {
                    S[m][r] += __shfl_xor(S[m][r], msk);
                    Q[m][r] += __shfl_xor(Q[m][r], msk);
                    G[m][r] += __shfl_xor(G[m][r], msk);
                }
        }
        if ((l & 15) == 0) {
            const int gg = l >> 4;
#pragma unroll
            for (int m = 0; m < 4; ++m)
#pragma unroll
                for (int r = 0; r < 4; ++r) {
                    const int row = wr * 64 + m * 16 + gg * 4 + r;
                    float* sp_ = scr + ((wc * 128 + row) * KT + k) * 3;
                    sp_[0] = S[m][r];
                    sp_[1] = Q[m][r];
                    sp_[2] = G[m][r];
                }
        }
    }
    __syncthreads();

#pragma unroll
    for (int i = 0; i < 3; ++i) {
        const int idx = i * 256 + t;  // 640 = 128 rows * 5 k
        if (idx < 128 * KT) {
            const int row = idx / KT, k = idx % KT;
            const float* a_ = scr + ((0 * 128 + row) * KT + k) * 3;
            const float* b_ = scr + ((1 * 128 + row) * KT + k) * 3;
            float4 o;
            o.x = a_[0] + b_[0];
            o.y = a_[1] + b_[1];
            o.z = a_[2] + b_[2];
            o.w = 0.f;
            *(float4*)(part + (((size_t)bn * (BB * SS) + row0 + row) * KT + k) * 4) = o;
        }
    }
}

// ---------------- K7 final: epi2+softmax_end fused (80) | ansred (16) ----------------
__global__ void k_final(const float* __restrict__ part, const float* __restrict__ p_mask,
                        const float* __restrict__ scal, const float* __restrict__ b_end1,
                        const float* __restrict__ anspart, const float* __restrict__ b_ans0,
                        const float* __restrict__ w_ans1, float* __restrict__ out) {
    const int bid = blockIdx.x;
    const int t = threadIdx.x;
    __shared__ float rscr[4];

    if (bid < 80) {
        // ---- epi2 (compute masked end logits for this (b,k)) + softmax + top-5 ----
        const int b = bid / KT, k = bid % KT;
        const float GW1 = scal[0], BW1 = scal[1], be1 = b_end1[0];
        float x01[2];
#pragma unroll
        for (int h = 0; h < 2; ++h) {
            const int s = h * 256 + t;
            const int row = b * SS + s;
            float S = 0.f, Q = 0.f, G = 0.f;
#pragma unroll
            for (int bn = 0; bn < 8; ++bn) {
                float4 v = *(const float4*)(part + (((size_t)bn * (BB * SS) + row) * KT + k) * 4);
                S += v.x;
                Q += v.y;
                G += v.z;
            }
            const float mu = S * (1.f / HH);
            const float var = Q * (1.f / HH) - mu * mu;
            const float rs = rsqrtf(var + 1e-12f);
            const float logit = rs * (G - mu * GW1) + BW1 + be1;
            const float pm = p_mask[row];
            x01[h] = logit * (1.f - pm) - NEGV * pm;
        }
        softmax_topk_vals<false>(x01[0], x01[1], nullptr,
                                 out + 160 + b * 25 + k * KT, out + 560 + b * 25 + k * KT, nullptr);
    } else {
        // ---- ansred: cls_logits ----
        const int b = bid - 80;
        float dsum = 0.f;
#pragma unroll
        for (int q = 0; q < 4; ++q) {
            const int h = q * 256 + t;
            float s = b_ans0[h];
#pragma unroll
            for (int kc = 0; kc < 16; ++kc) s += anspart[((size_t)kc * 16 + b) * HH + h];
            dsum += tanhf(s) * w_ans1[h];
        }
        dsum = wave_sum(dsum);
        if ((t & 63) == 0) rscr[t >> 6] = dsum;
        __syncthreads();
        if (t == 0) out[960 + b] = rscr[0] + rscr[1] + rscr[2] + rscr[3];
    }
}

// ---------------- launch ----------------
extern "C" void kernel_launch(void* const* d_in, const int* in_sizes, int n_in,
                              void* d_out, int out_size, void* d_ws, size_t ws_size,
                              hipStream_t stream) {
    const float* seq     = (const float*)d_in[0];
    const float* p_mask  = (const float*)d_in[1];
    const float* w_start = (const float*)d_in[2];
    const float* b_start = (const float*)d_in[3];
    const float* w_end0  = (const float*)d_in[4];
    const float* b_end0  = (const float*)d_in[5];
    const float* ln_g    = (const float*)d_in[6];
    const float* ln_b    = (const float*)d_in[7];
    const float* w_end1  = (const float*)d_in[8];
    const float* b_end1  = (const float*)d_in[9];
    const float* w_ans0  = (const float*)d_in[10];
    const float* b_ans0  = (const float*)d_in[11];
    const float* w_ans1  = (const float*)d_in[12];
    float* out = (float*)d_out;

    float* sm      = (float*)d_ws;                  // 8192
    float* sp      = sm + BB * SS;                  // 8192
    float* partial = sp + BB * SS;                  // 524288
    float* feat    = partial + BB * 32 * HH;        // 32768
    float* Cb      = feat + BB * 2048;              // 81920
    float* Cpart   = Cb + 80 * HH;                  // 655360
    float* anspart = Cpart + 8 * 80 * HH;           // 262144
    float* scal    = anspart + 16 * BB * HH;        // 16
    int*   idx     = (int*)(scal + 16);             // 80
    float* part    = (float*)(((uintptr_t)(idx + 80) + 255) & ~(uintptr_t)255);  // 1310720 floats
    short* wpk_hi  = (short*)(part + 8 * BB * SS * KT * 4);
    short* wpk_lo  = wpk_hi + (1 << 20);            // 1M bf16 each
    short* apk_hi  = wpk_lo + (1 << 20);            // 8M bf16 each
    short* apk_lo  = apk_hi + (1 << 23);

    hipLaunchKernelGGL(k_mega, dim3(6657), dim3(256), 0, stream,
                       seq, w_end0, p_mask, w_start, b_start, ln_g, ln_b, w_end1,
                       wpk_hi, wpk_lo, apk_hi, apk_lo, sm, scal);
    hipLaunchKernelGGL(k_softmax_start, dim3(BB), dim3(256), 0, stream, sm, sp, out, idx);
    hipLaunchKernelGGL(k_mid, dim3(1024), dim3(256), 0, stream,
                       seq, idx, w_end0, Cpart, sp, partial);
    hipLaunchKernelGGL(k_red, dim3(96), dim3(256), 0, stream,
                       Cpart, b_end0, Cb, seq, partial, feat);
    hipLaunchKernelGGL(k_ans, dim3(1024), dim3(256), 0, stream, feat, w_ans0, anspart);
    hipLaunchKernelGGL(k_gemm, dim3(512), dim3(256), 65536, stream,
                       apk_hi, apk_lo, wpk_hi, wpk_lo, Cb, ln_g, w_end1, part);
    hipLaunchKernelGGL(k_final, dim3(96), dim3(256), 0, stream,
                       part, p_mask, scal, b_end1, anspart, b_ans0, w_ans1, out);
}